// Round 6
// baseline (307.865 us; speedup 1.0000x reference)
//
#include <hip/hip_runtime.h>
#include <hip/hip_bf16.h>
#include <math.h>

#define B_   8
#define T_   128
#define D_   512
#define M_   2048
#define HID_ 128
#define BT_  1024

typedef __attribute__((ext_vector_type(8))) short short8t;
typedef __attribute__((ext_vector_type(8))) unsigned short ushort8t;
typedef __attribute__((ext_vector_type(4))) float f32x4;
typedef __hip_bfloat16 bf16;

// ws layout (float offsets; all multiples of 16 -> 64B aligned)
#define OFF_SCAL   0L
#define OFF_QKV    16L                            // 1024*1536 f32
#define OFF_SK2    (OFF_QKV + 1572864L)           // [dKre|dKim] f32, 2*BT*M
#define OFF_KP     (OFF_SK2 + 4194304L)           // [KR|KI] f32 exclusive prefix
#define OFF_VRAW   (OFF_KP + 4194304L)
#define OFF_VF     (OFF_VRAW + 524288L)
#define OFF_HFEAT  (OFF_VF + 524288L)
// bf16 buffers (size in floats = elems/2)
#define OFF_EB     (OFF_HFEAT + 524288L)          // 1024x512
#define OFF_WQKVT  (OFF_EB + 262144L)             // 1536x512
#define OFF_VP1T   (OFF_WQKVT + 393216L)          // 512x512
#define OFF_VP2T   (OFF_VP1T + 131072L)
#define OFF_RO1T   (OFF_VP2T + 131072L)           // 128x2048
#define OFF_RO2T   (OFF_RO1T + 131072L)           // 512x128
#define OFF_QCAT   (OFF_RO2T + 32768L)            // 1024x4096
#define OFF_KCAT   (OFF_QCAT + 2097152L)          // 1024x4096
#define OFF_DKT    (OFF_KCAT + 2097152L)          // 2x8x2048x128
#define OFF_VTB    (OFF_DKT + 2097152L)           // 8x512x128
#define OFF_PSIB   (OFF_VTB + 262144L)            // 1024x2048
#define OFF_SCOB   (OFF_PSIB + 1048576L)          // 8x128x128 bf16
#define OFF_VLNB   (OFF_SCOB + 65536L)            // 1024x512
#define OFF_V1B    (OFF_VLNB + 262144L)           // 1024x512
#define OFF_HIDB   (OFF_V1B + 262144L)            // 1024x128
#define OFF_SCOA   (OFF_HIDB + 65536L)            // 8x128x128 f32 split-K accumulator
#define OFF_QSUM   (OFF_SCOA + 131072L)           // 4x32768 f32 prefix quarter sums

#define FLAG_BIAS     1
#define FLAG_GELU     2
#define FLAG_ROWSCALE 4
#define FLAG_ATOMIC   8
#define FLAG_MASK     16
#define FLAG_HFB      32

__device__ __forceinline__ float gelu_f(float x) {
    return 0.5f * x * (1.0f + erff(x * 0.70710678118654752440f));
}

__global__ void scal_kernel(const float* tq, const float* tk, const float* om,
                            const float* gf, const float* gv, float* scal) {
    if (threadIdx.x == 0) {
        scal[0] = 0.5f * tanhf(tq[0]);
        scal[1] = 0.5f * tanhf(tk[0]);
        scal[2] = 0.5f * tanhf(om[0]);
        scal[3] = 0.25f / (1.0f + expf(-gf[0]));
        scal[4] = 0.25f / (1.0f + expf(-gv[0]));
    }
}

__global__ __launch_bounds__(256) void cast_kernel(const float* __restrict__ in,
                                                   bf16* __restrict__ out, int n) {
    int i = blockIdx.x * 256 + threadIdx.x;
    if (i < n) out[i] = __float2bfloat16(in[i]);
}

// tiled transpose-cast: in f32 [R][C] (ld_in, batch bs_in) -> out bf16 [C][R] (batch bs_out)
__global__ __launch_bounds__(256) void castT_kernel(const float* __restrict__ in,
                                                    bf16* __restrict__ out,
                                                    int R, int C, int ld_in,
                                                    long bs_in, long bs_out) {
    __shared__ float tile[32][33];
    int b = blockIdx.z;
    int c0 = blockIdx.x * 32, r0 = blockIdx.y * 32;
    int tx = threadIdx.x & 31, ty = threadIdx.x >> 5;
    for (int rr = ty; rr < 32; rr += 8) {
        int r = r0 + rr, c = c0 + tx;
        tile[rr][tx] = (r < R && c < C) ? in[(long)b * bs_in + (long)r * ld_in + c] : 0.f;
    }
    __syncthreads();
    for (int cc = ty; cc < 32; cc += 8) {
        int c = c0 + cc, r = r0 + tx;
        if (c < C && r < R) out[(long)b * bs_out + (long)c * R + r] = __float2bfloat16(tile[tx][cc]);
    }
}

// batched 512x512 transpose-cast for 5 weights in one launch
__global__ __launch_bounds__(256) void castT5_kernel(const float* w0, const float* w1,
                                                     const float* w2, const float* w3,
                                                     const float* w4,
                                                     bf16* d0, bf16* d1, bf16* d2,
                                                     bf16* d3, bf16* d4) {
    __shared__ float tile[32][33];
    int z = blockIdx.z;
    const float* src; bf16* dst;
    if (z == 0)      { src = w0; dst = d0; }
    else if (z == 1) { src = w1; dst = d1; }
    else if (z == 2) { src = w2; dst = d2; }
    else if (z == 3) { src = w3; dst = d3; }
    else             { src = w4; dst = d4; }
    int c0 = blockIdx.x * 32, r0 = blockIdx.y * 32;
    int tx = threadIdx.x & 31, ty = threadIdx.x >> 5;
    for (int rr = ty; rr < 32; rr += 8)
        tile[rr][tx] = src[(long)(r0 + rr) * 512 + c0 + tx];
    __syncthreads();
    for (int cc = ty; cc < 32; cc += 8)
        dst[(long)(c0 + cc) * 512 + r0 + tx] = __float2bfloat16(tile[tx][cc]);
}

// sketch (phase fused): SK2 f32 = [dKre|dKim]; qcat bf16 = [Qre|Qim]; kcat bf16 = [dKre|-dKim]
__global__ __launch_bounds__(256) void sketch_kernel(const float* __restrict__ qkv,
                                                     const float* __restrict__ sign,
                                                     const float* __restrict__ scal,
                                                     const int* __restrict__ h,
                                                     float* __restrict__ SK2,
                                                     bf16* __restrict__ qcat,
                                                     bf16* __restrict__ kcat) {
    int bt = blockIdx.x;
    int tid = threadIdx.x;
    __shared__ float s0[M_], s1[M_], s2[M_], s3[M_];
    for (int j = tid; j < M_; j += 256) { s0[j] = 0.f; s1[j] = 0.f; s2[j] = 0.f; s3[j] = 0.f; }
    __syncthreads();
    int t = bt & 127;
    float thq = scal[0], thk = scal[1], omg = scal[2];
    float ft = (float)t;
    for (int i = tid; i < D_; i += 256) {
        float q = qkv[(long)bt * 1536 + i];
        float k = qkv[(long)bt * 1536 + 512 + i];
        float sg = sign[i];
        float sq_, cq_, sk_, ck_;
        sincosf(thq * q - omg * ft, &sq_, &cq_);
        sincosf(thk * k + omg * ft, &sk_, &ck_);
        int m = h[i];
        atomicAdd(&s0[m], q * cq_ * sg);
        atomicAdd(&s1[m], q * sq_ * sg);
        atomicAdd(&s2[m], k * ck_ * sg);
        atomicAdd(&s3[m], k * sk_ * sg);
    }
    __syncthreads();
    long ob = (long)bt * M_;
    long qb = (long)bt * 4096;
    for (int j = tid; j < M_; j += 256) {
        SK2[ob + j]                  = s2[j];
        SK2[(long)BT_ * M_ + ob + j] = s3[j];
        qcat[qb + j]        = __float2bfloat16(s0[j]);
        qcat[qb + 2048 + j] = __float2bfloat16(s1[j]);
        kcat[qb + j]        = __float2bfloat16(s2[j]);
        kcat[qb + 2048 + j] = __float2bfloat16(-s3[j]);
    }
}

// ---- two-phase exclusive prefix over t (4-way t split) ----
__global__ __launch_bounds__(256) void prefix_p1(const float* __restrict__ SK2,
                                                 float* __restrict__ qsum) {
    int idx = blockIdx.x * 256 + threadIdx.x;   // 131072
    int col = idx & 32767, q = idx >> 15;
    int m = col & 2047, b = (col >> 11) & 7, comp = col >> 14;
    const float* src = SK2 + (long)comp * BT_ * M_ + (long)b * T_ * M_ + (long)(q * 32) * M_ + m;
    float s = 0.f;
    #pragma unroll 8
    for (int i = 0; i < 32; ++i) s += src[(long)i * M_];
    qsum[(long)q * 32768 + col] = s;
}

__global__ __launch_bounds__(256) void prefix_p2(const float* __restrict__ SK2,
                                                 const float* __restrict__ qsum,
                                                 float* __restrict__ KP,
                                                 float* __restrict__ kf_out) {
    int idx = blockIdx.x * 256 + threadIdx.x;   // 131072
    int col = idx & 32767, q = idx >> 15;
    int m = col & 2047, b = (col >> 11) & 7, comp = col >> 14;
    long cb = (long)comp * BT_ * M_ + (long)b * T_ * M_ + m + (long)(q * 32) * M_;
    const float* src = SK2 + cb;
    float* dst = KP + cb;
    float acc = 0.f;
    for (int p = 0; p < q; ++p) acc += qsum[(long)p * 32768 + col];
    #pragma unroll 4
    for (int i = 0; i < 32; ++i) {
        dst[(long)i * M_] = acc;
        acc += src[(long)i * M_];
    }
    if (q == 3) kf_out[((long)b * 2 + comp) * M_ + m] = acc;
}

// ==== wave-level 2048-pt FFT: 64 lanes x 32 regs, zero LDS, zero barriers ====
// Decomposition: x[32*n1+n2], lane=n1, slot=n2.
// Fwd: cross-lane DIF-64 (output k1=bitrev6(lane)) -> twiddle W2048^{n2*k1} -> in-reg DFT-32 (natural k2).
// Inv: exact mirror with conjugate twiddles. Unnormalized both ways (total x2048, folded into scale).

__device__ __forceinline__ void cxmul(float& ar, float& ai, float br, float bi) {
    float t = ar * br - ai * bi;
    ai = ar * bi + ai * br;
    ar = t;
}

template<int H>
__device__ __forceinline__ void fwd64_stage(float (&vr)[32], float (&vi)[32], int lane) {
    int j = lane & (H - 1);
    float s, c;
    sincosf((float)j * (3.14159265358979323846f / (float)H), &s, &c);   // W_{2H}^j = (c, -s)
    bool up = (lane & H) != 0;
    #pragma unroll
    for (int n = 0; n < 32; ++n) {
        float pr = __shfl_xor(vr[n], H);
        float pi = __shfl_xor(vi[n], H);
        float sr = vr[n] + pr, si = vi[n] + pi;        // lower: a + b
        float dr = pr - vr[n], di = pi - vi[n];        // upper: (a - b), a = partner
        float ur = dr * c + di * s;                    // * (c - i s)
        float ui = di * c - dr * s;
        vr[n] = up ? ur : sr;
        vi[n] = up ? ui : si;
    }
}

template<int H>
__device__ __forceinline__ void inv64_stage(float (&vr)[32], float (&vi)[32], int lane) {
    int j = lane & (H - 1);
    float s, c;
    sincosf((float)j * (3.14159265358979323846f / (float)H), &s, &c);   // w = (c, +s)
    bool up = (lane & H) != 0;
    #pragma unroll
    for (int n = 0; n < 32; ++n) {
        float pr = __shfl_xor(vr[n], H);
        float pi = __shfl_xor(vi[n], H);
        float wpr = pr * c - pi * s,       wpi = pi * c + pr * s;       // w*partner
        float wvr = vr[n] * c - vi[n] * s, wvi = vi[n] * c + vr[n] * s; // w*self
        float lr = vr[n] + wpr, li = vi[n] + wpi;   // lower: a + w*b
        float ur = pr - wvr,    ui = pi - wvi;      // upper: a - w*b
        vr[n] = up ? ur : lr;
        vi[n] = up ? ui : li;
    }
}

// SGN=-1: forward (exp(-i...)); SGN=+1: inverse
template<int SGN>
__device__ __forceinline__ void midtw(float (&vr)[32], float (&vi)[32], int lane) {
    int k1 = (int)(__brev((unsigned)lane) >> 26);
    float s0, c0;
    sincosf((float)k1 * (6.28318530717958647692f / 2048.0f), &s0, &c0);
    float br = c0, bi = (SGN < 0) ? -s0 : s0;
    float wr = 1.f, wi = 0.f;
    #pragma unroll
    for (int n = 0; n < 32; ++n) {
        cxmul(vr[n], vi[n], wr, wi);
        float t = wr * br - wi * bi;
        wi = wr * bi + wi * br;
        wr = t;
    }
}

// Stockham radix-2 DFT-32 over register slots, natural in/out. Twiddle = (C[p], SGN*S[p]).
template<int SGN>
__device__ __forceinline__ void dft32(float (&xr)[32], float (&xi)[32]) {
    const float C[16] = {1.f, 0.98078528f, 0.92387953f, 0.83146961f,
                         0.70710678f, 0.55557023f, 0.38268343f, 0.19509032f,
                         0.f, -0.19509032f, -0.38268343f, -0.55557023f,
                         -0.70710678f, -0.83146961f, -0.92387953f, -0.98078528f};
    const float S[16] = {0.f, 0.19509032f, 0.38268343f, 0.55557023f,
                         0.70710678f, 0.83146961f, 0.92387953f, 0.98078528f,
                         1.f, 0.98078528f, 0.92387953f, 0.83146961f,
                         0.70710678f, 0.55557023f, 0.38268343f, 0.19509032f};
    float yr[32], yi[32];
#define DSTG(SR, SI, DR, DI, MM)                                              \
    _Pragma("unroll")                                                         \
    for (int q = 0; q < 16; ++q) {                                            \
        int k = q & (MM - 1); int p = q - k;                                  \
        float ar = SR[q], ai = SI[q], br2 = SR[q + 16], bi2 = SI[q + 16];     \
        float twr = C[p], twi = (float)SGN * S[p];                            \
        DR[2 * p + k] = ar + br2; DI[2 * p + k] = ai + bi2;                   \
        float dr = ar - br2, di = ai - bi2;                                   \
        DR[2 * p + k + MM] = dr * twr - di * twi;                             \
        DI[2 * p + k + MM] = dr * twi + di * twr;                             \
    }
    DSTG(xr, xi, yr, yi, 1)
    DSTG(yr, yi, xr, xi, 2)
    DSTG(xr, xi, yr, yi, 4)
    DSTG(yr, yi, xr, xi, 8)
    DSTG(xr, xi, yr, yi, 16)
#undef DSTG
    #pragma unroll
    for (int q = 0; q < 32; ++q) { xr[q] = yr[q]; xi[q] = yi[q]; }
}

__device__ __forceinline__ void fwd2048(float (&vr)[32], float (&vi)[32], int lane) {
    fwd64_stage<32>(vr, vi, lane);
    fwd64_stage<16>(vr, vi, lane);
    fwd64_stage<8>(vr, vi, lane);
    fwd64_stage<4>(vr, vi, lane);
    fwd64_stage<2>(vr, vi, lane);
    fwd64_stage<1>(vr, vi, lane);
    midtw<-1>(vr, vi, lane);
    dft32<-1>(vr, vi);
}

// psi = Re(conv(Q, Kprefix)) * rsqrt(t+1) / 2048^1.5 -> bf16. One wave per (b,t).
__global__ __launch_bounds__(256) void psi_wfft_kernel(const bf16* __restrict__ qcat,
                                                       const float* __restrict__ KP,
                                                       bf16* __restrict__ psi_b) {
    int wid = threadIdx.x >> 6, lane = threadIdx.x & 63;
    int bt = blockIdx.x * 4 + wid;
    int t = bt & 127;

    float kr[32], ki[32];
    const float* kpr = KP + (long)bt * M_ + 32 * lane;
    const float* kpi = kpr + (long)BT_ * M_;
    #pragma unroll
    for (int u = 0; u < 8; ++u) {
        float4 a = *(const float4*)(kpr + 4 * u);
        kr[4 * u] = a.x; kr[4 * u + 1] = a.y; kr[4 * u + 2] = a.z; kr[4 * u + 3] = a.w;
        float4 b = *(const float4*)(kpi + 4 * u);
        ki[4 * u] = b.x; ki[4 * u + 1] = b.y; ki[4 * u + 2] = b.z; ki[4 * u + 3] = b.w;
    }
    fwd2048(kr, ki, lane);

    float qr[32], qi[32];
    const unsigned short* qp = (const unsigned short*)(qcat + (long)bt * 4096 + 32 * lane);
    #pragma unroll
    for (int u = 0; u < 4; ++u) {
        ushort8t a = *(const ushort8t*)(qp + 8 * u);
        ushort8t b = *(const ushort8t*)(qp + 2048 + 8 * u);
        #pragma unroll
        for (int j = 0; j < 8; ++j) {
            qr[8 * u + j] = __uint_as_float(((unsigned int)a[j]) << 16);
            qi[8 * u + j] = __uint_as_float(((unsigned int)b[j]) << 16);
        }
    }
    fwd2048(qr, qi, lane);

    #pragma unroll
    for (int n = 0; n < 32; ++n) cxmul(qr[n], qi[n], kr[n], ki[n]);

    dft32<1>(qr, qi);
    midtw<1>(qr, qi, lane);
    inv64_stage<1>(qr, qi, lane);
    inv64_stage<2>(qr, qi, lane);
    inv64_stage<4>(qr, qi, lane);
    inv64_stage<8>(qr, qi, lane);
    inv64_stage<16>(qr, qi, lane);
    inv64_stage<32>(qr, qi, lane);

    float scale = rsqrtf((float)(t + 1)) * (1.0f / 92681.900089f);   // 1/2048^1.5
    unsigned short* op = (unsigned short*)(psi_b + (long)bt * M_ + 32 * lane);
    #pragma unroll
    for (int u = 0; u < 4; ++u) {
        ushort8t o;
        #pragma unroll
        for (int j = 0; j < 8; ++j) {
            bf16 hv = __float2bfloat16(qr[8 * u + j] * scale);
            o[j] = *(unsigned short*)&hv;
        }
        *(ushort8t*)(op + 8 * u) = o;
    }
}

// MFMA bf16 TN GEMM: C[M,N] = A[M,K] * Bt[N,K]^T. 64x64 tile, 4 waves.
template<int FLAGS, int OUTB16>
__global__ __launch_bounds__(256) void gemm_mfma(
    const bf16* __restrict__ A, const bf16* __restrict__ Bt,
    const float* __restrict__ bias, void* __restrict__ Cv,
    int K, int ldc, long abz, long bbz, long cbz, int splitk)
{
    __shared__ __align__(16) bf16 As[64][44];
    __shared__ __align__(16) bf16 Bs[64][44];
    int bz = blockIdx.z;
    int batch = bz, kslice = 0;
    if (FLAGS & FLAG_ATOMIC) { batch = bz / splitk; kslice = bz % splitk; }
    const bf16* Ab;
    const bf16* Bb;
    long coff;
    if (FLAGS & FLAG_HFB) {
        int b = bz & 7, c = bz >> 3;
        Ab = A + (long)b * abz + (long)blockIdx.y * 64 * K;
        Bb = Bt + (long)c * 2097152L + (long)b * 262144L + (long)blockIdx.x * 64 * K;
        coff = (long)b * 2097152L + (long)c * 1048576L;
    } else {
        Ab = A + (long)batch * abz + (long)blockIdx.y * 64 * K;
        Bb = Bt + (long)batch * bbz + (long)blockIdx.x * 64 * K;
        coff = (long)batch * cbz;
    }
    int tid = threadIdx.x;
    int lrow = tid >> 2;
    int lk = (tid & 3) * 8;
    int w = tid >> 6, lane = tid & 63;
    int wr = (w >> 1) * 32, wc = (w & 1) * 32;
    int fm = lane & 15, fk = (lane >> 4) * 8;
    f32x4 acc00 = {0.f,0.f,0.f,0.f}, acc01 = acc00, acc10 = acc00, acc11 = acc00;

    int klen = K / splitk;
    int k0 = kslice * klen;
    for (int kt = k0; kt < k0 + klen; kt += 32) {
        *(float4*)&As[lrow][lk] = *(const float4*)&Ab[(long)lrow * K + kt + lk];
        *(float4*)&Bs[lrow][lk] = *(const float4*)&Bb[(long)lrow * K + kt + lk];
        __syncthreads();
        short8t a0 = *(const short8t*)&As[wr + fm][fk];
        short8t a1 = *(const short8t*)&As[wr + 16 + fm][fk];
        short8t b0 = *(const short8t*)&Bs[wc + fm][fk];
        short8t b1 = *(const short8t*)&Bs[wc + 16 + fm][fk];
        acc00 = __builtin_amdgcn_mfma_f32_16x16x32_bf16(a0, b0, acc00, 0, 0, 0);
        acc01 = __builtin_amdgcn_mfma_f32_16x16x32_bf16(a0, b1, acc01, 0, 0, 0);
        acc10 = __builtin_amdgcn_mfma_f32_16x16x32_bf16(a1, b0, acc10, 0, 0, 0);
        acc11 = __builtin_amdgcn_mfma_f32_16x16x32_bf16(a1, b1, acc11, 0, 0, 0);
        __syncthreads();
    }

    float* Cf = (float*)Cv;
    bf16* Cb = (bf16*)Cv;
    int row_base = blockIdx.y * 64 + wr + (lane >> 4) * 4;
    int col_base = blockIdx.x * 64 + wc + fm;
    #pragma unroll
    for (int fr = 0; fr < 2; ++fr) {
        #pragma unroll
        for (int fc = 0; fc < 2; ++fc) {
            const f32x4& a = fr == 0 ? (fc == 0 ? acc00 : acc01) : (fc == 0 ? acc10 : acc11);
            #pragma unroll
            for (int r = 0; r < 4; ++r) {
                int gi = row_base + fr * 16 + r;
                int gj = col_base + fc * 16;
                float v = a[r];
                long ci = coff + (long)gi * ldc + gj;
                if (FLAGS & FLAG_ATOMIC) {
                    atomicAdd(&Cf[ci], v);
                } else {
                    if (FLAGS & FLAG_BIAS) v += bias[gj];
                    if (FLAGS & FLAG_GELU) v = gelu_f(v);
                    if (FLAGS & FLAG_ROWSCALE) v *= rsqrtf((float)(gi & 127) + 1.0f);
                    if (FLAGS & FLAG_MASK) { if (gj >= gi) v = 0.f; }
                    if (OUTB16) Cb[ci] = __float2bfloat16(v);
                    else        Cf[ci] = v;
                }
            }
        }
    }
}

// scores epilogue: mask upper triangle (tau >= t) and cast to bf16
__global__ __launch_bounds__(256) void scomask_kernel(const float* __restrict__ acc,
                                                      bf16* __restrict__ scob) {
    int idx = blockIdx.x * 256 + threadIdx.x;   // 8*128*128
    int t = (idx >> 7) & 127, tau = idx & 127;
    float v = (tau < t) ? acc[idx] : 0.f;
    scob[idx] = __float2bfloat16(v);
}

// LN over D=512. FINAL=0: LN(x1); FINAL=1: LN(x1 + gf*x2 + gv*x3). OB16 selects out dtype.
template<int FINAL, int OB16>
__global__ __launch_bounds__(256) void ln_kernel(const float* __restrict__ x1,
                                                 const float* __restrict__ x2,
                                                 const float* __restrict__ x3,
                                                 const float* __restrict__ g,
                                                 const float* __restrict__ bb,
                                                 const float* __restrict__ scal,
                                                 void* __restrict__ outv) {
    int row = blockIdx.x, tid = threadIdx.x;
    long base = (long)row * D_;
    int d0 = tid, d1 = tid + 256;
    float v0, v1;
    if (FINAL) {
        float gf = scal[3], gv = scal[4];
        v0 = x1[base + d0] + gf * x2[base + d0] + gv * x3[base + d0];
        v1 = x1[base + d1] + gf * x2[base + d1] + gv * x3[base + d1];
    } else {
        v0 = x1[base + d0];
        v1 = x1[base + d1];
    }
    float s = v0 + v1;
    #pragma unroll
    for (int o = 32; o > 0; o >>= 1) s += __shfl_down(s, o);
    __shared__ float red[8];
    int wid = tid >> 6, lane = tid & 63;
    if (lane == 0) red[wid] = s;
    __syncthreads();
    float mu = (red[0] + red[1] + red[2] + red[3]) * (1.0f / D_);
    float e0 = v0 - mu, e1 = v1 - mu;
    float sq = e0 * e0 + e1 * e1;
    #pragma unroll
    for (int o = 32; o > 0; o >>= 1) sq += __shfl_down(sq, o);
    if (lane == 0) red[4 + wid] = sq;
    __syncthreads();
    float var = (red[4] + red[5] + red[6] + red[7]) * (1.0f / D_);
    float rs = rsqrtf(var + 1e-5f);
    float o0 = e0 * rs * g[d0] + bb[d0];
    float o1 = e1 * rs * g[d1] + bb[d1];
    if (OB16) {
        ((bf16*)outv)[base + d0] = __float2bfloat16(o0);
        ((bf16*)outv)[base + d1] = __float2bfloat16(o1);
    } else {
        ((float*)outv)[base + d0] = o0;
        ((float*)outv)[base + d1] = o1;
    }
}

extern "C" void kernel_launch(void* const* d_in, const int* in_sizes, int n_in,
                              void* d_out, int out_size, void* d_ws, size_t ws_size,
                              hipStream_t stream) {
    const float* e      = (const float*)d_in[0];
    const int*   h      = (const int*)d_in[1];
    const float* sign   = (const float*)d_in[2];
    const float* Wq     = (const float*)d_in[3];
    const float* Wk     = (const float*)d_in[4];
    const float* Wv     = (const float*)d_in[5];
    const float* ro_w1  = (const float*)d_in[6];
    const float* ro_b1  = (const float*)d_in[7];
    const float* ro_w2  = (const float*)d_in[8];
    const float* ro_b2  = (const float*)d_in[9];
    const float* vp_ln_g= (const float*)d_in[10];
    const float* vp_ln_b= (const float*)d_in[11];
    const float* vp_w1  = (const float*)d_in[12];
    const float* vp_b1  = (const float*)d_in[13];
    const float* vp_w2  = (const float*)d_in[14];
    const float* vp_b2  = (const float*)d_in[15];
    const float* ln_g   = (const float*)d_in[16];
    const float* ln_b   = (const float*)d_in[17];
    const float* tq     = (const float*)d_in[18];
    const float* tk     = (const float*)d_in[19];
    const float* om     = (const float*)d_in[20];
    const float* gfr    = (const float*)d_in[21];
    const float* gvr    = (const float*)d_in[22];

    float* ws    = (float*)d_ws;
    float* scal  = ws + OFF_SCAL;
    float* qkv   = ws + OFF_QKV;
    float* sk2   = ws + OFF_SK2;
    float* kp    = ws + OFF_KP;
    float* vraw  = ws + OFF_VRAW;
    float* vf    = ws + OFF_VF;
    float* hfeat = ws + OFF_HFEAT;
    float* scoacc= ws + OFF_SCOA;
    float* qsum  = ws + OFF_QSUM;
    bf16* eb    = (bf16*)(ws + OFF_EB);
    bf16* wqkvT = (bf16*)(ws + OFF_WQKVT);
    bf16* vp1T  = (bf16*)(ws + OFF_VP1T);
    bf16* vp2T  = (bf16*)(ws + OFF_VP2T);
    bf16* ro1T  = (bf16*)(ws + OFF_RO1T);
    bf16* ro2T  = (bf16*)(ws + OFF_RO2T);
    bf16* qcat  = (bf16*)(ws + OFF_QCAT);
    bf16* kcat  = (bf16*)(ws + OFF_KCAT);
    bf16* dkT   = (bf16*)(ws + OFF_DKT);
    bf16* vTb   = (bf16*)(ws + OFF_VTB);
    bf16* psib  = (bf16*)(ws + OFF_PSIB);
    bf16* scob  = (bf16*)(ws + OFF_SCOB);
    bf16* vlnb  = (bf16*)(ws + OFF_VLNB);
    bf16* v1b   = (bf16*)(ws + OFF_V1B);
    bf16* hidb  = (bf16*)(ws + OFF_HIDB);

    float* ys = (float*)d_out;
    float* kf = ys + (long)BT_ * D_;
    float* hf = kf + (long)B_ * 2 * M_;

    scal_kernel<<<1, 64, 0, stream>>>(tq, tk, om, gfr, gvr, scal);
    hipMemsetAsync(scoacc, 0, (size_t)B_ * T_ * T_ * 4, stream);

    // bf16 operand prep
    cast_kernel<<<2048, 256, 0, stream>>>(e, eb, BT_ * D_);
    castT5_kernel<<<dim3(16, 16, 5), 256, 0, stream>>>(
        Wq, Wk, Wv, vp_w1, vp_w2,
        wqkvT, wqkvT + 262144, wqkvT + 524288, vp1T, vp2T);
    castT_kernel<<<dim3(4, 64, 1), 256, 0, stream>>>(ro_w1, ro1T, 2048, 128, 128, 0, 0);
    castT_kernel<<<dim3(16, 4, 1), 256, 0, stream>>>(ro_w2, ro2T,  128, 512, 512, 0, 0);

    // qkv = e @ [Wq|Wk|Wv]  (1024 x 1536 x 512) -> f32
    gemm_mfma<0, 0><<<dim3(24, 16, 1), 256, 0, stream>>>(
        eb, wqkvT, nullptr, qkv, 512, 1536, 0, 0, 0, 1);

    sketch_kernel<<<1024, 256, 0, stream>>>(qkv, sign, scal, h, sk2, qcat, kcat);
    prefix_p1<<<512, 256, 0, stream>>>(sk2, qsum);
    prefix_p2<<<512, 256, 0, stream>>>(sk2, qsum, kp, kf);

    // psi via wave-level register FFT (one wave per (b,t))
    psi_wfft_kernel<<<256, 256, 0, stream>>>(qcat, kp, psib);

    // transposed bf16 copies (fused: z = comp*8 + b works because comp stride = 8*b stride)
    castT_kernel<<<dim3(64, 4, 16), 256, 0, stream>>>(sk2, dkT, 128, 2048, 2048, 262144, 262144);
    castT_kernel<<<dim3(16, 4, 8), 256, 0, stream>>>(qkv + 1024, vTb, 128, 512, 1536, 196608, 65536);

    // scores: split-K 16, f32 atomic accumulate (grid 2x2x128 = 512 blocks)
    gemm_mfma<FLAG_ATOMIC, 0><<<dim3(2, 2, 128), 256, 0, stream>>>(
        qcat, kcat, nullptr, scoacc, 4096, 128, 524288, 524288, 16384, 16);
    scomask_kernel<<<512, 256, 0, stream>>>(scoacc, scob);

    // vraw[b] = scores @ v * rsqrt(t+1)  (128x512x128) -> f32
    gemm_mfma<FLAG_ROWSCALE, 0><<<dim3(8, 2, 8), 256, 0, stream>>>(
        scob, vTb, nullptr, vraw, 128, 512, 16384, 65536, 65536, 1);

    ln_kernel<0, 1><<<1024, 256, 0, stream>>>(vraw, nullptr, nullptr, vp_ln_g, vp_ln_b, scal, vlnb);

    // vp MLP
    gemm_mfma<FLAG_BIAS | FLAG_GELU, 1><<<dim3(8, 16, 1), 256, 0, stream>>>(
        vlnb, vp1T, vp_b1, v1b, 512, 512, 0, 0, 0, 1);
    gemm_mfma<FLAG_BIAS, 0><<<dim3(8, 16, 1), 256, 0, stream>>>(
        v1b, vp2T, vp_b2, vf, 512, 512, 0, 0, 0, 1);

    // hid = gelu(psi @ ro_w1 + b1) (1024x128x2048) -> bf16
    gemm_mfma<FLAG_BIAS | FLAG_GELU, 1><<<dim3(2, 16, 1), 256, 0, stream>>>(
        psib, ro1T, ro_b1, hidb, 2048, 128, 0, 0, 0, 1);
    // hfeat = hid @ ro_w2 + b2 (1024x512x128)
    gemm_mfma<FLAG_BIAS, 0><<<dim3(8, 16, 1), 256, 0, stream>>>(
        hidb, ro2T, ro_b2, hfeat, 128, 512, 0, 0, 0, 1);

    // ys = LN(e + gf*hfeat + gv*vf)
    ln_kernel<1, 0><<<1024, 256, 0, stream>>>(e, hfeat, vf, ln_g, ln_b, scal, ys);

    // Hf fused: z in [0,16), b=z&7, c=z>>3
    gemm_mfma<FLAG_HFB, 0><<<dim3(32, 8, 16), 256, 0, stream>>>(
        vTb, dkT, nullptr, hf, 128, 2048, 65536, 0, 0, 1);
}

// Round 7
// 191.499 us; speedup vs baseline: 1.6077x; 1.6077x over previous
//
#include <hip/hip_runtime.h>
#include <hip/hip_bf16.h>
#include <math.h>

#define B_   8
#define T_   128
#define D_   512
#define M_   2048
#define HID_ 128
#define BT_  1024

typedef __attribute__((ext_vector_type(8))) short short8t;
typedef __attribute__((ext_vector_type(4))) float f32x4;
typedef __hip_bfloat16 bf16;

// ws layout (float offsets; all multiples of 16 -> 64B aligned)
#define OFF_SCAL   0L
#define OFF_QKV    16L                            // 1024*1536 f32
#define OFF_SK2    (OFF_QKV + 1572864L)           // [dKre|dKim] f32, 2*BT*M
#define OFF_KP     (OFF_SK2 + 4194304L)           // [KR|KI] f32 exclusive prefix
#define OFF_VRAW   (OFF_KP + 4194304L)
#define OFF_VF     (OFF_VRAW + 524288L)
#define OFF_HFEAT  (OFF_VF + 524288L)
// bf16 buffers (size in floats = elems/2)
#define OFF_EB     (OFF_HFEAT + 524288L)          // 1024x512
#define OFF_WQKVT  (OFF_EB + 262144L)             // 1536x512
#define OFF_VP1T   (OFF_WQKVT + 393216L)          // 512x512
#define OFF_VP2T   (OFF_VP1T + 131072L)
#define OFF_RO2T   (OFF_VP2T + 131072L)           // 512x128
#define OFF_QCAT   (OFF_RO2T + 32768L)            // 1024x4096
#define OFF_KCAT   (OFF_QCAT + 2097152L)          // 1024x4096
#define OFF_DKT    (OFF_KCAT + 2097152L)          // 2x8x2048x128
#define OFF_VTB    (OFF_DKT + 2097152L)           // 8x512x128
#define OFF_SCOB   (OFF_VTB + 262144L)            // 8x128x128 bf16
#define OFF_VLNB   (OFF_SCOB + 65536L)            // 1024x512
#define OFF_V1B    (OFF_VLNB + 262144L)           // 1024x512
#define OFF_HIDB   (OFF_V1B + 262144L)            // 1024x128
#define OFF_SCOA   (OFF_HIDB + 65536L)            // 8x128x128 f32 split-K accumulator
#define OFF_QSUM   (OFF_SCOA + 131072L)           // 4x32768 f32 prefix quarter sums
#define OFF_PCAT   (OFF_QSUM + 131072L)           // 1024x4096 bf16 [ReP|ImP]
#define OFF_RO1F   (OFF_PCAT + 2097152L)          // 128x4096 bf16 [ReG|ImG]
#define OFF_HACC   (OFF_RO1F + 262144L)           // 1024x128 f32

#define FLAG_BIAS     1
#define FLAG_GELU     2
#define FLAG_ROWSCALE 4
#define FLAG_ATOMIC   8
#define FLAG_MASK     16
#define FLAG_HFB      32

__device__ __forceinline__ float gelu_f(float x) {
    return 0.5f * x * (1.0f + erff(x * 0.70710678118654752440f));
}

__global__ void scal_kernel(const float* tq, const float* tk, const float* om,
                            const float* gf, const float* gv, float* scal) {
    if (threadIdx.x == 0) {
        scal[0] = 0.5f * tanhf(tq[0]);
        scal[1] = 0.5f * tanhf(tk[0]);
        scal[2] = 0.5f * tanhf(om[0]);
        scal[3] = 0.25f / (1.0f + expf(-gf[0]));
        scal[4] = 0.25f / (1.0f + expf(-gv[0]));
    }
}

__global__ __launch_bounds__(256) void cast_kernel(const float* __restrict__ in,
                                                   bf16* __restrict__ out, int n) {
    int i = blockIdx.x * 256 + threadIdx.x;
    if (i < n) out[i] = __float2bfloat16(in[i]);
}

// tiled transpose-cast: in f32 [R][C] (ld_in, batch bs_in) -> out bf16 [C][R] (batch bs_out)
__global__ __launch_bounds__(256) void castT_kernel(const float* __restrict__ in,
                                                    bf16* __restrict__ out,
                                                    int R, int C, int ld_in,
                                                    long bs_in, long bs_out) {
    __shared__ float tile[32][33];
    int b = blockIdx.z;
    int c0 = blockIdx.x * 32, r0 = blockIdx.y * 32;
    int tx = threadIdx.x & 31, ty = threadIdx.x >> 5;
    for (int rr = ty; rr < 32; rr += 8) {
        int r = r0 + rr, c = c0 + tx;
        tile[rr][tx] = (r < R && c < C) ? in[(long)b * bs_in + (long)r * ld_in + c] : 0.f;
    }
    __syncthreads();
    for (int cc = ty; cc < 32; cc += 8) {
        int c = c0 + cc, r = r0 + tx;
        if (c < C && r < R) out[(long)b * bs_out + (long)c * R + r] = __float2bfloat16(tile[tx][cc]);
    }
}

// batched 512x512 transpose-cast for 5 weights in one launch
__global__ __launch_bounds__(256) void castT5_kernel(const float* w0, const float* w1,
                                                     const float* w2, const float* w3,
                                                     const float* w4,
                                                     bf16* d0, bf16* d1, bf16* d2,
                                                     bf16* d3, bf16* d4) {
    __shared__ float tile[32][33];
    int z = blockIdx.z;
    const float* src; bf16* dst;
    if (z == 0)      { src = w0; dst = d0; }
    else if (z == 1) { src = w1; dst = d1; }
    else if (z == 2) { src = w2; dst = d2; }
    else if (z == 3) { src = w3; dst = d3; }
    else             { src = w4; dst = d4; }
    int c0 = blockIdx.x * 32, r0 = blockIdx.y * 32;
    int tx = threadIdx.x & 31, ty = threadIdx.x >> 5;
    for (int rr = ty; rr < 32; rr += 8)
        tile[rr][tx] = src[(long)(r0 + rr) * 512 + c0 + tx];
    __syncthreads();
    for (int cc = ty; cc < 32; cc += 8)
        dst[(long)(c0 + cc) * 512 + r0 + tx] = __float2bfloat16(tile[tx][cc]);
}

// sketch (phase fused): SK2 f32 = [dKre|dKim]; qcat bf16 = [Qre|Qim]; kcat bf16 = [dKre|-dKim]
__global__ __launch_bounds__(256) void sketch_kernel(const float* __restrict__ qkv,
                                                     const float* __restrict__ sign,
                                                     const float* __restrict__ scal,
                                                     const int* __restrict__ h,
                                                     float* __restrict__ SK2,
                                                     bf16* __restrict__ qcat,
                                                     bf16* __restrict__ kcat) {
    int bt = blockIdx.x;
    int tid = threadIdx.x;
    __shared__ float s0[M_], s1[M_], s2[M_], s3[M_];
    for (int j = tid; j < M_; j += 256) { s0[j] = 0.f; s1[j] = 0.f; s2[j] = 0.f; s3[j] = 0.f; }
    __syncthreads();
    int t = bt & 127;
    float thq = scal[0], thk = scal[1], omg = scal[2];
    float ft = (float)t;
    for (int i = tid; i < D_; i += 256) {
        float q = qkv[(long)bt * 1536 + i];
        float k = qkv[(long)bt * 1536 + 512 + i];
        float sg = sign[i];
        float sq_, cq_, sk_, ck_;
        sincosf(thq * q - omg * ft, &sq_, &cq_);
        sincosf(thk * k + omg * ft, &sk_, &ck_);
        int m = h[i];
        atomicAdd(&s0[m], q * cq_ * sg);
        atomicAdd(&s1[m], q * sq_ * sg);
        atomicAdd(&s2[m], k * ck_ * sg);
        atomicAdd(&s3[m], k * sk_ * sg);
    }
    __syncthreads();
    long ob = (long)bt * M_;
    long qb = (long)bt * 4096;
    for (int j = tid; j < M_; j += 256) {
        SK2[ob + j]                  = s2[j];
        SK2[(long)BT_ * M_ + ob + j] = s3[j];
        qcat[qb + j]        = __float2bfloat16(s0[j]);
        qcat[qb + 2048 + j] = __float2bfloat16(s1[j]);
        kcat[qb + j]        = __float2bfloat16(s2[j]);
        kcat[qb + 2048 + j] = __float2bfloat16(-s3[j]);
    }
}

// ---- two-phase exclusive prefix over t (4-way t split) ----
__global__ __launch_bounds__(256) void prefix_p1(const float* __restrict__ SK2,
                                                 float* __restrict__ qsum) {
    int idx = blockIdx.x * 256 + threadIdx.x;   // 131072
    int col = idx & 32767, q = idx >> 15;
    int m = col & 2047, b = (col >> 11) & 7, comp = col >> 14;
    const float* src = SK2 + (long)comp * BT_ * M_ + (long)b * T_ * M_ + (long)(q * 32) * M_ + m;
    float s = 0.f;
    #pragma unroll 8
    for (int i = 0; i < 32; ++i) s += src[(long)i * M_];
    qsum[(long)q * 32768 + col] = s;
}

__global__ __launch_bounds__(256) void prefix_p2(const float* __restrict__ SK2,
                                                 const float* __restrict__ qsum,
                                                 float* __restrict__ KP,
                                                 float* __restrict__ kf_out) {
    int idx = blockIdx.x * 256 + threadIdx.x;   // 131072
    int col = idx & 32767, q = idx >> 15;
    int m = col & 2047, b = (col >> 11) & 7, comp = col >> 14;
    long cb = (long)comp * BT_ * M_ + (long)b * T_ * M_ + m + (long)(q * 32) * M_;
    const float* src = SK2 + cb;
    float* dst = KP + cb;
    float acc = 0.f;
    for (int p = 0; p < q; ++p) acc += qsum[(long)p * 32768 + col];
    #pragma unroll 4
    for (int i = 0; i < 32; ++i) {
        dst[(long)i * M_] = acc;
        acc += src[(long)i * M_];
    }
    if (q == 3) kf_out[((long)b * 2 + comp) * M_ + m] = acc;
}

// ==== in-place radix-2 DIF forward FFT (scrambled/bit-rev output; order cancels
// because the frequency-domain GEMM B-operand uses the identical scramble) ====
#define PIDX(i) ((i) + ((i) >> 5))

// one DIF stage on two complex arrays (shared twiddle)
template<int M>
__device__ __forceinline__ void dif_pair(float* r0, float* i0_, float* r1, float* i1_, int tid) {
    #pragma unroll
    for (int u = 0; u < 4; ++u) {
        int q = u * 256 + tid;
        int k = q & (M - 1);
        int i = (q / M) * (2 * M) + k;
        float s, c;
        sincosf((float)k * (3.14159265358979323846f / (float)M), &s, &c);
        int p0 = PIDX(i), p1 = PIDX(i + M);
        {
            float ar = r0[p0], ai = i0_[p0], br = r0[p1], bi = i0_[p1];
            r0[p0] = ar + br; i0_[p0] = ai + bi;
            float dr = ar - br, di = ai - bi;
            r0[p1] = dr * c + di * s;    // (dr + i di) * (c - i s)
            i0_[p1] = di * c - dr * s;
        }
        {
            float ar = r1[p0], ai = i1_[p0], br = r1[p1], bi = i1_[p1];
            r1[p0] = ar + br; i1_[p0] = ai + bi;
            float dr = ar - br, di = ai - bi;
            r1[p1] = dr * c + di * s;
            i1_[p1] = di * c - dr * s;
        }
    }
}

template<int M>
__device__ __forceinline__ void dif_one(float* re, float* im, int tid) {
    #pragma unroll
    for (int u = 0; u < 4; ++u) {
        int q = u * 256 + tid;
        int k = q & (M - 1);
        int i = (q / M) * (2 * M) + k;
        float s, c;
        sincosf((float)k * (3.14159265358979323846f / (float)M), &s, &c);
        int p0 = PIDX(i), p1 = PIDX(i + M);
        float ar = re[p0], ai = im[p0], br = re[p1], bi = im[p1];
        re[p0] = ar + br; im[p0] = ai + bi;
        float dr = ar - br, di = ai - bi;
        re[p1] = dr * c + di * s;
        im[p1] = di * c - dr * s;
    }
}

// forward FFTs of Q sketch and K prefix; pcat = [Re(FQ*FK) | Im(FQ*FK)] bf16 (scrambled order)
__global__ __launch_bounds__(256) void fwdfft_kernel(const bf16* __restrict__ qcat,
                                                     const float* __restrict__ KP,
                                                     bf16* __restrict__ pcat) {
    __shared__ float KRs[2112], KIs[2112], QRs[2112], QIs[2112];   // 33 KB
    int bt = blockIdx.x, tid = threadIdx.x;
    const unsigned short* qp = (const unsigned short*)(qcat + (long)bt * 4096);
    for (int u = 0; u < 8; ++u) {
        int j = u * 256 + tid;
        int pj = PIDX(j);
        KRs[pj] = KP[(long)bt * M_ + j];
        KIs[pj] = KP[(long)BT_ * M_ + (long)bt * M_ + j];
        QRs[pj] = __uint_as_float(((unsigned int)qp[j]) << 16);
        QIs[pj] = __uint_as_float(((unsigned int)qp[2048 + j]) << 16);
    }
    __syncthreads();
#define FSTEP(MM) dif_pair<MM>(KRs, KIs, QRs, QIs, tid); __syncthreads();
    FSTEP(1024) FSTEP(512) FSTEP(256) FSTEP(128) FSTEP(64)
    FSTEP(32) FSTEP(16) FSTEP(8) FSTEP(4) FSTEP(2) FSTEP(1)
#undef FSTEP
    unsigned short* op = (unsigned short*)(pcat + (long)bt * 4096);
    for (int u = 0; u < 8; ++u) {
        int j = u * 256 + tid;
        int pj = PIDX(j);
        float ar = QRs[pj], ai = QIs[pj], br = KRs[pj], bi = KIs[pj];
        bf16 re = __float2bfloat16(ar * br - ai * bi);
        bf16 im = __float2bfloat16(ar * bi + ai * br);
        op[j]        = *(unsigned short*)&re;
        op[2048 + j] = *(unsigned short*)&im;
    }
}

// Ghat for column j of ro_w1: ro1f[j] = [Re FFT | Im FFT] (scrambled, same DIF) bf16
// (hid_pre[j] = Re(sum_m P[m]*conj(F)[m]) = sum ReP*ReF + ImP*ImF)
__global__ __launch_bounds__(256) void ro1fft_kernel(const float* __restrict__ ro_w1,
                                                     bf16* __restrict__ ro1f) {
    __shared__ float Rs[2112], Is[2112];
    int j = blockIdx.x, tid = threadIdx.x;
    for (int u = 0; u < 8; ++u) {
        int n = u * 256 + tid;
        Rs[PIDX(n)] = ro_w1[(long)n * HID_ + j];
        Is[PIDX(n)] = 0.f;
    }
    __syncthreads();
#define FSTEP(MM) dif_one<MM>(Rs, Is, tid); __syncthreads();
    FSTEP(1024) FSTEP(512) FSTEP(256) FSTEP(128) FSTEP(64)
    FSTEP(32) FSTEP(16) FSTEP(8) FSTEP(4) FSTEP(2) FSTEP(1)
#undef FSTEP
    unsigned short* op = (unsigned short*)(ro1f + (long)j * 4096);
    for (int u = 0; u < 8; ++u) {
        int r = u * 256 + tid;
        int pr = PIDX(r);
        bf16 re = __float2bfloat16(Rs[pr]);
        bf16 im = __float2bfloat16(Is[pr]);
        op[r]        = *(unsigned short*)&re;
        op[2048 + r] = *(unsigned short*)&im;
    }
}

// hid epilogue: hid = gelu(hacc * scale(t) + b1) -> bf16
__global__ __launch_bounds__(256) void hidgelu_kernel(const float* __restrict__ hacc,
                                                      const float* __restrict__ b1,
                                                      bf16* __restrict__ hidb) {
    int idx = blockIdx.x * 256 + threadIdx.x;   // 131072
    int j = idx & 127;
    int t = (idx >> 7) & 127;
    float scale = rsqrtf((float)(t + 1)) * (1.0f / 92681.900089f);   // 1/2048^1.5
    hidb[idx] = __float2bfloat16(gelu_f(hacc[idx] * scale + b1[j]));
}

// MFMA bf16 TN GEMM: C[M,N] = A[M,K] * Bt[N,K]^T. 64x64 tile, 4 waves.
template<int FLAGS, int OUTB16>
__global__ __launch_bounds__(256) void gemm_mfma(
    const bf16* __restrict__ A, const bf16* __restrict__ Bt,
    const float* __restrict__ bias, void* __restrict__ Cv,
    int K, int ldc, long abz, long bbz, long cbz, int splitk)
{
    __shared__ __align__(16) bf16 As[64][44];
    __shared__ __align__(16) bf16 Bs[64][44];
    int bz = blockIdx.z;
    int batch = bz, kslice = 0;
    if (FLAGS & FLAG_ATOMIC) { batch = bz / splitk; kslice = bz % splitk; }
    const bf16* Ab;
    const bf16* Bb;
    long coff;
    if (FLAGS & FLAG_HFB) {
        int b = bz & 7, c = bz >> 3;
        Ab = A + (long)b * abz + (long)blockIdx.y * 64 * K;
        Bb = Bt + (long)c * 2097152L + (long)b * 262144L + (long)blockIdx.x * 64 * K;
        coff = (long)b * 2097152L + (long)c * 1048576L;
    } else {
        Ab = A + (long)batch * abz + (long)blockIdx.y * 64 * K;
        Bb = Bt + (long)batch * bbz + (long)blockIdx.x * 64 * K;
        coff = (long)batch * cbz;
    }
    int tid = threadIdx.x;
    int lrow = tid >> 2;
    int lk = (tid & 3) * 8;
    int w = tid >> 6, lane = tid & 63;
    int wr = (w >> 1) * 32, wc = (w & 1) * 32;
    int fm = lane & 15, fk = (lane >> 4) * 8;
    f32x4 acc00 = {0.f,0.f,0.f,0.f}, acc01 = acc00, acc10 = acc00, acc11 = acc00;

    int klen = K / splitk;
    int k0 = kslice * klen;
    for (int kt = k0; kt < k0 + klen; kt += 32) {
        *(float4*)&As[lrow][lk] = *(const float4*)&Ab[(long)lrow * K + kt + lk];
        *(float4*)&Bs[lrow][lk] = *(const float4*)&Bb[(long)lrow * K + kt + lk];
        __syncthreads();
        short8t a0 = *(const short8t*)&As[wr + fm][fk];
        short8t a1 = *(const short8t*)&As[wr + 16 + fm][fk];
        short8t b0 = *(const short8t*)&Bs[wc + fm][fk];
        short8t b1 = *(const short8t*)&Bs[wc + 16 + fm][fk];
        acc00 = __builtin_amdgcn_mfma_f32_16x16x32_bf16(a0, b0, acc00, 0, 0, 0);
        acc01 = __builtin_amdgcn_mfma_f32_16x16x32_bf16(a0, b1, acc01, 0, 0, 0);
        acc10 = __builtin_amdgcn_mfma_f32_16x16x32_bf16(a1, b0, acc10, 0, 0, 0);
        acc11 = __builtin_amdgcn_mfma_f32_16x16x32_bf16(a1, b1, acc11, 0, 0, 0);
        __syncthreads();
    }

    float* Cf = (float*)Cv;
    bf16* Cb = (bf16*)Cv;
    int row_base = blockIdx.y * 64 + wr + (lane >> 4) * 4;
    int col_base = blockIdx.x * 64 + wc + fm;
    #pragma unroll
    for (int fr = 0; fr < 2; ++fr) {
        #pragma unroll
        for (int fc = 0; fc < 2; ++fc) {
            const f32x4& a = fr == 0 ? (fc == 0 ? acc00 : acc01) : (fc == 0 ? acc10 : acc11);
            #pragma unroll
            for (int r = 0; r < 4; ++r) {
                int gi = row_base + fr * 16 + r;
                int gj = col_base + fc * 16;
                float v = a[r];
                long ci = coff + (long)gi * ldc + gj;
                if (FLAGS & FLAG_ATOMIC) {
                    atomicAdd(&Cf[ci], v);
                } else {
                    if (FLAGS & FLAG_BIAS) v += bias[gj];
                    if (FLAGS & FLAG_GELU) v = gelu_f(v);
                    if (FLAGS & FLAG_ROWSCALE) v *= rsqrtf((float)(gi & 127) + 1.0f);
                    if (FLAGS & FLAG_MASK) { if (gj >= gi) v = 0.f; }
                    if (OUTB16) Cb[ci] = __float2bfloat16(v);
                    else        Cf[ci] = v;
                }
            }
        }
    }
}

// scores epilogue: mask upper triangle (tau >= t) and cast to bf16
__global__ __launch_bounds__(256) void scomask_kernel(const float* __restrict__ acc,
                                                      bf16* __restrict__ scob) {
    int idx = blockIdx.x * 256 + threadIdx.x;   // 8*128*128
    int t = (idx >> 7) & 127, tau = idx & 127;
    float v = (tau < t) ? acc[idx] : 0.f;
    scob[idx] = __float2bfloat16(v);
}

// LN over D=512. FINAL=0: LN(x1); FINAL=1: LN(x1 + gf*x2 + gv*x3). OB16 selects out dtype.
template<int FINAL, int OB16>
__global__ __launch_bounds__(256) void ln_kernel(const float* __restrict__ x1,
                                                 const float* __restrict__ x2,
                                                 const float* __restrict__ x3,
                                                 const float* __restrict__ g,
                                                 const float* __restrict__ bb,
                                                 const float* __restrict__ scal,
                                                 void* __restrict__ outv) {
    int row = blockIdx.x, tid = threadIdx.x;
    long base = (long)row * D_;
    int d0 = tid, d1 = tid + 256;
    float v0, v1;
    if (FINAL) {
        float gf = scal[3], gv = scal[4];
        v0 = x1[base + d0] + gf * x2[base + d0] + gv * x3[base + d0];
        v1 = x1[base + d1] + gf * x2[base + d1] + gv * x3[base + d1];
    } else {
        v0 = x1[base + d0];
        v1 = x1[base + d1];
    }
    float s = v0 + v1;
    #pragma unroll
    for (int o = 32; o > 0; o >>= 1) s += __shfl_down(s, o);
    __shared__ float red[8];
    int wid = tid >> 6, lane = tid & 63;
    if (lane == 0) red[wid] = s;
    __syncthreads();
    float mu = (red[0] + red[1] + red[2] + red[3]) * (1.0f / D_);
    float e0 = v0 - mu, e1 = v1 - mu;
    float sq = e0 * e0 + e1 * e1;
    #pragma unroll
    for (int o = 32; o > 0; o >>= 1) sq += __shfl_down(sq, o);
    if (lane == 0) red[4 + wid] = sq;
    __syncthreads();
    float var = (red[4] + red[5] + red[6] + red[7]) * (1.0f / D_);
    float rs = rsqrtf(var + 1e-5f);
    float o0 = e0 * rs * g[d0] + bb[d0];
    float o1 = e1 * rs * g[d1] + bb[d1];
    if (OB16) {
        ((bf16*)outv)[base + d0] = __float2bfloat16(o0);
        ((bf16*)outv)[base + d1] = __float2bfloat16(o1);
    } else {
        ((float*)outv)[base + d0] = o0;
        ((float*)outv)[base + d1] = o1;
    }
}

extern "C" void kernel_launch(void* const* d_in, const int* in_sizes, int n_in,
                              void* d_out, int out_size, void* d_ws, size_t ws_size,
                              hipStream_t stream) {
    const float* e      = (const float*)d_in[0];
    const int*   h      = (const int*)d_in[1];
    const float* sign   = (const float*)d_in[2];
    const float* Wq     = (const float*)d_in[3];
    const float* Wk     = (const float*)d_in[4];
    const float* Wv     = (const float*)d_in[5];
    const float* ro_w1  = (const float*)d_in[6];
    const float* ro_b1  = (const float*)d_in[7];
    const float* ro_w2  = (const float*)d_in[8];
    const float* ro_b2  = (const float*)d_in[9];
    const float* vp_ln_g= (const float*)d_in[10];
    const float* vp_ln_b= (const float*)d_in[11];
    const float* vp_w1  = (const float*)d_in[12];
    const float* vp_b1  = (const float*)d_in[13];
    const float* vp_w2  = (const float*)d_in[14];
    const float* vp_b2  = (const float*)d_in[15];
    const float* ln_g   = (const float*)d_in[16];
    const float* ln_b   = (const float*)d_in[17];
    const float* tq     = (const float*)d_in[18];
    const float* tk     = (const float*)d_in[19];
    const float* om     = (const float*)d_in[20];
    const float* gfr    = (const float*)d_in[21];
    const float* gvr    = (const float*)d_in[22];

    float* ws    = (float*)d_ws;
    float* scal  = ws + OFF_SCAL;
    float* qkv   = ws + OFF_QKV;
    float* sk2   = ws + OFF_SK2;
    float* kp    = ws + OFF_KP;
    float* vraw  = ws + OFF_VRAW;
    float* vf    = ws + OFF_VF;
    float* hfeat = ws + OFF_HFEAT;
    float* scoacc= ws + OFF_SCOA;
    float* qsum  = ws + OFF_QSUM;
    float* hacc  = ws + OFF_HACC;
    bf16* eb    = (bf16*)(ws + OFF_EB);
    bf16* wqkvT = (bf16*)(ws + OFF_WQKVT);
    bf16* vp1T  = (bf16*)(ws + OFF_VP1T);
    bf16* vp2T  = (bf16*)(ws + OFF_VP2T);
    bf16* ro2T  = (bf16*)(ws + OFF_RO2T);
    bf16* qcat  = (bf16*)(ws + OFF_QCAT);
    bf16* kcat  = (bf16*)(ws + OFF_KCAT);
    bf16* dkT   = (bf16*)(ws + OFF_DKT);
    bf16* vTb   = (bf16*)(ws + OFF_VTB);
    bf16* scob  = (bf16*)(ws + OFF_SCOB);
    bf16* vlnb  = (bf16*)(ws + OFF_VLNB);
    bf16* v1b   = (bf16*)(ws + OFF_V1B);
    bf16* hidb  = (bf16*)(ws + OFF_HIDB);
    bf16* pcat  = (bf16*)(ws + OFF_PCAT);
    bf16* ro1f  = (bf16*)(ws + OFF_RO1F);

    float* ys = (float*)d_out;
    float* kf = ys + (long)BT_ * D_;
    float* hf = kf + (long)B_ * 2 * M_;

    scal_kernel<<<1, 64, 0, stream>>>(tq, tk, om, gfr, gvr, scal);
    hipMemsetAsync(scoacc, 0, (size_t)B_ * T_ * T_ * 4, stream);
    hipMemsetAsync(hacc, 0, (size_t)BT_ * HID_ * 4, stream);

    // bf16 operand prep
    cast_kernel<<<2048, 256, 0, stream>>>(e, eb, BT_ * D_);
    castT5_kernel<<<dim3(16, 16, 5), 256, 0, stream>>>(
        Wq, Wk, Wv, vp_w1, vp_w2,
        wqkvT, wqkvT + 262144, wqkvT + 524288, vp1T, vp2T);
    castT_kernel<<<dim3(16, 4, 1), 256, 0, stream>>>(ro_w2, ro2T, 128, 512, 512, 0, 0);
    ro1fft_kernel<<<128, 256, 0, stream>>>(ro_w1, ro1f);

    // qkv = e @ [Wq|Wk|Wv]  (1024 x 1536 x 512) -> f32
    gemm_mfma<0, 0><<<dim3(24, 16, 1), 256, 0, stream>>>(
        eb, wqkvT, nullptr, qkv, 512, 1536, 0, 0, 0, 1);

    sketch_kernel<<<1024, 256, 0, stream>>>(qkv, sign, scal, h, sk2, qcat, kcat);
    prefix_p1<<<512, 256, 0, stream>>>(sk2, qsum);
    prefix_p2<<<512, 256, 0, stream>>>(sk2, qsum, kp, kf);

    // forward FFTs + spectral product (no inverse; scrambled order matches ro1f)
    fwdfft_kernel<<<1024, 256, 0, stream>>>(qcat, kp, pcat);

    // transposed bf16 copies (fused: z = comp*8 + b works because comp stride = 8*b stride)
    castT_kernel<<<dim3(64, 4, 16), 256, 0, stream>>>(sk2, dkT, 128, 2048, 2048, 262144, 262144);
    castT_kernel<<<dim3(16, 4, 8), 256, 0, stream>>>(qkv + 1024, vTb, 128, 512, 1536, 196608, 65536);

    // scores: split-K 16, f32 atomic accumulate (grid 2x2x128 = 512 blocks)
    gemm_mfma<FLAG_ATOMIC, 0><<<dim3(2, 2, 128), 256, 0, stream>>>(
        qcat, kcat, nullptr, scoacc, 4096, 128, 524288, 524288, 16384, 16);
    scomask_kernel<<<512, 256, 0, stream>>>(scoacc, scob);

    // vraw[b] = scores @ v * rsqrt(t+1)  (128x512x128) -> f32
    gemm_mfma<FLAG_ROWSCALE, 0><<<dim3(8, 2, 8), 256, 0, stream>>>(
        scob, vTb, nullptr, vraw, 128, 512, 16384, 65536, 65536, 1);

    ln_kernel<0, 1><<<1024, 256, 0, stream>>>(vraw, nullptr, nullptr, vp_ln_g, vp_ln_b, scal, vlnb);

    // vp MLP
    gemm_mfma<FLAG_BIAS | FLAG_GELU, 1><<<dim3(8, 16, 1), 256, 0, stream>>>(
        vlnb, vp1T, vp_b1, v1b, 512, 512, 0, 0, 0, 1);
    gemm_mfma<FLAG_BIAS, 0><<<dim3(8, 16, 1), 256, 0, stream>>>(
        v1b, vp2T, vp_b2, vf, 512, 512, 0, 0, 0, 1);

    // hid_pre = pcat @ ro1f^T (1024x128x4096), split-K 8 atomic into hacc
    gemm_mfma<FLAG_ATOMIC, 0><<<dim3(2, 16, 8), 256, 0, stream>>>(
        pcat, ro1f, nullptr, hacc, 4096, 128, 0, 0, 0, 8);
    hidgelu_kernel<<<512, 256, 0, stream>>>(hacc, ro_b1, hidb);

    // hfeat = hid @ ro_w2 + b2 (1024x512x128)
    gemm_mfma<FLAG_BIAS, 0><<<dim3(8, 16, 1), 256, 0, stream>>>(
        hidb, ro2T, ro_b2, hfeat, 128, 512, 0, 0, 0, 1);

    // ys = LN(e + gf*hfeat + gv*vf)
    ln_kernel<1, 0><<<1024, 256, 0, stream>>>(e, hfeat, vf, ln_g, ln_b, scal, ys);

    // Hf fused: z in [0,16), b=z&7, c=z>>3
    gemm_mfma<FLAG_HFB, 0><<<dim3(32, 8, 16), 256, 0, stream>>>(
        vTb, dkT, nullptr, hf, 128, 2048, 65536, 0, 0, 1);
}

// Round 8
// 175.804 us; speedup vs baseline: 1.7512x; 1.0893x over previous
//
#include <hip/hip_runtime.h>
#include <hip/hip_bf16.h>
#include <math.h>

#define B_   8
#define T_   128
#define D_   512
#define M_   2048
#define HID_ 128
#define BT_  1024

typedef __attribute__((ext_vector_type(8))) short short8t;
typedef __attribute__((ext_vector_type(8))) unsigned short ushort8t;
typedef __attribute__((ext_vector_type(4))) float f32x4;
typedef __hip_bfloat16 bf16;

// ws layout (float offsets; all multiples of 16 -> 64B aligned)
#define OFF_SCAL   0L
#define OFF_QKV    16L                            // 1024*1536 f32
#define OFF_SK2    (OFF_QKV + 1572864L)           // [dKre|dKim] f32, 2*BT*M
#define OFF_KP     (OFF_SK2 + 4194304L)           // [KR|KI] bf16 exclusive prefix (2*BT*M bf16)
#define OFF_VRAW   (OFF_KP + 4194304L)
#define OFF_VF     (OFF_VRAW + 524288L)
#define OFF_HFEAT  (OFF_VF + 524288L)
// bf16 buffers (size in floats = elems/2)
#define OFF_EB     (OFF_HFEAT + 524288L)          // 1024x512
#define OFF_WQKVT  (OFF_EB + 262144L)             // 1536x512
#define OFF_VP1T   (OFF_WQKVT + 393216L)          // 512x512
#define OFF_VP2T   (OFF_VP1T + 131072L)
#define OFF_RO2T   (OFF_VP2T + 131072L)           // 512x128
#define OFF_QCAT   (OFF_RO2T + 32768L)            // 1024x4096
#define OFF_KCAT   (OFF_QCAT + 2097152L)          // 1024x4096
#define OFF_DKT    (OFF_KCAT + 2097152L)          // 2x8x2048x128
#define OFF_VTB    (OFF_DKT + 2097152L)           // 8x512x128
#define OFF_SCOB   (OFF_VTB + 262144L)            // 8x128x128 bf16
#define OFF_VLNB   (OFF_SCOB + 65536L)            // 1024x512
#define OFF_V1B    (OFF_VLNB + 262144L)           // 1024x512
#define OFF_HIDB   (OFF_V1B + 262144L)            // 1024x128
#define OFF_SCOA   (OFF_HIDB + 65536L)            // 8x128x128 f32 split-K accumulator
#define OFF_QSUM   (OFF_SCOA + 131072L)           // 4x32768 f32 prefix quarter sums
#define OFF_PCAT   (OFF_QSUM + 131072L)           // 1024x4096 bf16 [ReP|ImP]
#define OFF_RO1F   (OFF_PCAT + 2097152L)          // 128x4096 bf16 [ReG|ImG]
#define OFF_HACC   (OFF_RO1F + 262144L)           // 1024x128 f32

#define FLAG_BIAS     1
#define FLAG_GELU     2
#define FLAG_ROWSCALE 4
#define FLAG_ATOMIC   8
#define FLAG_MASK     16
#define FLAG_HFB      32

__device__ __forceinline__ float gelu_f(float x) {
    return 0.5f * x * (1.0f + erff(x * 0.70710678118654752440f));
}

__device__ __forceinline__ float b2f(unsigned short u) {
    return __uint_as_float(((unsigned int)u) << 16);
}

__global__ void scal_kernel(const float* tq, const float* tk, const float* om,
                            const float* gf, const float* gv, float* scal) {
    if (threadIdx.x == 0) {
        scal[0] = 0.5f * tanhf(tq[0]);
        scal[1] = 0.5f * tanhf(tk[0]);
        scal[2] = 0.5f * tanhf(om[0]);
        scal[3] = 0.25f / (1.0f + expf(-gf[0]));
        scal[4] = 0.25f / (1.0f + expf(-gv[0]));
    }
}

__global__ __launch_bounds__(256) void cast_kernel(const float* __restrict__ in,
                                                   bf16* __restrict__ out, int n) {
    int i = blockIdx.x * 256 + threadIdx.x;
    if (i < n) out[i] = __float2bfloat16(in[i]);
}

// tiled transpose-cast: in f32 [R][C] (ld_in, batch bs_in) -> out bf16 [C][R] (batch bs_out)
__global__ __launch_bounds__(256) void castT_kernel(const float* __restrict__ in,
                                                    bf16* __restrict__ out,
                                                    int R, int C, int ld_in,
                                                    long bs_in, long bs_out) {
    __shared__ float tile[32][33];
    int b = blockIdx.z;
    int c0 = blockIdx.x * 32, r0 = blockIdx.y * 32;
    int tx = threadIdx.x & 31, ty = threadIdx.x >> 5;
    for (int rr = ty; rr < 32; rr += 8) {
        int r = r0 + rr, c = c0 + tx;
        tile[rr][tx] = (r < R && c < C) ? in[(long)b * bs_in + (long)r * ld_in + c] : 0.f;
    }
    __syncthreads();
    for (int cc = ty; cc < 32; cc += 8) {
        int c = c0 + cc, r = r0 + tx;
        if (c < C && r < R) out[(long)b * bs_out + (long)c * R + r] = __float2bfloat16(tile[tx][cc]);
    }
}

// batched 512x512 transpose-cast for 5 weights in one launch
__global__ __launch_bounds__(256) void castT5_kernel(const float* w0, const float* w1,
                                                     const float* w2, const float* w3,
                                                     const float* w4,
                                                     bf16* d0, bf16* d1, bf16* d2,
                                                     bf16* d3, bf16* d4) {
    __shared__ float tile[32][33];
    int z = blockIdx.z;
    const float* src; bf16* dst;
    if (z == 0)      { src = w0; dst = d0; }
    else if (z == 1) { src = w1; dst = d1; }
    else if (z == 2) { src = w2; dst = d2; }
    else if (z == 3) { src = w3; dst = d3; }
    else             { src = w4; dst = d4; }
    int c0 = blockIdx.x * 32, r0 = blockIdx.y * 32;
    int tx = threadIdx.x & 31, ty = threadIdx.x >> 5;
    for (int rr = ty; rr < 32; rr += 8)
        tile[rr][tx] = src[(long)(r0 + rr) * 512 + c0 + tx];
    __syncthreads();
    for (int cc = ty; cc < 32; cc += 8)
        dst[(long)(c0 + cc) * 512 + r0 + tx] = __float2bfloat16(tile[tx][cc]);
}

// sketch (phase fused): SK2 f32 = [dKre|dKim]; qcat bf16 = [Qre|Qim]; kcat bf16 = [dKre|-dKim]
__global__ __launch_bounds__(256) void sketch_kernel(const float* __restrict__ qkv,
                                                     const float* __restrict__ sign,
                                                     const float* __restrict__ scal,
                                                     const int* __restrict__ h,
                                                     float* __restrict__ SK2,
                                                     bf16* __restrict__ qcat,
                                                     bf16* __restrict__ kcat) {
    int bt = blockIdx.x;
    int tid = threadIdx.x;
    __shared__ float s0[M_], s1[M_], s2[M_], s3[M_];
    for (int j = tid; j < M_; j += 256) { s0[j] = 0.f; s1[j] = 0.f; s2[j] = 0.f; s3[j] = 0.f; }
    __syncthreads();
    int t = bt & 127;
    float thq = scal[0], thk = scal[1], omg = scal[2];
    float ft = (float)t;
    for (int i = tid; i < D_; i += 256) {
        float q = qkv[(long)bt * 1536 + i];
        float k = qkv[(long)bt * 1536 + 512 + i];
        float sg = sign[i];
        float sq_, cq_, sk_, ck_;
        __sincosf(thq * q - omg * ft, &sq_, &cq_);
        __sincosf(thk * k + omg * ft, &sk_, &ck_);
        int m = h[i];
        atomicAdd(&s0[m], q * cq_ * sg);
        atomicAdd(&s1[m], q * sq_ * sg);
        atomicAdd(&s2[m], k * ck_ * sg);
        atomicAdd(&s3[m], k * sk_ * sg);
    }
    __syncthreads();
    long ob = (long)bt * M_;
    long qb = (long)bt * 4096;
    for (int j = tid; j < M_; j += 256) {
        SK2[ob + j]                  = s2[j];
        SK2[(long)BT_ * M_ + ob + j] = s3[j];
        qcat[qb + j]        = __float2bfloat16(s0[j]);
        qcat[qb + 2048 + j] = __float2bfloat16(s1[j]);
        kcat[qb + j]        = __float2bfloat16(s2[j]);
        kcat[qb + 2048 + j] = __float2bfloat16(-s3[j]);
    }
}

// ---- two-phase exclusive prefix over t (4-way t split) ----
__global__ __launch_bounds__(256) void prefix_p1(const float* __restrict__ SK2,
                                                 float* __restrict__ qsum) {
    int idx = blockIdx.x * 256 + threadIdx.x;   // 131072
    int col = idx & 32767, q = idx >> 15;
    int m = col & 2047, b = (col >> 11) & 7, comp = col >> 14;
    const float* src = SK2 + (long)comp * BT_ * M_ + (long)b * T_ * M_ + (long)(q * 32) * M_ + m;
    float s = 0.f;
    #pragma unroll 8
    for (int i = 0; i < 32; ++i) s += src[(long)i * M_];
    qsum[(long)q * 32768 + col] = s;
}

// KP written as bf16 (only fwdfft reads it); kf_out stays f32
__global__ __launch_bounds__(256) void prefix_p2(const float* __restrict__ SK2,
                                                 const float* __restrict__ qsum,
                                                 bf16* __restrict__ KP16,
                                                 float* __restrict__ kf_out) {
    int idx = blockIdx.x * 256 + threadIdx.x;   // 131072
    int col = idx & 32767, q = idx >> 15;
    int m = col & 2047, b = (col >> 11) & 7, comp = col >> 14;
    long cb = (long)comp * BT_ * M_ + (long)b * T_ * M_ + m + (long)(q * 32) * M_;
    const float* src = SK2 + cb;
    bf16* dst = KP16 + cb;
    float acc = 0.f;
    for (int p = 0; p < q; ++p) acc += qsum[(long)p * 32768 + col];
    #pragma unroll 4
    for (int i = 0; i < 32; ++i) {
        dst[(long)i * M_] = __float2bfloat16(acc);
        acc += src[(long)i * M_];
    }
    if (q == 3) kf_out[((long)b * 2 + comp) * M_ + m] = acc;
}

// ==== in-place radix-2 DIF forward FFT (scrambled output; order cancels
// because the frequency-domain GEMM B-operand uses the identical scramble) ====
#define PIDX(i) ((i) + ((i) >> 5))

// one DIF stage on two complex arrays (shared twiddle) — LDS phase (M >= 32)
template<int M>
__device__ __forceinline__ void dif_pair(float* r0, float* i0_, float* r1, float* i1_, int tid) {
    #pragma unroll
    for (int u = 0; u < 4; ++u) {
        int q = u * 256 + tid;
        int k = q & (M - 1);
        int i = (q / M) * (2 * M) + k;
        float s, c;
        __sincosf((float)k * (3.14159265358979323846f / (float)M), &s, &c);
        int p0 = PIDX(i), p1 = PIDX(i + M);
        {
            float ar = r0[p0], ai = i0_[p0], br = r0[p1], bi = i0_[p1];
            r0[p0] = ar + br; i0_[p0] = ai + bi;
            float dr = ar - br, di = ai - bi;
            r0[p1] = dr * c + di * s;    // (dr + i di) * (c - i s)
            i0_[p1] = di * c - dr * s;
        }
        {
            float ar = r1[p0], ai = i1_[p0], br = r1[p1], bi = i1_[p1];
            r1[p0] = ar + br; i1_[p0] = ai + bi;
            float dr = ar - br, di = ai - bi;
            r1[p1] = dr * c + di * s;
            i1_[p1] = di * c - dr * s;
        }
    }
}

template<int M>
__device__ __forceinline__ void dif_one(float* re, float* im, int tid) {
    #pragma unroll
    for (int u = 0; u < 4; ++u) {
        int q = u * 256 + tid;
        int k = q & (M - 1);
        int i = (q / M) * (2 * M) + k;
        float s, c;
        __sincosf((float)k * (3.14159265358979323846f / (float)M), &s, &c);
        int p0 = PIDX(i), p1 = PIDX(i + M);
        float ar = re[p0], ai = im[p0], br = re[p1], bi = im[p1];
        re[p0] = ar + br; im[p0] = ai + bi;
        float dr = ar - br, di = ai - bi;
        re[p1] = dr * c + di * s;
        im[p1] = di * c - dr * s;
    }
}

// forward FFTs of Q sketch and K prefix; pcat = [Re(FQ*FK) | Im(FQ*FK)] bf16 (scrambled order)
// Phase A: stages 1024..32 in LDS. Phase B: stages 16,8 via shfl_xor; 4,2,1 in registers.
__global__ __launch_bounds__(256) void fwdfft_kernel(const bf16* __restrict__ qcat,
                                                     const bf16* __restrict__ KP16,
                                                     bf16* __restrict__ pcat) {
    __shared__ float KRs[2112], KIs[2112], QRs[2112], QIs[2112];   // 33 KB
    int bt = blockIdx.x, tid = threadIdx.x;
    const unsigned short* qp = (const unsigned short*)(qcat + (long)bt * 4096);
    const unsigned short* kpr = (const unsigned short*)(KP16 + (long)bt * M_);
    const unsigned short* kpi = (const unsigned short*)(KP16 + (long)BT_ * M_ + (long)bt * M_);
    for (int u = 0; u < 8; ++u) {
        int j = u * 256 + tid;
        int pj = PIDX(j);
        KRs[pj] = b2f(kpr[j]);
        KIs[pj] = b2f(kpi[j]);
        QRs[pj] = b2f(qp[j]);
        QIs[pj] = b2f(qp[2048 + j]);
    }
    __syncthreads();
#define FSTEP(MM) dif_pair<MM>(KRs, KIs, QRs, QIs, tid); __syncthreads();
    FSTEP(1024) FSTEP(512) FSTEP(256) FSTEP(128) FSTEP(64) FSTEP(32)
#undef FSTEP

    // ---- Phase B: thread g owns elements [8g, 8g+8) ----
    float kr_[8], ki_[8], qr_[8], qi_[8];
    #pragma unroll
    for (int l = 0; l < 8; ++l) {
        int pj = PIDX(8 * tid + l);
        kr_[l] = KRs[pj]; ki_[l] = KIs[pj];
        qr_[l] = QRs[pj]; qi_[l] = QIs[pj];
    }

    const float C16[16] = {1.f, 0.98078528f, 0.92387953f, 0.83146961f,
                           0.70710678f, 0.55557023f, 0.38268343f, 0.19509032f,
                           0.f, -0.19509032f, -0.38268343f, -0.55557023f,
                           -0.70710678f, -0.83146961f, -0.92387953f, -0.98078528f};
    const float S16[16] = {0.f, 0.19509032f, 0.38268343f, 0.55557023f,
                           0.70710678f, 0.83146961f, 0.92387953f, 0.98078528f,
                           1.f, 0.98078528f, 0.92387953f, 0.83146961f,
                           0.70710678f, 0.55557023f, 0.38268343f, 0.19509032f};
    bool odd = (tid & 1) != 0;
    // stage M=16: partner lane^2, twiddle k = l + 8*(tid&1)
    {
        bool hi2 = (tid & 2) != 0;
        #pragma unroll
        for (int l = 0; l < 8; ++l) {
            float c = odd ? C16[l + 8] : C16[l];
            float s = odd ? S16[l + 8] : S16[l];
            float pr, pi2, sr, si, dr, di;
            pr = __shfl_xor(kr_[l], 2); pi2 = __shfl_xor(ki_[l], 2);
            sr = kr_[l] + pr; si = ki_[l] + pi2;
            dr = pr - kr_[l]; di = pi2 - ki_[l];
            kr_[l] = hi2 ? (dr * c + di * s) : sr;
            ki_[l] = hi2 ? (di * c - dr * s) : si;
            pr = __shfl_xor(qr_[l], 2); pi2 = __shfl_xor(qi_[l], 2);
            sr = qr_[l] + pr; si = qi_[l] + pi2;
            dr = pr - qr_[l]; di = pi2 - qi_[l];
            qr_[l] = hi2 ? (dr * c + di * s) : sr;
            qi_[l] = hi2 ? (di * c - dr * s) : si;
        }
    }
    // stage M=8: partner lane^1, twiddle k = l (compile-time)
    {
        #pragma unroll
        for (int l = 0; l < 8; ++l) {
            float c = C16[2 * l];   // cos(l*pi/8) = C16[2l]
            float s = S16[2 * l];
            float pr, pi2, sr, si, dr, di;
            pr = __shfl_xor(kr_[l], 1); pi2 = __shfl_xor(ki_[l], 1);
            sr = kr_[l] + pr; si = ki_[l] + pi2;
            dr = pr - kr_[l]; di = pi2 - ki_[l];
            kr_[l] = odd ? (dr * c + di * s) : sr;
            ki_[l] = odd ? (di * c - dr * s) : si;
            pr = __shfl_xor(qr_[l], 1); pi2 = __shfl_xor(qi_[l], 1);
            sr = qr_[l] + pr; si = qi_[l] + pi2;
            dr = pr - qr_[l]; di = pi2 - qi_[l];
            qr_[l] = odd ? (dr * c + di * s) : sr;
            qi_[l] = odd ? (di * c - dr * s) : si;
        }
    }
    // stage M=4: pairs (l, l+4), twiddle k=l (compile-time)
    {
        const float C4[4] = {1.f, 0.70710678f, 0.f, -0.70710678f};
        const float S4[4] = {0.f, 0.70710678f, 1.f, 0.70710678f};
        #pragma unroll
        for (int l = 0; l < 4; ++l) {
            float ar, ai, br, bi, dr, di;
            ar = kr_[l]; ai = ki_[l]; br = kr_[l + 4]; bi = ki_[l + 4];
            kr_[l] = ar + br; ki_[l] = ai + bi;
            dr = ar - br; di = ai - bi;
            kr_[l + 4] = dr * C4[l] + di * S4[l];
            ki_[l + 4] = di * C4[l] - dr * S4[l];
            ar = qr_[l]; ai = qi_[l]; br = qr_[l + 4]; bi = qi_[l + 4];
            qr_[l] = ar + br; qi_[l] = ai + bi;
            dr = ar - br; di = ai - bi;
            qr_[l + 4] = dr * C4[l] + di * S4[l];
            qi_[l + 4] = di * C4[l] - dr * S4[l];
        }
    }
    // stage M=2: pairs (b+0,b+2) tw=1; (b+1,b+3) tw=-i
    #pragma unroll
    for (int b2 = 0; b2 < 8; b2 += 4) {
        {
            float ar = kr_[b2], ai = ki_[b2], br = kr_[b2 + 2], bi = ki_[b2 + 2];
            kr_[b2] = ar + br; ki_[b2] = ai + bi;
            kr_[b2 + 2] = ar - br; ki_[b2 + 2] = ai - bi;
            ar = qr_[b2]; ai = qi_[b2]; br = qr_[b2 + 2]; bi = qi_[b2 + 2];
            qr_[b2] = ar + br; qi_[b2] = ai + bi;
            qr_[b2 + 2] = ar - br; qi_[b2 + 2] = ai - bi;
        }
        {
            float ar = kr_[b2 + 1], ai = ki_[b2 + 1], br = kr_[b2 + 3], bi = ki_[b2 + 3];
            kr_[b2 + 1] = ar + br; ki_[b2 + 1] = ai + bi;
            float dr = ar - br, di = ai - bi;
            kr_[b2 + 3] = di; ki_[b2 + 3] = -dr;     // * (-i)
            ar = qr_[b2 + 1]; ai = qi_[b2 + 1]; br = qr_[b2 + 3]; bi = qi_[b2 + 3];
            qr_[b2 + 1] = ar + br; qi_[b2 + 1] = ai + bi;
            dr = ar - br; di = ai - bi;
            qr_[b2 + 3] = di; qi_[b2 + 3] = -dr;
        }
    }
    // stage M=1: pairs (i, i+1), tw=1
    #pragma unroll
    for (int i0 = 0; i0 < 8; i0 += 2) {
        float ar = kr_[i0], ai = ki_[i0], br = kr_[i0 + 1], bi = ki_[i0 + 1];
        kr_[i0] = ar + br; ki_[i0] = ai + bi;
        kr_[i0 + 1] = ar - br; ki_[i0 + 1] = ai - bi;
        ar = qr_[i0]; ai = qi_[i0]; br = qr_[i0 + 1]; bi = qi_[i0 + 1];
        qr_[i0] = ar + br; qi_[i0] = ai + bi;
        qr_[i0 + 1] = ar - br; qi_[i0 + 1] = ai - bi;
    }

    // spectral product -> bf16 (contiguous 16B stores)
    unsigned short* op = (unsigned short*)(pcat + (long)bt * 4096 + 8 * tid);
    ushort8t ore, oim;
    #pragma unroll
    for (int l = 0; l < 8; ++l) {
        float pr = qr_[l] * kr_[l] - qi_[l] * ki_[l];
        float pi2 = qr_[l] * ki_[l] + qi_[l] * kr_[l];
        bf16 hr = __float2bfloat16(pr);
        bf16 hi = __float2bfloat16(pi2);
        ore[l] = *(unsigned short*)&hr;
        oim[l] = *(unsigned short*)&hi;
    }
    *(ushort8t*)op = ore;
    *(ushort8t*)(op + 2048) = oim;
}

// Ghat for column j of ro_w1: ro1f[j] = [Re FFT | Im FFT] (scrambled, same DIF) bf16
__global__ __launch_bounds__(256) void ro1fft_kernel(const float* __restrict__ ro_w1,
                                                     bf16* __restrict__ ro1f) {
    __shared__ float Rs[2112], Is[2112];
    int j = blockIdx.x, tid = threadIdx.x;
    for (int u = 0; u < 8; ++u) {
        int n = u * 256 + tid;
        Rs[PIDX(n)] = ro_w1[(long)n * HID_ + j];
        Is[PIDX(n)] = 0.f;
    }
    __syncthreads();
#define FSTEP(MM) dif_one<MM>(Rs, Is, tid); __syncthreads();
    FSTEP(1024) FSTEP(512) FSTEP(256) FSTEP(128) FSTEP(64)
    FSTEP(32) FSTEP(16) FSTEP(8) FSTEP(4) FSTEP(2) FSTEP(1)
#undef FSTEP
    unsigned short* op = (unsigned short*)(ro1f + (long)j * 4096);
    for (int u = 0; u < 8; ++u) {
        int r = u * 256 + tid;
        int pr = PIDX(r);
        bf16 re = __float2bfloat16(Rs[pr]);
        bf16 im = __float2bfloat16(Is[pr]);
        op[r]        = *(unsigned short*)&re;
        op[2048 + r] = *(unsigned short*)&im;
    }
}

// hid epilogue: hid = gelu(hacc * scale(t) + b1) -> bf16
__global__ __launch_bounds__(256) void hidgelu_kernel(const float* __restrict__ hacc,
                                                      const float* __restrict__ b1,
                                                      bf16* __restrict__ hidb) {
    int idx = blockIdx.x * 256 + threadIdx.x;   // 131072
    int j = idx & 127;
    int t = (idx >> 7) & 127;
    float scale = rsqrtf((float)(t + 1)) * (1.0f / 92681.900089f);   // 1/2048^1.5
    hidb[idx] = __float2bfloat16(gelu_f(hacc[idx] * scale + b1[j]));
}

// MFMA bf16 TN GEMM: C[M,N] = A[M,K] * Bt[N,K]^T. 64x64 tile, 4 waves.
template<int FLAGS, int OUTB16>
__global__ __launch_bounds__(256) void gemm_mfma(
    const bf16* __restrict__ A, const bf16* __restrict__ Bt,
    const float* __restrict__ bias, void* __restrict__ Cv,
    int K, int ldc, long abz, long bbz, long cbz, int splitk)
{
    __shared__ __align__(16) bf16 As[64][44];
    __shared__ __align__(16) bf16 Bs[64][44];
    int bz = blockIdx.z;
    int batch = bz, kslice = 0;
    if (FLAGS & FLAG_ATOMIC) { batch = bz / splitk; kslice = bz % splitk; }
    const bf16* Ab;
    const bf16* Bb;
    long coff;
    if (FLAGS & FLAG_HFB) {
        int b = bz & 7, c = bz >> 3;
        Ab = A + (long)b * abz + (long)blockIdx.y * 64 * K;
        Bb = Bt + (long)c * 2097152L + (long)b * 262144L + (long)blockIdx.x * 64 * K;
        coff = (long)b * 2097152L + (long)c * 1048576L;
    } else {
        Ab = A + (long)batch * abz + (long)blockIdx.y * 64 * K;
        Bb = Bt + (long)batch * bbz + (long)blockIdx.x * 64 * K;
        coff = (long)batch * cbz;
    }
    int tid = threadIdx.x;
    int lrow = tid >> 2;
    int lk = (tid & 3) * 8;
    int w = tid >> 6, lane = tid & 63;
    int wr = (w >> 1) * 32, wc = (w & 1) * 32;
    int fm = lane & 15, fk = (lane >> 4) * 8;
    f32x4 acc00 = {0.f,0.f,0.f,0.f}, acc01 = acc00, acc10 = acc00, acc11 = acc00;

    int klen = K / splitk;
    int k0 = kslice * klen;
    for (int kt = k0; kt < k0 + klen; kt += 32) {
        *(float4*)&As[lrow][lk] = *(const float4*)&Ab[(long)lrow * K + kt + lk];
        *(float4*)&Bs[lrow][lk] = *(const float4*)&Bb[(long)lrow * K + kt + lk];
        __syncthreads();
        short8t a0 = *(const short8t*)&As[wr + fm][fk];
        short8t a1 = *(const short8t*)&As[wr + 16 + fm][fk];
        short8t b0 = *(const short8t*)&Bs[wc + fm][fk];
        short8t b1 = *(const short8t*)&Bs[wc + 16 + fm][fk];
        acc00 = __builtin_amdgcn_mfma_f32_16x16x32_bf16(a0, b0, acc00, 0, 0, 0);
        acc01 = __builtin_amdgcn_mfma_f32_16x16x32_bf16(a0, b1, acc01, 0, 0, 0);
        acc10 = __builtin_amdgcn_mfma_f32_16x16x32_bf16(a1, b0, acc10, 0, 0, 0);
        acc11 = __builtin_amdgcn_mfma_f32_16x16x32_bf16(a1, b1, acc11, 0, 0, 0);
        __syncthreads();
    }

    float* Cf = (float*)Cv;
    bf16* Cb = (bf16*)Cv;
    int row_base = blockIdx.y * 64 + wr + (lane >> 4) * 4;
    int col_base = blockIdx.x * 64 + wc + fm;
    #pragma unroll
    for (int fr = 0; fr < 2; ++fr) {
        #pragma unroll
        for (int fc = 0; fc < 2; ++fc) {
            const f32x4& a = fr == 0 ? (fc == 0 ? acc00 : acc01) : (fc == 0 ? acc10 : acc11);
            #pragma unroll
            for (int r = 0; r < 4; ++r) {
                int gi = row_base + fr * 16 + r;
                int gj = col_base + fc * 16;
                float v = a[r];
                long ci = coff + (long)gi * ldc + gj;
                if (FLAGS & FLAG_ATOMIC) {
                    atomicAdd(&Cf[ci], v);
                } else {
                    if (FLAGS & FLAG_BIAS) v += bias[gj];
                    if (FLAGS & FLAG_GELU) v = gelu_f(v);
                    if (FLAGS & FLAG_ROWSCALE) v *= rsqrtf((float)(gi & 127) + 1.0f);
                    if (FLAGS & FLAG_MASK) { if (gj >= gi) v = 0.f; }
                    if (OUTB16) Cb[ci] = __float2bfloat16(v);
                    else        Cf[ci] = v;
                }
            }
        }
    }
}

// scores epilogue: mask upper triangle (tau >= t) and cast to bf16
__global__ __launch_bounds__(256) void scomask_kernel(const float* __restrict__ acc,
                                                      bf16* __restrict__ scob) {
    int idx = blockIdx.x * 256 + threadIdx.x;   // 8*128*128
    int t = (idx >> 7) & 127, tau = idx & 127;
    float v = (tau < t) ? acc[idx] : 0.f;
    scob[idx] = __float2bfloat16(v);
}

// LN over D=512. FINAL=0: LN(x1); FINAL=1: LN(x1 + gf*x2 + gv*x3). OB16 selects out dtype.
template<int FINAL, int OB16>
__global__ __launch_bounds__(256) void ln_kernel(const float* __restrict__ x1,
                                                 const float* __restrict__ x2,
                                                 const float* __restrict__ x3,
                                                 const float* __restrict__ g,
                                                 const float* __restrict__ bb,
                                                 const float* __restrict__ scal,
                                                 void* __restrict__ outv) {
    int row = blockIdx.x, tid = threadIdx.x;
    long base = (long)row * D_;
    int d0 = tid, d1 = tid + 256;
    float v0, v1;
    if (FINAL) {
        float gf = scal[3], gv = scal[4];
        v0 = x1[base + d0] + gf * x2[base + d0] + gv * x3[base + d0];
        v1 = x1[base + d1] + gf * x2[base + d1] + gv * x3[base + d1];
    } else {
        v0 = x1[base + d0];
        v1 = x1[base + d1];
    }
    float s = v0 + v1;
    #pragma unroll
    for (int o = 32; o > 0; o >>= 1) s += __shfl_down(s, o);
    __shared__ float red[8];
    int wid = tid >> 6, lane = tid & 63;
    if (lane == 0) red[wid] = s;
    __syncthreads();
    float mu = (red[0] + red[1] + red[2] + red[3]) * (1.0f / D_);
    float e0 = v0 - mu, e1 = v1 - mu;
    float sq = e0 * e0 + e1 * e1;
    #pragma unroll
    for (int o = 32; o > 0; o >>= 1) sq += __shfl_down(sq, o);
    if (lane == 0) red[4 + wid] = sq;
    __syncthreads();
    float var = (red[4] + red[5] + red[6] + red[7]) * (1.0f / D_);
    float rs = rsqrtf(var + 1e-5f);
    float o0 = e0 * rs * g[d0] + bb[d0];
    float o1 = e1 * rs * g[d1] + bb[d1];
    if (OB16) {
        ((bf16*)outv)[base + d0] = __float2bfloat16(o0);
        ((bf16*)outv)[base + d1] = __float2bfloat16(o1);
    } else {
        ((float*)outv)[base + d0] = o0;
        ((float*)outv)[base + d1] = o1;
    }
}

extern "C" void kernel_launch(void* const* d_in, const int* in_sizes, int n_in,
                              void* d_out, int out_size, void* d_ws, size_t ws_size,
                              hipStream_t stream) {
    const float* e      = (const float*)d_in[0];
    const int*   h      = (const int*)d_in[1];
    const float* sign   = (const float*)d_in[2];
    const float* Wq     = (const float*)d_in[3];
    const float* Wk     = (const float*)d_in[4];
    const float* Wv     = (const float*)d_in[5];
    const float* ro_w1  = (const float*)d_in[6];
    const float* ro_b1  = (const float*)d_in[7];
    const float* ro_w2  = (const float*)d_in[8];
    const float* ro_b2  = (const float*)d_in[9];
    const float* vp_ln_g= (const float*)d_in[10];
    const float* vp_ln_b= (const float*)d_in[11];
    const float* vp_w1  = (const float*)d_in[12];
    const float* vp_b1  = (const float*)d_in[13];
    const float* vp_w2  = (const float*)d_in[14];
    const float* vp_b2  = (const float*)d_in[15];
    const float* ln_g   = (const float*)d_in[16];
    const float* ln_b   = (const float*)d_in[17];
    const float* tq     = (const float*)d_in[18];
    const float* tk     = (const float*)d_in[19];
    const float* om     = (const float*)d_in[20];
    const float* gfr    = (const float*)d_in[21];
    const float* gvr    = (const float*)d_in[22];

    float* ws    = (float*)d_ws;
    float* scal  = ws + OFF_SCAL;
    float* qkv   = ws + OFF_QKV;
    float* sk2   = ws + OFF_SK2;
    float* vraw  = ws + OFF_VRAW;
    float* vf    = ws + OFF_VF;
    float* hfeat = ws + OFF_HFEAT;
    float* scoacc= ws + OFF_SCOA;
    float* qsum  = ws + OFF_QSUM;
    float* hacc  = ws + OFF_HACC;
    bf16* kp16  = (bf16*)(ws + OFF_KP);
    bf16* eb    = (bf16*)(ws + OFF_EB);
    bf16* wqkvT = (bf16*)(ws + OFF_WQKVT);
    bf16* vp1T  = (bf16*)(ws + OFF_VP1T);
    bf16* vp2T  = (bf16*)(ws + OFF_VP2T);
    bf16* ro2T  = (bf16*)(ws + OFF_RO2T);
    bf16* qcat  = (bf16*)(ws + OFF_QCAT);
    bf16* kcat  = (bf16*)(ws + OFF_KCAT);
    bf16* dkT   = (bf16*)(ws + OFF_DKT);
    bf16* vTb   = (bf16*)(ws + OFF_VTB);
    bf16* scob  = (bf16*)(ws + OFF_SCOB);
    bf16* vlnb  = (bf16*)(ws + OFF_VLNB);
    bf16* v1b   = (bf16*)(ws + OFF_V1B);
    bf16* hidb  = (bf16*)(ws + OFF_HIDB);
    bf16* pcat  = (bf16*)(ws + OFF_PCAT);
    bf16* ro1f  = (bf16*)(ws + OFF_RO1F);

    float* ys = (float*)d_out;
    float* kf = ys + (long)BT_ * D_;
    float* hf = kf + (long)B_ * 2 * M_;

    scal_kernel<<<1, 64, 0, stream>>>(tq, tk, om, gfr, gvr, scal);
    hipMemsetAsync(scoacc, 0, (size_t)B_ * T_ * T_ * 4, stream);
    hipMemsetAsync(hacc, 0, (size_t)BT_ * HID_ * 4, stream);

    // bf16 operand prep
    cast_kernel<<<2048, 256, 0, stream>>>(e, eb, BT_ * D_);
    castT5_kernel<<<dim3(16, 16, 5), 256, 0, stream>>>(
        Wq, Wk, Wv, vp_w1, vp_w2,
        wqkvT, wqkvT + 262144, wqkvT + 524288, vp1T, vp2T);
    castT_kernel<<<dim3(16, 4, 1), 256, 0, stream>>>(ro_w2, ro2T, 128, 512, 512, 0, 0);
    ro1fft_kernel<<<128, 256, 0, stream>>>(ro_w1, ro1f);

    // qkv = e @ [Wq|Wk|Wv]  (1024 x 1536 x 512) -> f32
    gemm_mfma<0, 0><<<dim3(24, 16, 1), 256, 0, stream>>>(
        eb, wqkvT, nullptr, qkv, 512, 1536, 0, 0, 0, 1);

    sketch_kernel<<<1024, 256, 0, stream>>>(qkv, sign, scal, h, sk2, qcat, kcat);
    prefix_p1<<<512, 256, 0, stream>>>(sk2, qsum);
    prefix_p2<<<512, 256, 0, stream>>>(sk2, qsum, kp16, kf);

    // forward FFTs + spectral product (no inverse; scrambled order matches ro1f)
    fwdfft_kernel<<<1024, 256, 0, stream>>>(qcat, kp16, pcat);

    // transposed bf16 copies (fused: z = comp*8 + b works because comp stride = 8*b stride)
    castT_kernel<<<dim3(64, 4, 16), 256, 0, stream>>>(sk2, dkT, 128, 2048, 2048, 262144, 262144);
    castT_kernel<<<dim3(16, 4, 8), 256, 0, stream>>>(qkv + 1024, vTb, 128, 512, 1536, 196608, 65536);

    // scores: split-K 16, f32 atomic accumulate (grid 2x2x128 = 512 blocks)
    gemm_mfma<FLAG_ATOMIC, 0><<<dim3(2, 2, 128), 256, 0, stream>>>(
        qcat, kcat, nullptr, scoacc, 4096, 128, 524288, 524288, 16384, 16);
    scomask_kernel<<<512, 256, 0, stream>>>(scoacc, scob);

    // vraw[b] = scores @ v * rsqrt(t+1)  (128x512x128) -> f32
    gemm_mfma<FLAG_ROWSCALE, 0><<<dim3(8, 2, 8), 256, 0, stream>>>(
        scob, vTb, nullptr, vraw, 128, 512, 16384, 65536, 65536, 1);

    ln_kernel<0, 1><<<1024, 256, 0, stream>>>(vraw, nullptr, nullptr, vp_ln_g, vp_ln_b, scal, vlnb);

    // vp MLP
    gemm_mfma<FLAG_BIAS | FLAG_GELU, 1><<<dim3(8, 16, 1), 256, 0, stream>>>(
        vlnb, vp1T, vp_b1, v1b, 512, 512, 0, 0, 0, 1);
    gemm_mfma<FLAG_BIAS, 0><<<dim3(8, 16, 1), 256, 0, stream>>>(
        v1b, vp2T, vp_b2, vf, 512, 512, 0, 0, 0, 1);

    // hid_pre = pcat @ ro1f^T (1024x128x4096), split-K 8 atomic into hacc
    gemm_mfma<FLAG_ATOMIC, 0><<<dim3(2, 16, 8), 256, 0, stream>>>(
        pcat, ro1f, nullptr, hacc, 4096, 128, 0, 0, 0, 8);
    hidgelu_kernel<<<512, 256, 0, stream>>>(hacc, ro_b1, hidb);

    // hfeat = hid @ ro_w2 + b2 (1024x512x128)
    gemm_mfma<FLAG_BIAS, 0><<<dim3(8, 16, 1), 256, 0, stream>>>(
        hidb, ro2T, ro_b2, hfeat, 128, 512, 0, 0, 0, 1);

    // ys = LN(e + gf*hfeat + gv*vf)
    ln_kernel<1, 0><<<1024, 256, 0, stream>>>(e, hfeat, vf, ln_g, ln_b, scal, ys);

    // Hf fused: z in [0,16), b=z&7, c=z>>3
    gemm_mfma<FLAG_HFB, 0><<<dim3(32, 8, 16), 256, 0, stream>>>(
        vTb, dkT, nullptr, hf, 128, 2048, 65536, 0, 0, 1);
}

// Round 9
// 172.190 us; speedup vs baseline: 1.7879x; 1.0210x over previous
//
#include <hip/hip_runtime.h>
#include <hip/hip_bf16.h>
#include <math.h>

#define B_   8
#define T_   128
#define D_   512
#define M_   2048
#define HID_ 128
#define BT_  1024

typedef __attribute__((ext_vector_type(8))) short short8t;
typedef __attribute__((ext_vector_type(8))) unsigned short ushort8t;
typedef __attribute__((ext_vector_type(4))) float f32x4;
typedef __hip_bfloat16 bf16;

// ws layout (float offsets; all multiples of 16 -> 64B aligned)
#define OFF_SCAL   0L
#define OFF_QKV    16L                            // 1024*1536 f32
#define OFF_SK2    (OFF_QKV + 1572864L)           // [dKre|dKim] f32, 2*BT*M
#define OFF_KP     (OFF_SK2 + 4194304L)           // [KR|KI] bf16 exclusive prefix (2*BT*M bf16)
#define OFF_VRAW   (OFF_KP + 4194304L)
#define OFF_VF     (OFF_VRAW + 524288L)
#define OFF_HFEAT  (OFF_VF + 524288L)
// bf16 buffers (size in floats = elems/2)
#define OFF_EB     (OFF_HFEAT + 524288L)          // 1024x512
#define OFF_WQKVT  (OFF_EB + 262144L)             // 1536x512
#define OFF_VP1T   (OFF_WQKVT + 393216L)          // 512x512
#define OFF_VP2T   (OFF_VP1T + 131072L)
#define OFF_RO2T   (OFF_VP2T + 131072L)           // 512x128
#define OFF_QCAT   (OFF_RO2T + 32768L)            // 1024x4096
#define OFF_KCAT   (OFF_QCAT + 2097152L)          // 1024x4096
#define OFF_DKT    (OFF_KCAT + 2097152L)          // 2x8x2048x128
#define OFF_VTB    (OFF_DKT + 2097152L)           // 8x512x128
#define OFF_SCOB   (OFF_VTB + 262144L)            // (unused)
#define OFF_VLNB   (OFF_SCOB + 65536L)            // 1024x512
#define OFF_V1B    (OFF_VLNB + 262144L)           // 1024x512
#define OFF_HIDB   (OFF_V1B + 262144L)            // (unused)
#define OFF_SCOA   (OFF_HIDB + 65536L)            // 8x128x128 f32 split-K accumulator
#define OFF_QSUM   (OFF_SCOA + 131072L)           // 4x32768 f32 prefix quarter sums
#define OFF_PCAT   (OFF_QSUM + 131072L)           // 1024x4096 bf16 [ReP|ImP]
#define OFF_RO1F   (OFF_PCAT + 2097152L)          // 128x4096 bf16 [ReG|ImG]
#define OFF_HACC   (OFF_RO1F + 262144L)           // 1024x128 f32

#define FLAG_BIAS     1
#define FLAG_GELU     2
#define FLAG_ROWSCALE 4
#define FLAG_ATOMIC   8
#define FLAG_HFB      32

__device__ __forceinline__ float gelu_f(float x) {
    return 0.5f * x * (1.0f + erff(x * 0.70710678118654752440f));
}

__device__ __forceinline__ float b2f(unsigned short u) {
    return __uint_as_float(((unsigned int)u) << 16);
}

__global__ void scal_kernel(const float* tq, const float* tk, const float* om,
                            const float* gf, const float* gv, float* scal) {
    if (threadIdx.x == 0) {
        scal[0] = 0.5f * tanhf(tq[0]);
        scal[1] = 0.5f * tanhf(tk[0]);
        scal[2] = 0.5f * tanhf(om[0]);
        scal[3] = 0.25f / (1.0f + expf(-gf[0]));
        scal[4] = 0.25f / (1.0f + expf(-gv[0]));
    }
}

__global__ __launch_bounds__(256) void cast_kernel(const float* __restrict__ in,
                                                   bf16* __restrict__ out, int n) {
    int i = blockIdx.x * 256 + threadIdx.x;
    if (i < n) out[i] = __float2bfloat16(in[i]);
}

// tiled transpose-cast: in f32 [R][C] (ld_in, batch bs_in) -> out bf16 [C][R] (batch bs_out)
__global__ __launch_bounds__(256) void castT_kernel(const float* __restrict__ in,
                                                    bf16* __restrict__ out,
                                                    int R, int C, int ld_in,
                                                    long bs_in, long bs_out) {
    __shared__ float tile[32][33];
    int b = blockIdx.z;
    int c0 = blockIdx.x * 32, r0 = blockIdx.y * 32;
    int tx = threadIdx.x & 31, ty = threadIdx.x >> 5;
    for (int rr = ty; rr < 32; rr += 8) {
        int r = r0 + rr, c = c0 + tx;
        tile[rr][tx] = (r < R && c < C) ? in[(long)b * bs_in + (long)r * ld_in + c] : 0.f;
    }
    __syncthreads();
    for (int cc = ty; cc < 32; cc += 8) {
        int c = c0 + cc, r = r0 + tx;
        if (c < C && r < R) out[(long)b * bs_out + (long)c * R + r] = __float2bfloat16(tile[tx][cc]);
    }
}

// batched 512x512 transpose-cast for 5 weights in one launch
__global__ __launch_bounds__(256) void castT5_kernel(const float* w0, const float* w1,
                                                     const float* w2, const float* w3,
                                                     const float* w4,
                                                     bf16* d0, bf16* d1, bf16* d2,
                                                     bf16* d3, bf16* d4) {
    __shared__ float tile[32][33];
    int z = blockIdx.z;
    const float* src; bf16* dst;
    if (z == 0)      { src = w0; dst = d0; }
    else if (z == 1) { src = w1; dst = d1; }
    else if (z == 2) { src = w2; dst = d2; }
    else if (z == 3) { src = w3; dst = d3; }
    else             { src = w4; dst = d4; }
    int c0 = blockIdx.x * 32, r0 = blockIdx.y * 32;
    int tx = threadIdx.x & 31, ty = threadIdx.x >> 5;
    for (int rr = ty; rr < 32; rr += 8)
        tile[rr][tx] = src[(long)(r0 + rr) * 512 + c0 + tx];
    __syncthreads();
    for (int cc = ty; cc < 32; cc += 8)
        dst[(long)(c0 + cc) * 512 + r0 + tx] = __float2bfloat16(tile[tx][cc]);
}

// sketch (phase fused): SK2 f32 = [dKre|dKim]; qcat bf16 = [Qre|Qim]; kcat bf16 = [dKre|-dKim]
__global__ __launch_bounds__(256) void sketch_kernel(const float* __restrict__ qkv,
                                                     const float* __restrict__ sign,
                                                     const float* __restrict__ scal,
                                                     const int* __restrict__ h,
                                                     float* __restrict__ SK2,
                                                     bf16* __restrict__ qcat,
                                                     bf16* __restrict__ kcat) {
    int bt = blockIdx.x;
    int tid = threadIdx.x;
    __shared__ float s0[M_], s1[M_], s2[M_], s3[M_];
    for (int j = tid; j < M_; j += 256) { s0[j] = 0.f; s1[j] = 0.f; s2[j] = 0.f; s3[j] = 0.f; }
    __syncthreads();
    int t = bt & 127;
    float thq = scal[0], thk = scal[1], omg = scal[2];
    float ft = (float)t;
    for (int i = tid; i < D_; i += 256) {
        float q = qkv[(long)bt * 1536 + i];
        float k = qkv[(long)bt * 1536 + 512 + i];
        float sg = sign[i];
        float sq_, cq_, sk_, ck_;
        __sincosf(thq * q - omg * ft, &sq_, &cq_);
        __sincosf(thk * k + omg * ft, &sk_, &ck_);
        int m = h[i];
        atomicAdd(&s0[m], q * cq_ * sg);
        atomicAdd(&s1[m], q * sq_ * sg);
        atomicAdd(&s2[m], k * ck_ * sg);
        atomicAdd(&s3[m], k * sk_ * sg);
    }
    __syncthreads();
    long ob = (long)bt * M_;
    long qb = (long)bt * 4096;
    for (int j = tid; j < M_; j += 256) {
        SK2[ob + j]                  = s2[j];
        SK2[(long)BT_ * M_ + ob + j] = s3[j];
        qcat[qb + j]        = __float2bfloat16(s0[j]);
        qcat[qb + 2048 + j] = __float2bfloat16(s1[j]);
        kcat[qb + j]        = __float2bfloat16(s2[j]);
        kcat[qb + 2048 + j] = __float2bfloat16(-s3[j]);
    }
}

// ---- two-phase exclusive prefix over t (4-way t split) ----
__global__ __launch_bounds__(256) void prefix_p1(const float* __restrict__ SK2,
                                                 float* __restrict__ qsum) {
    int idx = blockIdx.x * 256 + threadIdx.x;   // 131072
    int col = idx & 32767, q = idx >> 15;
    int m = col & 2047, b = (col >> 11) & 7, comp = col >> 14;
    const float* src = SK2 + (long)comp * BT_ * M_ + (long)b * T_ * M_ + (long)(q * 32) * M_ + m;
    float s = 0.f;
    #pragma unroll 8
    for (int i = 0; i < 32; ++i) s += src[(long)i * M_];
    qsum[(long)q * 32768 + col] = s;
}

// KP written as bf16 (only fwdfft reads it); kf_out stays f32
__global__ __launch_bounds__(256) void prefix_p2(const float* __restrict__ SK2,
                                                 const float* __restrict__ qsum,
                                                 bf16* __restrict__ KP16,
                                                 float* __restrict__ kf_out) {
    int idx = blockIdx.x * 256 + threadIdx.x;   // 131072
    int col = idx & 32767, q = idx >> 15;
    int m = col & 2047, b = (col >> 11) & 7, comp = col >> 14;
    long cb = (long)comp * BT_ * M_ + (long)b * T_ * M_ + m + (long)(q * 32) * M_;
    const float* src = SK2 + cb;
    bf16* dst = KP16 + cb;
    float acc = 0.f;
    for (int p = 0; p < q; ++p) acc += qsum[(long)p * 32768 + col];
    #pragma unroll 4
    for (int i = 0; i < 32; ++i) {
        dst[(long)i * M_] = __float2bfloat16(acc);
        acc += src[(long)i * M_];
    }
    if (q == 3) kf_out[((long)b * 2 + comp) * M_ + m] = acc;
}

// ==== in-place DIF forward FFT (scrambled output; order cancels because the
// frequency-domain GEMM B-operand uses the identical scramble) ====
#define PIDX(i) ((i) + ((i) >> 5))

// fused 3-stage radix-8 DIF pass on both (K,Q) arrays. Butterfly g=tid:
// elements base + r*S, base = (g/S)*8S + g%S. Twiddles all derived from w=W_{8S}^k.
template<int S>
__device__ __forceinline__ void dif8_pair(float* r0, float* i0a, float* r1, float* i1a, int tid) {
    int k = tid % S;
    int grp = tid / S;
    int base = grp * 8 * S + k;
    float sw, cw;
    __sincosf((float)k * (3.14159265358979323846f / (4.0f * (float)S)), &sw, &cw);
    float wr = cw, wi = -sw;                              // w = W_{8S}^k
    float w2r = wr * wr - wi * wi, w2i = 2.f * wr * wi;   // w^2
    float w4r = w2r * w2r - w2i * w2i, w4i = 2.f * w2r * w2i; // w^4
    const float RH = 0.70710678118654752440f;
    // stage-1 twiddles: w * W8^r, r=0..3  (W8 = e^{-i pi/4})
    float t1r[4] = {wr, (wr + wi) * RH, wi, (wi - wr) * RH};
    float t1i[4] = {wi, (wi - wr) * RH, -wr, -(wr + wi) * RH};
    // stage-2 twiddles: w^2, w^2*(-i)
    float u0r = w2r, u0i = w2i;
    float u1r = w2i, u1i = -w2r;
    #pragma unroll
    for (int a = 0; a < 2; ++a) {
        float* re = a ? r1 : r0;
        float* im = a ? i1a : i0a;
        float xr[8], xi[8];
        #pragma unroll
        for (int r = 0; r < 8; ++r) { int p = PIDX(base + r * S); xr[r] = re[p]; xi[r] = im[p]; }
        // stage 1: (r, r+4)
        #pragma unroll
        for (int r = 0; r < 4; ++r) {
            float ar = xr[r], ai = xi[r], br = xr[r + 4], bi = xi[r + 4];
            xr[r] = ar + br; xi[r] = ai + bi;
            float dr = ar - br, di = ai - bi;
            xr[r + 4] = dr * t1r[r] - di * t1i[r];
            xi[r + 4] = dr * t1i[r] + di * t1r[r];
        }
        // stage 2: within each half, (r, r+2)
        #pragma unroll
        for (int hb = 0; hb < 8; hb += 4) {
            #pragma unroll
            for (int r = 0; r < 2; ++r) {
                float tr = (r == 0) ? u0r : u1r, ti = (r == 0) ? u0i : u1i;
                float ar = xr[hb + r], ai = xi[hb + r], br = xr[hb + r + 2], bi = xi[hb + r + 2];
                xr[hb + r] = ar + br; xi[hb + r] = ai + bi;
                float dr = ar - br, di = ai - bi;
                xr[hb + r + 2] = dr * tr - di * ti;
                xi[hb + r + 2] = dr * ti + di * tr;
            }
        }
        // stage 3: (r, r+1), tw = w^4
        #pragma unroll
        for (int r = 0; r < 8; r += 2) {
            float ar = xr[r], ai = xi[r], br = xr[r + 1], bi = xi[r + 1];
            xr[r] = ar + br; xi[r] = ai + bi;
            float dr = ar - br, di = ai - bi;
            xr[r + 1] = dr * w4r - di * w4i;
            xi[r + 1] = dr * w4i + di * w4r;
        }
        #pragma unroll
        for (int r = 0; r < 8; ++r) { int p = PIDX(base + r * S); re[p] = xr[r]; im[p] = xi[r]; }
    }
}

template<int M>
__device__ __forceinline__ void dif_one(float* re, float* im, int tid) {
    #pragma unroll
    for (int u = 0; u < 4; ++u) {
        int q = u * 256 + tid;
        int k = q & (M - 1);
        int i = (q / M) * (2 * M) + k;
        float s, c;
        __sincosf((float)k * (3.14159265358979323846f / (float)M), &s, &c);
        int p0 = PIDX(i), p1 = PIDX(i + M);
        float ar = re[p0], ai = im[p0], br = re[p1], bi = im[p1];
        re[p0] = ar + br; im[p0] = ai + bi;
        float dr = ar - br, di = ai - bi;
        re[p1] = dr * c + di * s;
        im[p1] = di * c - dr * s;
    }
}

// forward FFTs of Q sketch and K prefix; pcat = [Re(FQ*FK) | Im(FQ*FK)] bf16 (scrambled order)
// Phase A: 2 radix-8 LDS passes (stages 1024..32). Phase B: 16,8 via shfl; 4,2,1 in regs.
__global__ __launch_bounds__(256) void fwdfft_kernel(const bf16* __restrict__ qcat,
                                                     const bf16* __restrict__ KP16,
                                                     bf16* __restrict__ pcat) {
    __shared__ float KRs[2112], KIs[2112], QRs[2112], QIs[2112];   // 33 KB
    int bt = blockIdx.x, tid = threadIdx.x;
    const unsigned short* qp = (const unsigned short*)(qcat + (long)bt * 4096);
    const unsigned short* kpr = (const unsigned short*)(KP16 + (long)bt * M_);
    const unsigned short* kpi = (const unsigned short*)(KP16 + (long)BT_ * M_ + (long)bt * M_);
    for (int u = 0; u < 8; ++u) {
        int j = u * 256 + tid;
        int pj = PIDX(j);
        KRs[pj] = b2f(kpr[j]);
        KIs[pj] = b2f(kpi[j]);
        QRs[pj] = b2f(qp[j]);
        QIs[pj] = b2f(qp[2048 + j]);
    }
    __syncthreads();
    dif8_pair<256>(KRs, KIs, QRs, QIs, tid);  __syncthreads();
    dif8_pair<32>(KRs, KIs, QRs, QIs, tid);   __syncthreads();

    // ---- Phase B: thread g owns elements [8g, 8g+8) ----
    float kr_[8], ki_[8], qr_[8], qi_[8];
    #pragma unroll
    for (int l = 0; l < 8; ++l) {
        int pj = PIDX(8 * tid + l);
        kr_[l] = KRs[pj]; ki_[l] = KIs[pj];
        qr_[l] = QRs[pj]; qi_[l] = QIs[pj];
    }

    const float C16[16] = {1.f, 0.98078528f, 0.92387953f, 0.83146961f,
                           0.70710678f, 0.55557023f, 0.38268343f, 0.19509032f,
                           0.f, -0.19509032f, -0.38268343f, -0.55557023f,
                           -0.70710678f, -0.83146961f, -0.92387953f, -0.98078528f};
    const float S16[16] = {0.f, 0.19509032f, 0.38268343f, 0.55557023f,
                           0.70710678f, 0.83146961f, 0.92387953f, 0.98078528f,
                           1.f, 0.98078528f, 0.92387953f, 0.83146961f,
                           0.70710678f, 0.55557023f, 0.38268343f, 0.19509032f};
    bool odd = (tid & 1) != 0;
    // stage M=16: partner lane^2, twiddle k = l + 8*(tid&1)
    {
        bool hi2 = (tid & 2) != 0;
        #pragma unroll
        for (int l = 0; l < 8; ++l) {
            float c = odd ? C16[l + 8] : C16[l];
            float s = odd ? S16[l + 8] : S16[l];
            float pr, pi2, sr, si, dr, di;
            pr = __shfl_xor(kr_[l], 2); pi2 = __shfl_xor(ki_[l], 2);
            sr = kr_[l] + pr; si = ki_[l] + pi2;
            dr = pr - kr_[l]; di = pi2 - ki_[l];
            kr_[l] = hi2 ? (dr * c + di * s) : sr;
            ki_[l] = hi2 ? (di * c - dr * s) : si;
            pr = __shfl_xor(qr_[l], 2); pi2 = __shfl_xor(qi_[l], 2);
            sr = qr_[l] + pr; si = qi_[l] + pi2;
            dr = pr - qr_[l]; di = pi2 - qi_[l];
            qr_[l] = hi2 ? (dr * c + di * s) : sr;
            qi_[l] = hi2 ? (di * c - dr * s) : si;
        }
    }
    // stage M=8: partner lane^1, twiddle k = l
    {
        #pragma unroll
        for (int l = 0; l < 8; ++l) {
            float c = C16[2 * l];
            float s = S16[2 * l];
            float pr, pi2, sr, si, dr, di;
            pr = __shfl_xor(kr_[l], 1); pi2 = __shfl_xor(ki_[l], 1);
            sr = kr_[l] + pr; si = ki_[l] + pi2;
            dr = pr - kr_[l]; di = pi2 - ki_[l];
            kr_[l] = odd ? (dr * c + di * s) : sr;
            ki_[l] = odd ? (di * c - dr * s) : si;
            pr = __shfl_xor(qr_[l], 1); pi2 = __shfl_xor(qi_[l], 1);
            sr = qr_[l] + pr; si = qi_[l] + pi2;
            dr = pr - qr_[l]; di = pi2 - qi_[l];
            qr_[l] = odd ? (dr * c + di * s) : sr;
            qi_[l] = odd ? (di * c - dr * s) : si;
        }
    }
    // stage M=4: pairs (l, l+4)
    {
        const float C4[4] = {1.f, 0.70710678f, 0.f, -0.70710678f};
        const float S4[4] = {0.f, 0.70710678f, 1.f, 0.70710678f};
        #pragma unroll
        for (int l = 0; l < 4; ++l) {
            float ar, ai, br, bi, dr, di;
            ar = kr_[l]; ai = ki_[l]; br = kr_[l + 4]; bi = ki_[l + 4];
            kr_[l] = ar + br; ki_[l] = ai + bi;
            dr = ar - br; di = ai - bi;
            kr_[l + 4] = dr * C4[l] + di * S4[l];
            ki_[l + 4] = di * C4[l] - dr * S4[l];
            ar = qr_[l]; ai = qi_[l]; br = qr_[l + 4]; bi = qi_[l + 4];
            qr_[l] = ar + br; qi_[l] = ai + bi;
            dr = ar - br; di = ai - bi;
            qr_[l + 4] = dr * C4[l] + di * S4[l];
            qi_[l + 4] = di * C4[l] - dr * S4[l];
        }
    }
    // stage M=2
    #pragma unroll
    for (int b2 = 0; b2 < 8; b2 += 4) {
        {
            float ar = kr_[b2], ai = ki_[b2], br = kr_[b2 + 2], bi = ki_[b2 + 2];
            kr_[b2] = ar + br; ki_[b2] = ai + bi;
            kr_[b2 + 2] = ar - br; ki_[b2 + 2] = ai - bi;
            ar = qr_[b2]; ai = qi_[b2]; br = qr_[b2 + 2]; bi = qi_[b2 + 2];
            qr_[b2] = ar + br; qi_[b2] = ai + bi;
            qr_[b2 + 2] = ar - br; qi_[b2 + 2] = ai - bi;
        }
        {
            float ar = kr_[b2 + 1], ai = ki_[b2 + 1], br = kr_[b2 + 3], bi = ki_[b2 + 3];
            kr_[b2 + 1] = ar + br; ki_[b2 + 1] = ai + bi;
            float dr = ar - br, di = ai - bi;
            kr_[b2 + 3] = di; ki_[b2 + 3] = -dr;
            ar = qr_[b2 + 1]; ai = qi_[b2 + 1]; br = qr_[b2 + 3]; bi = qi_[b2 + 3];
            qr_[b2 + 1] = ar + br; qi_[b2 + 1] = ai + bi;
            dr = ar - br; di = ai - bi;
            qr_[b2 + 3] = di; qi_[b2 + 3] = -dr;
        }
    }
    // stage M=1
    #pragma unroll
    for (int i0 = 0; i0 < 8; i0 += 2) {
        float ar = kr_[i0], ai = ki_[i0], br = kr_[i0 + 1], bi = ki_[i0 + 1];
        kr_[i0] = ar + br; ki_[i0] = ai + bi;
        kr_[i0 + 1] = ar - br; ki_[i0 + 1] = ai - bi;
        ar = qr_[i0]; ai = qi_[i0]; br = qr_[i0 + 1]; bi = qi_[i0 + 1];
        qr_[i0] = ar + br; qi_[i0] = ai + bi;
        qr_[i0 + 1] = ar - br; qi_[i0 + 1] = ai - bi;
    }

    // spectral product -> bf16
    unsigned short* op = (unsigned short*)(pcat + (long)bt * 4096 + 8 * tid);
    ushort8t ore, oim;
    #pragma unroll
    for (int l = 0; l < 8; ++l) {
        float pr = qr_[l] * kr_[l] - qi_[l] * ki_[l];
        float pi2 = qr_[l] * ki_[l] + qi_[l] * kr_[l];
        bf16 hr = __float2bfloat16(pr);
        bf16 hi = __float2bfloat16(pi2);
        ore[l] = *(unsigned short*)&hr;
        oim[l] = *(unsigned short*)&hi;
    }
    *(ushort8t*)op = ore;
    *(ushort8t*)(op + 2048) = oim;
}

// Ghat for column j of ro_w1: ro1f[j] = [Re FFT | Im FFT] (scrambled, same DIF) bf16
__global__ __launch_bounds__(256) void ro1fft_kernel(const float* __restrict__ ro_w1,
                                                     bf16* __restrict__ ro1f) {
    __shared__ float Rs[2112], Is[2112];
    int j = blockIdx.x, tid = threadIdx.x;
    for (int u = 0; u < 8; ++u) {
        int n = u * 256 + tid;
        Rs[PIDX(n)] = ro_w1[(long)n * HID_ + j];
        Is[PIDX(n)] = 0.f;
    }
    __syncthreads();
#define FSTEP(MM) dif_one<MM>(Rs, Is, tid); __syncthreads();
    FSTEP(1024) FSTEP(512) FSTEP(256) FSTEP(128) FSTEP(64)
    FSTEP(32) FSTEP(16) FSTEP(8) FSTEP(4) FSTEP(2) FSTEP(1)
#undef FSTEP
    unsigned short* op = (unsigned short*)(ro1f + (long)j * 4096);
    for (int u = 0; u < 8; ++u) {
        int r = u * 256 + tid;
        int pr = PIDX(r);
        bf16 re = __float2bfloat16(Rs[pr]);
        bf16 im = __float2bfloat16(Is[pr]);
        op[r]        = *(unsigned short*)&re;
        op[2048 + r] = *(unsigned short*)&im;
    }
}

// MFMA bf16 TN GEMM: C[M,N] = A * Bt^T. 64x64 tile, 4 waves.
// AMODE 0: A bf16. AMODE 1: A f32 + causal mask (row=t in [0,128), col k=tau; keep k<row).
// AMODE 2: A f32, value = gelu(a*scale(row&127) + abias[k]).
template<int FLAGS, int OUTB16, int AMODE>
__global__ __launch_bounds__(256) void gemm_mfma(
    const void* __restrict__ Av, const bf16* __restrict__ Bt,
    const float* __restrict__ bias, const float* __restrict__ abias,
    void* __restrict__ Cv,
    int K, int ldc, long abz, long bbz, long cbz, int splitk)
{
    __shared__ __align__(16) bf16 As[64][44];
    __shared__ __align__(16) bf16 Bs[64][44];
    int bz = blockIdx.z;
    int batch = bz, kslice = 0;
    if (FLAGS & FLAG_ATOMIC) { batch = bz / splitk; kslice = bz % splitk; }
    long aoff;
    const bf16* Bb;
    long coff;
    if (FLAGS & FLAG_HFB) {
        int b = bz & 7, c = bz >> 3;
        aoff = (long)b * abz + (long)blockIdx.y * 64 * K;
        Bb = Bt + (long)c * 2097152L + (long)b * 262144L + (long)blockIdx.x * 64 * K;
        coff = (long)b * 2097152L + (long)c * 1048576L;
    } else {
        aoff = (long)batch * abz + (long)blockIdx.y * 64 * K;
        Bb = Bt + (long)batch * bbz + (long)blockIdx.x * 64 * K;
        coff = (long)batch * cbz;
    }
    int tid = threadIdx.x;
    int lrow = tid >> 2;
    int lk = (tid & 3) * 8;
    int w = tid >> 6, lane = tid & 63;
    int wr = (w >> 1) * 32, wc = (w & 1) * 32;
    int fm = lane & 15, fk = (lane >> 4) * 8;
    f32x4 acc00 = {0.f,0.f,0.f,0.f}, acc01 = acc00, acc10 = acc00, acc11 = acc00;

    int klen = K / splitk;
    int k0 = kslice * klen;
    for (int kt = k0; kt < k0 + klen; kt += 32) {
        if (AMODE == 0) {
            const bf16* Ab = (const bf16*)Av + aoff;
            *(float4*)&As[lrow][lk] = *(const float4*)&Ab[(long)lrow * K + kt + lk];
        } else {
            const float* Af = (const float*)Av + aoff;
            int gk0 = kt + lk;
            float4 v0 = *(const float4*)&Af[(long)lrow * K + gk0];
            float4 v1 = *(const float4*)&Af[(long)lrow * K + gk0 + 4];
            float vv[8] = {v0.x, v0.y, v0.z, v0.w, v1.x, v1.y, v1.z, v1.w};
            int grow = blockIdx.y * 64 + lrow;
            float sc = 0.f;
            if (AMODE == 2) sc = rsqrtf((float)((grow & 127) + 1)) * (1.0f / 92681.900089f);
            #pragma unroll
            for (int j = 0; j < 8; ++j) {
                float val = vv[j];
                int gk = gk0 + j;
                if (AMODE == 1) val = (gk < grow) ? val : 0.f;
                if (AMODE == 2) val = gelu_f(val * sc + abias[gk]);
                As[lrow][lk + j] = __float2bfloat16(val);
            }
        }
        *(float4*)&Bs[lrow][lk] = *(const float4*)&Bb[(long)lrow * K + kt + lk];
        __syncthreads();
        short8t a0 = *(const short8t*)&As[wr + fm][fk];
        short8t a1 = *(const short8t*)&As[wr + 16 + fm][fk];
        short8t b0 = *(const short8t*)&Bs[wc + fm][fk];
        short8t b1 = *(const short8t*)&Bs[wc + 16 + fm][fk];
        acc00 = __builtin_amdgcn_mfma_f32_16x16x32_bf16(a0, b0, acc00, 0, 0, 0);
        acc01 = __builtin_amdgcn_mfma_f32_16x16x32_bf16(a0, b1, acc01, 0, 0, 0);
        acc10 = __builtin_amdgcn_mfma_f32_16x16x32_bf16(a1, b0, acc10, 0, 0, 0);
        acc11 = __builtin_amdgcn_mfma_f32_16x16x32_bf16(a1, b1, acc11, 0, 0, 0);
        __syncthreads();
    }

    float* Cf = (float*)Cv;
    bf16* Cb = (bf16*)Cv;
    int row_base = blockIdx.y * 64 + wr + (lane >> 4) * 4;
    int col_base = blockIdx.x * 64 + wc + fm;
    #pragma unroll
    for (int fr = 0; fr < 2; ++fr) {
        #pragma unroll
        for (int fc = 0; fc < 2; ++fc) {
            const f32x4& a = fr == 0 ? (fc == 0 ? acc00 : acc01) : (fc == 0 ? acc10 : acc11);
            #pragma unroll
            for (int r = 0; r < 4; ++r) {
                int gi = row_base + fr * 16 + r;
                int gj = col_base + fc * 16;
                float v = a[r];
                long ci = coff + (long)gi * ldc + gj;
                if (FLAGS & FLAG_ATOMIC) {
                    atomicAdd(&Cf[ci], v);
                } else {
                    if (FLAGS & FLAG_BIAS) v += bias[gj];
                    if (FLAGS & FLAG_GELU) v = gelu_f(v);
                    if (FLAGS & FLAG_ROWSCALE) v *= rsqrtf((float)(gi & 127) + 1.0f);
                    if (OUTB16) Cb[ci] = __float2bfloat16(v);
                    else        Cf[ci] = v;
                }
            }
        }
    }
}

// LN over D=512. FINAL=0: LN(x1); FINAL=1: LN(x1 + gf*x2 + gv*x3). OB16 selects out dtype.
template<int FINAL, int OB16>
__global__ __launch_bounds__(256) void ln_kernel(const float* __restrict__ x1,
                                                 const float* __restrict__ x2,
                                                 const float* __restrict__ x3,
                                                 const float* __restrict__ g,
                                                 const float* __restrict__ bb,
                                                 const float* __restrict__ scal,
                                                 void* __restrict__ outv) {
    int row = blockIdx.x, tid = threadIdx.x;
    long base = (long)row * D_;
    int d0 = tid, d1 = tid + 256;
    float v0, v1;
    if (FINAL) {
        float gf = scal[3], gv = scal[4];
        v0 = x1[base + d0] + gf * x2[base + d0] + gv * x3[base + d0];
        v1 = x1[base + d1] + gf * x2[base + d1] + gv * x3[base + d1];
    } else {
        v0 = x1[base + d0];
        v1 = x1[base + d1];
    }
    float s = v0 + v1;
    #pragma unroll
    for (int o = 32; o > 0; o >>= 1) s += __shfl_down(s, o);
    __shared__ float red[8];
    int wid = tid >> 6, lane = tid & 63;
    if (lane == 0) red[wid] = s;
    __syncthreads();
    float mu = (red[0] + red[1] + red[2] + red[3]) * (1.0f / D_);
    float e0 = v0 - mu, e1 = v1 - mu;
    float sq = e0 * e0 + e1 * e1;
    #pragma unroll
    for (int o = 32; o > 0; o >>= 1) sq += __shfl_down(sq, o);
    if (lane == 0) red[4 + wid] = sq;
    __syncthreads();
    float var = (red[4] + red[5] + red[6] + red[7]) * (1.0f / D_);
    float rs = rsqrtf(var + 1e-5f);
    float o0 = e0 * rs * g[d0] + bb[d0];
    float o1 = e1 * rs * g[d1] + bb[d1];
    if (OB16) {
        ((bf16*)outv)[base + d0] = __float2bfloat16(o0);
        ((bf16*)outv)[base + d1] = __float2bfloat16(o1);
    } else {
        ((float*)outv)[base + d0] = o0;
        ((float*)outv)[base + d1] = o1;
    }
}

extern "C" void kernel_launch(void* const* d_in, const int* in_sizes, int n_in,
                              void* d_out, int out_size, void* d_ws, size_t ws_size,
                              hipStream_t stream) {
    const float* e      = (const float*)d_in[0];
    const int*   h      = (const int*)d_in[1];
    const float* sign   = (const float*)d_in[2];
    const float* Wq     = (const float*)d_in[3];
    const float* Wk     = (const float*)d_in[4];
    const float* Wv     = (const float*)d_in[5];
    const float* ro_w1  = (const float*)d_in[6];
    const float* ro_b1  = (const float*)d_in[7];
    const float* ro_w2  = (const float*)d_in[8];
    const float* ro_b2  = (const float*)d_in[9];
    const float* vp_ln_g= (const float*)d_in[10];
    const float* vp_ln_b= (const float*)d_in[11];
    const float* vp_w1  = (const float*)d_in[12];
    const float* vp_b1  = (const float*)d_in[13];
    const float* vp_w2  = (const float*)d_in[14];
    const float* vp_b2  = (const float*)d_in[15];
    const float* ln_g   = (const float*)d_in[16];
    const float* ln_b   = (const float*)d_in[17];
    const float* tq     = (const float*)d_in[18];
    const float* tk     = (const float*)d_in[19];
    const float* om     = (const float*)d_in[20];
    const float* gfr    = (const float*)d_in[21];
    const float* gvr    = (const float*)d_in[22];

    float* ws    = (float*)d_ws;
    float* scal  = ws + OFF_SCAL;
    float* qkv   = ws + OFF_QKV;
    float* sk2   = ws + OFF_SK2;
    float* vraw  = ws + OFF_VRAW;
    float* vf    = ws + OFF_VF;
    float* hfeat = ws + OFF_HFEAT;
    float* scoacc= ws + OFF_SCOA;
    float* qsum  = ws + OFF_QSUM;
    float* hacc  = ws + OFF_HACC;
    bf16* kp16  = (bf16*)(ws + OFF_KP);
    bf16* eb    = (bf16*)(ws + OFF_EB);
    bf16* wqkvT = (bf16*)(ws + OFF_WQKVT);
    bf16* vp1T  = (bf16*)(ws + OFF_VP1T);
    bf16* vp2T  = (bf16*)(ws + OFF_VP2T);
    bf16* ro2T  = (bf16*)(ws + OFF_RO2T);
    bf16* qcat  = (bf16*)(ws + OFF_QCAT);
    bf16* kcat  = (bf16*)(ws + OFF_KCAT);
    bf16* dkT   = (bf16*)(ws + OFF_DKT);
    bf16* vTb   = (bf16*)(ws + OFF_VTB);
    bf16* vlnb  = (bf16*)(ws + OFF_VLNB);
    bf16* v1b   = (bf16*)(ws + OFF_V1B);
    bf16* pcat  = (bf16*)(ws + OFF_PCAT);
    bf16* ro1f  = (bf16*)(ws + OFF_RO1F);

    float* ys = (float*)d_out;
    float* kf = ys + (long)BT_ * D_;
    float* hf = kf + (long)B_ * 2 * M_;

    scal_kernel<<<1, 64, 0, stream>>>(tq, tk, om, gfr, gvr, scal);
    hipMemsetAsync(scoacc, 0, (size_t)B_ * T_ * T_ * 4, stream);
    hipMemsetAsync(hacc, 0, (size_t)BT_ * HID_ * 4, stream);

    // bf16 operand prep
    cast_kernel<<<2048, 256, 0, stream>>>(e, eb, BT_ * D_);
    castT5_kernel<<<dim3(16, 16, 5), 256, 0, stream>>>(
        Wq, Wk, Wv, vp_w1, vp_w2,
        wqkvT, wqkvT + 262144, wqkvT + 524288, vp1T, vp2T);
    castT_kernel<<<dim3(16, 4, 1), 256, 0, stream>>>(ro_w2, ro2T, 128, 512, 512, 0, 0);
    ro1fft_kernel<<<128, 256, 0, stream>>>(ro_w1, ro1f);

    // qkv = e @ [Wq|Wk|Wv]  (1024 x 1536 x 512) -> f32
    gemm_mfma<0, 0, 0><<<dim3(24, 16, 1), 256, 0, stream>>>(
        eb, wqkvT, nullptr, nullptr, qkv, 512, 1536, 0, 0, 0, 1);

    sketch_kernel<<<1024, 256, 0, stream>>>(qkv, sign, scal, h, sk2, qcat, kcat);
    prefix_p1<<<512, 256, 0, stream>>>(sk2, qsum);
    prefix_p2<<<512, 256, 0, stream>>>(sk2, qsum, kp16, kf);

    // forward FFTs + spectral product (no inverse; scrambled order matches ro1f)
    fwdfft_kernel<<<1024, 256, 0, stream>>>(qcat, kp16, pcat);

    // transposed bf16 copies (fused: z = comp*8 + b works because comp stride = 8*b stride)
    castT_kernel<<<dim3(64, 4, 16), 256, 0, stream>>>(sk2, dkT, 128, 2048, 2048, 262144, 262144);
    castT_kernel<<<dim3(16, 4, 8), 256, 0, stream>>>(qkv + 1024, vTb, 128, 512, 1536, 196608, 65536);

    // scores: split-K 16, f32 atomic accumulate (grid 2x2x128 = 512 blocks)
    gemm_mfma<FLAG_ATOMIC, 0, 0><<<dim3(2, 2, 128), 256, 0, stream>>>(
        qcat, kcat, nullptr, nullptr, scoacc, 4096, 128, 524288, 524288, 16384, 16);

    // vraw[b] = masked(scores) @ v * rsqrt(t+1)  (128x512x128) -> f32 (mask fused in A-load)
    gemm_mfma<FLAG_ROWSCALE, 0, 1><<<dim3(8, 2, 8), 256, 0, stream>>>(
        scoacc, vTb, nullptr, nullptr, vraw, 128, 512, 16384, 65536, 65536, 1);

    ln_kernel<0, 1><<<1024, 256, 0, stream>>>(vraw, nullptr, nullptr, vp_ln_g, vp_ln_b, scal, vlnb);

    // vp MLP
    gemm_mfma<FLAG_BIAS | FLAG_GELU, 1, 0><<<dim3(8, 16, 1), 256, 0, stream>>>(
        vlnb, vp1T, vp_b1, nullptr, v1b, 512, 512, 0, 0, 0, 1);
    gemm_mfma<FLAG_BIAS, 0, 0><<<dim3(8, 16, 1), 256, 0, stream>>>(
        v1b, vp2T, vp_b2, nullptr, vf, 512, 512, 0, 0, 0, 1);

    // hid_pre = pcat @ ro1f^T (1024x128x4096), split-K 8 atomic into hacc
    gemm_mfma<FLAG_ATOMIC, 0, 0><<<dim3(2, 16, 8), 256, 0, stream>>>(
        pcat, ro1f, nullptr, nullptr, hacc, 4096, 128, 0, 0, 0, 8);

    // hfeat = gelu(hacc*scale+b1) @ ro_w2 + b2 (1024x512x128); hid epilogue fused in A-load
    gemm_mfma<FLAG_BIAS, 0, 2><<<dim3(8, 16, 1), 256, 0, stream>>>(
        hacc, ro2T, ro_b2, ro_b1, hfeat, 128, 512, 0, 0, 0, 1);

    // ys = LN(e + gf*hfeat + gv*vf)
    ln_kernel<1, 0><<<1024, 256, 0, stream>>>(e, hfeat, vf, ln_g, ln_b, scal, ys);

    // Hf fused: z in [0,16), b=z&7, c=z>>3
    gemm_mfma<FLAG_HFB, 0, 0><<<dim3(32, 8, 16), 256, 0, stream>>>(
        vTb, dkT, nullptr, nullptr, hf, 128, 2048, 65536, 0, 0, 1);
}

// Round 11
// 159.503 us; speedup vs baseline: 1.9302x; 1.0795x over previous
//
#include <hip/hip_runtime.h>
#include <hip/hip_bf16.h>
#include <math.h>

#define B_   8
#define T_   128
#define D_   512
#define M_   2048
#define HID_ 128
#define BT_  1024

typedef __attribute__((ext_vector_type(8))) short short8t;
typedef __attribute__((ext_vector_type(8))) unsigned short ushort8t;
typedef __attribute__((ext_vector_type(4))) unsigned short ushort4t;
typedef __attribute__((ext_vector_type(4))) float f32x4;
typedef __hip_bfloat16 bf16;

// ws layout (float offsets; all multiples of 16 -> 64B aligned)
#define OFF_SCAL   0L
#define OFF_QKV    16L                            // 1024*1536 f32
#define OFF_SK2    (OFF_QKV + 1572864L)           // [dKre|dKim] f32, 2*BT*M
#define OFF_KP     (OFF_SK2 + 4194304L)           // [KR|KI] bf16 exclusive prefix (2*BT*M bf16)
#define OFF_VRAW   (OFF_KP + 4194304L)
#define OFF_VF     (OFF_VRAW + 524288L)
#define OFF_HFEAT  (OFF_VF + 524288L)
// bf16 buffers (size in floats = elems/2)
#define OFF_EB     (OFF_HFEAT + 524288L)          // 1024x512
#define OFF_WQKVT  (OFF_EB + 262144L)             // 1536x512
#define OFF_VP1T   (OFF_WQKVT + 393216L)          // 512x512
#define OFF_VP2T   (OFF_VP1T + 131072L)
#define OFF_RO2T   (OFF_VP2T + 131072L)           // 512x128
#define OFF_QCAT   (OFF_RO2T + 32768L)            // 1024x4096
#define OFF_KCAT   (OFF_QCAT + 2097152L)          // 1024x4096
#define OFF_DKT    (OFF_KCAT + 2097152L)          // 2x8x2048x128
#define OFF_VTB    (OFF_DKT + 2097152L)           // 8x512x128
#define OFF_VLNB   (OFF_VTB + 262144L)            // 1024x512
#define OFF_V1B    (OFF_VLNB + 262144L)           // 1024x512
#define OFF_SCOA   (OFF_V1B + 262144L)            // 8x128x128 f32 split-K accumulator
#define OFF_QSUM   (OFF_SCOA + 131072L)           // 4x32768 f32 prefix quarter sums
#define OFF_PCAT   (OFF_QSUM + 131072L)           // 1024x4096 bf16 [ReP|ImP]
#define OFF_RO1F   (OFF_PCAT + 2097152L)          // 128x4096 bf16 [ReG|ImG]
#define OFF_HACC   (OFF_RO1F + 262144L)           // 1024x128 f32

#define FLAG_BIAS     1
#define FLAG_GELU     2
#define FLAG_ROWSCALE 4
#define FLAG_ATOMIC   8
#define FLAG_HFB      32
#define FLAG_TRI      64

__device__ __forceinline__ float gelu_f(float x) {
    return 0.5f * x * (1.0f + erff(x * 0.70710678118654752440f));
}

__device__ __forceinline__ float b2f(unsigned short u) {
    return __uint_as_float(((unsigned int)u) << 16);
}

// scalars + zero scoacc (131072 f32) + hacc (131072 f32). grid 1024x256.
__global__ __launch_bounds__(256) void scal_zero_kernel(const float* tq, const float* tk,
                                                        const float* om, const float* gf,
                                                        const float* gv, float* scal,
                                                        float* scoacc, float* hacc) {
    int idx = blockIdx.x * 256 + threadIdx.x;
    if (idx < 131072) scoacc[idx] = 0.f;
    else hacc[idx - 131072] = 0.f;
    if (idx == 0) {
        scal[0] = 0.5f * tanhf(tq[0]);
        scal[1] = 0.5f * tanhf(tk[0]);
        scal[2] = 0.5f * tanhf(om[0]);
        scal[3] = 0.25f / (1.0f + expf(-gf[0]));
        scal[4] = 0.25f / (1.0f + expf(-gv[0]));
    }
}

// vectorized f32 -> bf16 cast, 4 elems/thread
__global__ __launch_bounds__(256) void cast4_kernel(const float4* __restrict__ in,
                                                    ushort4t* __restrict__ out, int n4) {
    int i = blockIdx.x * 256 + threadIdx.x;
    if (i >= n4) return;
    float4 v = in[i];
    ushort4t o;
    bf16 h0 = __float2bfloat16(v.x), h1 = __float2bfloat16(v.y);
    bf16 h2 = __float2bfloat16(v.z), h3 = __float2bfloat16(v.w);
    o[0] = *(unsigned short*)&h0; o[1] = *(unsigned short*)&h1;
    o[2] = *(unsigned short*)&h2; o[3] = *(unsigned short*)&h3;
    out[i] = o;
}

// tiled transpose-cast: in f32 [R][C] (ld_in, batch bs_in) -> out bf16 [C][R] (batch bs_out)
__global__ __launch_bounds__(256) void castT_kernel(const float* __restrict__ in,
                                                    bf16* __restrict__ out,
                                                    int R, int C, int ld_in,
                                                    long bs_in, long bs_out) {
    __shared__ float tile[32][33];
    int b = blockIdx.z;
    int c0 = blockIdx.x * 32, r0 = blockIdx.y * 32;
    int tx = threadIdx.x & 31, ty = threadIdx.x >> 5;
    for (int rr = ty; rr < 32; rr += 8) {
        int r = r0 + rr, c = c0 + tx;
        tile[rr][tx] = (r < R && c < C) ? in[(long)b * bs_in + (long)r * ld_in + c] : 0.f;
    }
    __syncthreads();
    for (int cc = ty; cc < 32; cc += 8) {
        int c = c0 + cc, r = r0 + tx;
        if (c < C && r < R) out[(long)b * bs_out + (long)c * R + r] = __float2bfloat16(tile[tx][cc]);
    }
}

// batched transpose-cast for 6 weights in one launch (z=5 is 128x512 ro_w2)
__global__ __launch_bounds__(256) void castT6_kernel(const float* w0, const float* w1,
                                                     const float* w2, const float* w3,
                                                     const float* w4, const float* w5,
                                                     bf16* d0, bf16* d1, bf16* d2,
                                                     bf16* d3, bf16* d4, bf16* d5) {
    __shared__ float tile[32][33];
    int z = blockIdx.z;
    const float* src; bf16* dst; int R = 512;
    if (z == 0)      { src = w0; dst = d0; }
    else if (z == 1) { src = w1; dst = d1; }
    else if (z == 2) { src = w2; dst = d2; }
    else if (z == 3) { src = w3; dst = d3; }
    else if (z == 4) { src = w4; dst = d4; }
    else             { src = w5; dst = d5; R = 128; }
    int c0 = blockIdx.x * 32, r0 = blockIdx.y * 32;
    if (r0 >= R) return;
    int tx = threadIdx.x & 31, ty = threadIdx.x >> 5;
    for (int rr = ty; rr < 32; rr += 8) {
        int r = r0 + rr;
        tile[rr][tx] = (r < R) ? src[(long)r * 512 + c0 + tx] : 0.f;
    }
    __syncthreads();
    int r = r0 + tx;
    if (r < R)
        for (int cc = ty; cc < 32; cc += 8)
            dst[(long)(c0 + cc) * R + r] = __float2bfloat16(tile[tx][cc]);
}

// sketch (phase fused): SK2 f32 = [dKre|dKim]; qcat bf16 = [Qre|Qim]; kcat bf16 = [dKre|-dKim]
__global__ __launch_bounds__(256) void sketch_kernel(const float* __restrict__ qkv,
                                                     const float* __restrict__ sign,
                                                     const float* __restrict__ scal,
                                                     const int* __restrict__ h,
                                                     float* __restrict__ SK2,
                                                     bf16* __restrict__ qcat,
                                                     bf16* __restrict__ kcat) {
    int bt = blockIdx.x;
    int tid = threadIdx.x;
    __shared__ float s0[M_], s1[M_], s2[M_], s3[M_];
    for (int j = tid; j < M_; j += 256) { s0[j] = 0.f; s1[j] = 0.f; s2[j] = 0.f; s3[j] = 0.f; }
    __syncthreads();
    int t = bt & 127;
    float thq = scal[0], thk = scal[1], omg = scal[2];
    float ft = (float)t;
    for (int i = tid; i < D_; i += 256) {
        float q = qkv[(long)bt * 1536 + i];
        float k = qkv[(long)bt * 1536 + 512 + i];
        float sg = sign[i];
        float sq_, cq_, sk_, ck_;
        __sincosf(thq * q - omg * ft, &sq_, &cq_);
        __sincosf(thk * k + omg * ft, &sk_, &ck_);
        int m = h[i];
        atomicAdd(&s0[m], q * cq_ * sg);
        atomicAdd(&s1[m], q * sq_ * sg);
        atomicAdd(&s2[m], k * ck_ * sg);
        atomicAdd(&s3[m], k * sk_ * sg);
    }
    __syncthreads();
    long ob = (long)bt * M_;
    long qb = (long)bt * 4096;
    for (int j = tid; j < M_; j += 256) {
        SK2[ob + j]                  = s2[j];
        SK2[(long)BT_ * M_ + ob + j] = s3[j];
        qcat[qb + j]        = __float2bfloat16(s0[j]);
        qcat[qb + 2048 + j] = __float2bfloat16(s1[j]);
        kcat[qb + j]        = __float2bfloat16(s2[j]);
        kcat[qb + 2048 + j] = __float2bfloat16(-s3[j]);
    }
}

// ---- two-phase exclusive prefix over t (4-way t split) ----
__global__ __launch_bounds__(256) void prefix_p1(const float* __restrict__ SK2,
                                                 float* __restrict__ qsum) {
    int idx = blockIdx.x * 256 + threadIdx.x;   // 131072
    int col = idx & 32767, q = idx >> 15;
    int m = col & 2047, b = (col >> 11) & 7, comp = col >> 14;
    const float* src = SK2 + (long)comp * BT_ * M_ + (long)b * T_ * M_ + (long)(q * 32) * M_ + m;
    float s = 0.f;
    #pragma unroll 8
    for (int i = 0; i < 32; ++i) s += src[(long)i * M_];
    qsum[(long)q * 32768 + col] = s;
}

// KP written as bf16; also emits dkT[c][b][m][t] bf16 (t-contiguous per thread)
__global__ __launch_bounds__(256) void prefix_p2(const float* __restrict__ SK2,
                                                 const float* __restrict__ qsum,
                                                 bf16* __restrict__ KP16,
                                                 bf16* __restrict__ dkT,
                                                 float* __restrict__ kf_out) {
    int idx = blockIdx.x * 256 + threadIdx.x;   // 131072
    int col = idx & 32767, q = idx >> 15;
    int m = col & 2047, b = (col >> 11) & 7, comp = col >> 14;
    long cb = (long)comp * BT_ * M_ + (long)b * T_ * M_ + m + (long)(q * 32) * M_;
    const float* src = SK2 + cb;
    bf16* dst = KP16 + cb;
    bf16* dkt = dkT + (long)comp * 2097152L + (long)b * 262144L + (long)m * 128L + (long)(q * 32);
    float acc = 0.f;
    for (int p = 0; p < q; ++p) acc += qsum[(long)p * 32768 + col];
    #pragma unroll 4
    for (int i = 0; i < 32; ++i) {
        float v = src[(long)i * M_];
        dst[(long)i * M_] = __float2bfloat16(acc);
        dkt[i] = __float2bfloat16(v);
        acc += v;
    }
    if (q == 3) kf_out[((long)b * 2 + comp) * M_ + m] = acc;
}

// ==== in-place DIF forward FFT (scrambled output; order cancels because the
// frequency-domain GEMM B-operand uses the identical scramble) ====
#define PIDX(i) ((i) + ((i) >> 5))

// fused 3-stage radix-8 DIF pass on both (K,Q) arrays.
template<int S>
__device__ __forceinline__ void dif8_pair(float* r0, float* i0a, float* r1, float* i1a, int tid) {
    int k = tid % S;
    int grp = tid / S;
    int base = grp * 8 * S + k;
    float sw, cw;
    __sincosf((float)k * (3.14159265358979323846f / (4.0f * (float)S)), &sw, &cw);
    float wr = cw, wi = -sw;
    float w2r = wr * wr - wi * wi, w2i = 2.f * wr * wi;
    float w4r = w2r * w2r - w2i * w2i, w4i = 2.f * w2r * w2i;
    const float RH = 0.70710678118654752440f;
    float t1r[4] = {wr, (wr + wi) * RH, wi, (wi - wr) * RH};
    float t1i[4] = {wi, (wi - wr) * RH, -wr, -(wr + wi) * RH};
    float u0r = w2r, u0i = w2i;
    float u1r = w2i, u1i = -w2r;
    #pragma unroll
    for (int a = 0; a < 2; ++a) {
        float* re = a ? r1 : r0;
        float* im = a ? i1a : i0a;
        float xr[8], xi[8];
        #pragma unroll
        for (int r = 0; r < 8; ++r) { int p = PIDX(base + r * S); xr[r] = re[p]; xi[r] = im[p]; }
        #pragma unroll
        for (int r = 0; r < 4; ++r) {
            float ar = xr[r], ai = xi[r], br = xr[r + 4], bi = xi[r + 4];
            xr[r] = ar + br; xi[r] = ai + bi;
            float dr = ar - br, di = ai - bi;
            xr[r + 4] = dr * t1r[r] - di * t1i[r];
            xi[r + 4] = dr * t1i[r] + di * t1r[r];
        }
        #pragma unroll
        for (int hb = 0; hb < 8; hb += 4) {
            #pragma unroll
            for (int r = 0; r < 2; ++r) {
                float tr = (r == 0) ? u0r : u1r, ti = (r == 0) ? u0i : u1i;
                float ar = xr[hb + r], ai = xi[hb + r], br = xr[hb + r + 2], bi = xi[hb + r + 2];
                xr[hb + r] = ar + br; xi[hb + r] = ai + bi;
                float dr = ar - br, di = ai - bi;
                xr[hb + r + 2] = dr * tr - di * ti;
                xi[hb + r + 2] = dr * ti + di * tr;
            }
        }
        #pragma unroll
        for (int r = 0; r < 8; r += 2) {
            float ar = xr[r], ai = xi[r], br = xr[r + 1], bi = xi[r + 1];
            xr[r] = ar + br; xi[r] = ai + bi;
            float dr = ar - br, di = ai - bi;
            xr[r + 1] = dr * w4r - di * w4i;
            xi[r + 1] = dr * w4i + di * w4r;
        }
        #pragma unroll
        for (int r = 0; r < 8; ++r) { int p = PIDX(base + r * S); re[p] = xr[r]; im[p] = xi[r]; }
    }
}

template<int M>
__device__ __forceinline__ void dif_one(float* re, float* im, int tid) {
    #pragma unroll
    for (int u = 0; u < 4; ++u) {
        int q = u * 256 + tid;
        int k = q & (M - 1);
        int i = (q / M) * (2 * M) + k;
        float s, c;
        __sincosf((float)k * (3.14159265358979323846f / (float)M), &s, &c);
        int p0 = PIDX(i), p1 = PIDX(i + M);
        float ar = re[p0], ai = im[p0], br = re[p1], bi = im[p1];
        re[p0] = ar + br; im[p0] = ai + bi;
        float dr = ar - br, di = ai - bi;
        re[p1] = dr * c + di * s;
        im[p1] = di * c - dr * s;
    }
}

// forward FFTs of Q sketch and K prefix; pcat = [Re(FQ*FK) | Im(FQ*FK)] bf16 (scrambled order)
__global__ __launch_bounds__(256) void fwdfft_kernel(const bf16* __restrict__ qcat,
                                                     const bf16* __restrict__ KP16,
                                                     bf16* __restrict__ pcat) {
    __shared__ float KRs[2112], KIs[2112], QRs[2112], QIs[2112];   // 33 KB
    int bt = blockIdx.x, tid = threadIdx.x;
    const unsigned short* qp = (const unsigned short*)(qcat + (long)bt * 4096);
    const unsigned short* kpr = (const unsigned short*)(KP16 + (long)bt * M_);
    const unsigned short* kpi = (const unsigned short*)(KP16 + (long)BT_ * M_ + (long)bt * M_);
    for (int u = 0; u < 8; ++u) {
        int j = u * 256 + tid;
        int pj = PIDX(j);
        KRs[pj] = b2f(kpr[j]);
        KIs[pj] = b2f(kpi[j]);
        QRs[pj] = b2f(qp[j]);
        QIs[pj] = b2f(qp[2048 + j]);
    }
    __syncthreads();
    dif8_pair<256>(KRs, KIs, QRs, QIs, tid);  __syncthreads();
    dif8_pair<32>(KRs, KIs, QRs, QIs, tid);   __syncthreads();

    float kr_[8], ki_[8], qr_[8], qi_[8];
    #pragma unroll
    for (int l = 0; l < 8; ++l) {
        int pj = PIDX(8 * tid + l);
        kr_[l] = KRs[pj]; ki_[l] = KIs[pj];
        qr_[l] = QRs[pj]; qi_[l] = QIs[pj];
    }

    const float C16[16] = {1.f, 0.98078528f, 0.92387953f, 0.83146961f,
                           0.70710678f, 0.55557023f, 0.38268343f, 0.19509032f,
                           0.f, -0.19509032f, -0.38268343f, -0.55557023f,
                           -0.70710678f, -0.83146961f, -0.92387953f, -0.98078528f};
    const float S16[16] = {0.f, 0.19509032f, 0.38268343f, 0.55557023f,
                           0.70710678f, 0.83146961f, 0.92387953f, 0.98078528f,
                           1.f, 0.98078528f, 0.92387953f, 0.83146961f,
                           0.70710678f, 0.55557023f, 0.38268343f, 0.19509032f};
    bool odd = (tid & 1) != 0;
    {
        bool hi2 = (tid & 2) != 0;
        #pragma unroll
        for (int l = 0; l < 8; ++l) {
            float c = odd ? C16[l + 8] : C16[l];
            float s = odd ? S16[l + 8] : S16[l];
            float pr, pi2, sr, si, dr, di;
            pr = __shfl_xor(kr_[l], 2); pi2 = __shfl_xor(ki_[l], 2);
            sr = kr_[l] + pr; si = ki_[l] + pi2;
            dr = pr - kr_[l]; di = pi2 - ki_[l];
            kr_[l] = hi2 ? (dr * c + di * s) : sr;
            ki_[l] = hi2 ? (di * c - dr * s) : si;
            pr = __shfl_xor(qr_[l], 2); pi2 = __shfl_xor(qi_[l], 2);
            sr = qr_[l] + pr; si = qi_[l] + pi2;
            dr = pr - qr_[l]; di = pi2 - qi_[l];
            qr_[l] = hi2 ? (dr * c + di * s) : sr;
            qi_[l] = hi2 ? (di * c - dr * s) : si;
        }
    }
    {
        #pragma unroll
        for (int l = 0; l < 8; ++l) {
            float c = C16[2 * l];
            float s = S16[2 * l];
            float pr, pi2, sr, si, dr, di;
            pr = __shfl_xor(kr_[l], 1); pi2 = __shfl_xor(ki_[l], 1);
            sr = kr_[l] + pr; si = ki_[l] + pi2;
            dr = pr - kr_[l]; di = pi2 - ki_[l];
            kr_[l] = odd ? (dr * c + di * s) : sr;
            ki_[l] = odd ? (di * c - dr * s) : si;
            pr = __shfl_xor(qr_[l], 1); pi2 = __shfl_xor(qi_[l], 1);
            sr = qr_[l] + pr; si = qi_[l] + pi2;
            dr = pr - qr_[l]; di = pi2 - qi_[l];
            qr_[l] = odd ? (dr * c + di * s) : sr;
            qi_[l] = odd ? (di * c - dr * s) : si;
        }
    }
    {
        const float C4[4] = {1.f, 0.70710678f, 0.f, -0.70710678f};
        const float S4[4] = {0.f, 0.70710678f, 1.f, 0.70710678f};
        #pragma unroll
        for (int l = 0; l < 4; ++l) {
            float ar, ai, br, bi, dr, di;
            ar = kr_[l]; ai = ki_[l]; br = kr_[l + 4]; bi = ki_[l + 4];
            kr_[l] = ar + br; ki_[l] = ai + bi;
            dr = ar - br; di = ai - bi;
            kr_[l + 4] = dr * C4[l] + di * S4[l];
            ki_[l + 4] = di * C4[l] - dr * S4[l];
            ar = qr_[l]; ai = qi_[l]; br = qr_[l + 4]; bi = qi_[l + 4];
            qr_[l] = ar + br; qi_[l] = ai + bi;
            dr = ar - br; di = ai - bi;
            qr_[l + 4] = dr * C4[l] + di * S4[l];
            qi_[l + 4] = di * C4[l] - dr * S4[l];
        }
    }
    #pragma unroll
    for (int b2 = 0; b2 < 8; b2 += 4) {
        {
            float ar = kr_[b2], ai = ki_[b2], br = kr_[b2 + 2], bi = ki_[b2 + 2];
            kr_[b2] = ar + br; ki_[b2] = ai + bi;
            kr_[b2 + 2] = ar - br; ki_[b2 + 2] = ai - bi;
            ar = qr_[b2]; ai = qi_[b2]; br = qr_[b2 + 2]; bi = qi_[b2 + 2];
            qr_[b2] = ar + br; qi_[b2] = ai + bi;
            qr_[b2 + 2] = ar - br; qi_[b2 + 2] = ai - bi;
        }
        {
            float ar = kr_[b2 + 1], ai = ki_[b2 + 1], br = kr_[b2 + 3], bi = ki_[b2 + 3];
            kr_[b2 + 1] = ar + br; ki_[b2 + 1] = ai + bi;
            float dr = ar - br, di = ai - bi;
            kr_[b2 + 3] = di; ki_[b2 + 3] = -dr;
            ar = qr_[b2 + 1]; ai = qi_[b2 + 1]; br = qr_[b2 + 3]; bi = qi_[b2 + 3];
            qr_[b2 + 1] = ar + br; qi_[b2 + 1] = ai + bi;
            dr = ar - br; di = ai - bi;
            qr_[b2 + 3] = di; qi_[b2 + 3] = -dr;
        }
    }
    #pragma unroll
    for (int i0 = 0; i0 < 8; i0 += 2) {
        float ar = kr_[i0], ai = ki_[i0], br = kr_[i0 + 1], bi = ki_[i0 + 1];
        kr_[i0] = ar + br; ki_[i0] = ai + bi;
        kr_[i0 + 1] = ar - br; ki_[i0 + 1] = ai - bi;
        ar = qr_[i0]; ai = qi_[i0]; br = qr_[i0 + 1]; bi = qi_[i0 + 1];
        qr_[i0] = ar + br; qi_[i0] = ai + bi;
        qr_[i0 + 1] = ar - br; qi_[i0 + 1] = ai - bi;
    }

    unsigned short* op = (unsigned short*)(pcat + (long)bt * 4096 + 8 * tid);
    ushort8t ore, oim;
    #pragma unroll
    for (int l = 0; l < 8; ++l) {
        float pr = qr_[l] * kr_[l] - qi_[l] * ki_[l];
        float pi2 = qr_[l] * ki_[l] + qi_[l] * kr_[l];
        bf16 hr = __float2bfloat16(pr);
        bf16 hi = __float2bfloat16(pi2);
        ore[l] = *(unsigned short*)&hr;
        oim[l] = *(unsigned short*)&hi;
    }
    *(ushort8t*)op = ore;
    *(ushort8t*)(op + 2048) = oim;
}

// Ghat for column j of ro_w1: ro1f[j] = [Re FFT | Im FFT] (scrambled, same DIF) bf16
__global__ __launch_bounds__(256) void ro1fft_kernel(const float* __restrict__ ro_w1,
                                                     bf16* __restrict__ ro1f) {
    __shared__ float Rs[2112], Is[2112];
    int j = blockIdx.x, tid = threadIdx.x;
    for (int u = 0; u < 8; ++u) {
        int n = u * 256 + tid;
        Rs[PIDX(n)] = ro_w1[(long)n * HID_ + j];
        Is[PIDX(n)] = 0.f;
    }
    __syncthreads();
#define FSTEP(MM) dif_one<MM>(Rs, Is, tid); __syncthreads();
    FSTEP(1024) FSTEP(512) FSTEP(256) FSTEP(128) FSTEP(64)
    FSTEP(32) FSTEP(16) FSTEP(8) FSTEP(4) FSTEP(2) FSTEP(1)
#undef FSTEP
    unsigned short* op = (unsigned short*)(ro1f + (long)j * 4096);
    for (int u = 0; u < 8; ++u) {
        int r = u * 256 + tid;
        int pr = PIDX(r);
        bf16 re = __float2bfloat16(Rs[pr]);
        bf16 im = __float2bfloat16(Is[pr]);
        op[r]        = *(unsigned short*)&re;
        op[2048 + r] = *(unsigned short*)&im;
    }
}

// MFMA bf16 TN GEMM: C[M,N] = A * Bt^T. 64x64 tile, 4 waves.
// AMODE 0: A bf16. AMODE 1: A f32 + causal mask. AMODE 2: A f32, gelu(a*scale+abias).
// FLAG_TRI: blockIdx.x in {0,1,2} decodes (tile_x,tile_y) = (0,0),(0,1),(1,1).
template<int FLAGS, int OUTB16, int AMODE>
__global__ __launch_bounds__(256) void gemm_mfma(
    const void* __restrict__ Av, const bf16* __restrict__ Bt,
    const float* __restrict__ bias, const float* __restrict__ abias,
    void* __restrict__ Cv,
    int K, int ldc, long abz, long bbz, long cbz, int splitk)
{
    __shared__ __align__(16) bf16 As[64][44];
    __shared__ __align__(16) bf16 Bs[64][44];
    int bz = blockIdx.z;
    int batch = bz, kslice = 0;
    if (FLAGS & FLAG_ATOMIC) { batch = bz / splitk; kslice = bz % splitk; }
    int tbx = blockIdx.x, tby = blockIdx.y;
    if (FLAGS & FLAG_TRI) { tby = (blockIdx.x > 0) ? 1 : 0; tbx = (blockIdx.x == 2) ? 1 : 0; }
    long aoff;
    const bf16* Bb;
    long coff;
    if (FLAGS & FLAG_HFB) {
        int b = bz & 7, c = bz >> 3;
        aoff = (long)b * abz + (long)tby * 64 * K;
        Bb = Bt + (long)c * 2097152L + (long)b * 262144L + (long)tbx * 64 * K;
        coff = (long)b * 2097152L + (long)c * 1048576L;
    } else {
        aoff = (long)batch * abz + (long)tby * 64 * K;
        Bb = Bt + (long)batch * bbz + (long)tbx * 64 * K;
        coff = (long)batch * cbz;
    }
    int tid = threadIdx.x;
    int lrow = tid >> 2;
    int lk = (tid & 3) * 8;
    int w = tid >> 6, lane = tid & 63;
    int wr = (w >> 1) * 32, wc = (w & 1) * 32;
    int fm = lane & 15, fk = (lane >> 4) * 8;
    f32x4 acc00 = {0.f,0.f,0.f,0.f}, acc01 = acc00, acc10 = acc00, acc11 = acc00;

    int klen = K / splitk;
    int k0 = kslice * klen;
    for (int kt = k0; kt < k0 + klen; kt += 32) {
        if (AMODE == 0) {
            const bf16* Ab = (const bf16*)Av + aoff;
            *(float4*)&As[lrow][lk] = *(const float4*)&Ab[(long)lrow * K + kt + lk];
        } else {
            const float* Af = (const float*)Av + aoff;
            int gk0 = kt + lk;
            float4 v0 = *(const float4*)&Af[(long)lrow * K + gk0];
            float4 v1 = *(const float4*)&Af[(long)lrow * K + gk0 + 4];
            float vv[8] = {v0.x, v0.y, v0.z, v0.w, v1.x, v1.y, v1.z, v1.w};
            int grow = tby * 64 + lrow;
            float sc = 0.f;
            if (AMODE == 2) sc = rsqrtf((float)((grow & 127) + 1)) * (1.0f / 92681.900089f);
            #pragma unroll
            for (int j = 0; j < 8; ++j) {
                float val = vv[j];
                int gk = gk0 + j;
                if (AMODE == 1) val = (gk < grow) ? val : 0.f;
                if (AMODE == 2) val = gelu_f(val * sc + abias[gk]);
                As[lrow][lk + j] = __float2bfloat16(val);
            }
        }
        *(float4*)&Bs[lrow][lk] = *(const float4*)&Bb[(long)lrow * K + kt + lk];
        __syncthreads();
        short8t a0 = *(const short8t*)&As[wr + fm][fk];
        short8t a1 = *(const short8t*)&As[wr + 16 + fm][fk];
        short8t b0 = *(const short8t*)&Bs[wc + fm][fk];
        short8t b1 = *(const short8t*)&Bs[wc + 16 + fm][fk];
        acc00 = __builtin_amdgcn_mfma_f32_16x16x32_bf16(a0, b0, acc00, 0, 0, 0);
        acc01 = __builtin_amdgcn_mfma_f32_16x16x32_bf16(a0, b1, acc01, 0, 0, 0);
        acc10 = __builtin_amdgcn_mfma_f32_16x16x32_bf16(a1, b0, acc10, 0, 0, 0);
        acc11 = __builtin_amdgcn_mfma_f32_16x16x32_bf16(a1, b1, acc11, 0, 0, 0);
        __syncthreads();
    }

    float* Cf = (float*)Cv;
    bf16* Cb = (bf16*)Cv;
    int row_base = tby * 64 + wr + (lane >> 4) * 4;
    int col_base = tbx * 64 + wc + fm;
    #pragma unroll
    for (int fr = 0; fr < 2; ++fr) {
        #pragma unroll
        for (int fc = 0; fc < 2; ++fc) {
            const f32x4& a = fr == 0 ? (fc == 0 ? acc00 : acc01) : (fc == 0 ? acc10 : acc11);
            #pragma unroll
            for (int r = 0; r < 4; ++r) {
                int gi = row_base + fr * 16 + r;
                int gj = col_base + fc * 16;
                float v = a[r];
                long ci = coff + (long)gi * ldc + gj;
                if (FLAGS & FLAG_ATOMIC) {
                    atomicAdd(&Cf[ci], v);
                } else {
                    if (FLAGS & FLAG_BIAS) v += bias[gj];
                    if (FLAGS & FLAG_GELU) v = gelu_f(v);
                    if (FLAGS & FLAG_ROWSCALE) v *= rsqrtf((float)(gi & 127) + 1.0f);
                    if (OUTB16) Cb[ci] = __float2bfloat16(v);
                    else        Cf[ci] = v;
                }
            }
        }
    }
}

// LN over D=512. FINAL=0: LN(x1); FINAL=1: LN(x1 + gf*x2 + gv*x3). OB16 selects out dtype.
template<int FINAL, int OB16>
__global__ __launch_bounds__(256) void ln_kernel(const float* __restrict__ x1,
                                                 const float* __restrict__ x2,
                                                 const float* __restrict__ x3,
                                                 const float* __restrict__ g,
                                                 const float* __restrict__ bb,
                                                 const float* __restrict__ scal,
                                                 void* __restrict__ outv) {
    int row = blockIdx.x, tid = threadIdx.x;
    long base = (long)row * D_;
    int d0 = tid, d1 = tid + 256;
    float v0, v1;
    if (FINAL) {
        float gf = scal[3], gv = scal[4];
        v0 = x1[base + d0] + gf * x2[base + d0] + gv * x3[base + d0];
        v1 = x1[base + d1] + gf * x2[base + d1] + gv * x3[base + d1];
    } else {
        v0 = x1[base + d0];
        v1 = x1[base + d1];
    }
    float s = v0 + v1;
    #pragma unroll
    for (int o = 32; o > 0; o >>= 1) s += __shfl_down(s, o);
    __shared__ float red[8];
    int wid = tid >> 6, lane = tid & 63;
    if (lane == 0) red[wid] = s;
    __syncthreads();
    float mu = (red[0] + red[1] + red[2] + red[3]) * (1.0f / D_);
    float e0 = v0 - mu, e1 = v1 - mu;
    float sq = e0 * e0 + e1 * e1;
    #pragma unroll
    for (int o = 32; o > 0; o >>= 1) sq += __shfl_down(sq, o);
    if (lane == 0) red[4 + wid] = sq;
    __syncthreads();
    float var = (red[4] + red[5] + red[6] + red[7]) * (1.0f / D_);
    float rs = rsqrtf(var + 1e-5f);
    float o0 = e0 * rs * g[d0] + bb[d0];
    float o1 = e1 * rs * g[d1] + bb[d1];
    if (OB16) {
        ((bf16*)outv)[base + d0] = __float2bfloat16(o0);
        ((bf16*)outv)[base + d1] = __float2bfloat16(o1);
    } else {
        ((float*)outv)[base + d0] = o0;
        ((float*)outv)[base + d1] = o1;
    }
}

extern "C" void kernel_launch(void* const* d_in, const int* in_sizes, int n_in,
                              void* d_out, int out_size, void* d_ws, size_t ws_size,
                              hipStream_t stream) {
    const float* e      = (const float*)d_in[0];
    const int*   h      = (const int*)d_in[1];
    const float* sign   = (const float*)d_in[2];
    const float* Wq     = (const float*)d_in[3];
    const float* Wk     = (const float*)d_in[4];
    const float* Wv     = (const float*)d_in[5];
    const float* ro_w1  = (const float*)d_in[6];
    const float* ro_b1  = (const float*)d_in[7];
    const float* ro_w2  = (const float*)d_in[8];
    const float* ro_b2  = (const float*)d_in[9];
    const float* vp_ln_g= (const float*)d_in[10];
    const float* vp_ln_b= (const float*)d_in[11];
    const float* vp_w1  = (const float*)d_in[12];
    const float* vp_b1  = (const float*)d_in[13];
    const float* vp_w2  = (const float*)d_in[14];
    const float* vp_b2  = (const float*)d_in[15];
    const float* ln_g   = (const float*)d_in[16];
    const float* ln_b   = (const float*)d_in[17];
    const float* tq     = (const float*)d_in[18];
    const float* tk     = (const float*)d_in[19];
    const float* om     = (const float*)d_in[20];
    const float* gfr    = (const float*)d_in[21];
    const float* gvr    = (const float*)d_in[22];

    float* ws    = (float*)d_ws;
    float* scal  = ws + OFF_SCAL;
    float* qkv   = ws + OFF_QKV;
    float* sk2   = ws + OFF_SK2;
    float* vraw  = ws + OFF_VRAW;
    float* vf    = ws + OFF_VF;
    float* hfeat = ws + OFF_HFEAT;
    float* scoacc= ws + OFF_SCOA;
    float* qsum  = ws + OFF_QSUM;
    float* hacc  = ws + OFF_HACC;
    bf16* kp16  = (bf16*)(ws + OFF_KP);
    bf16* eb    = (bf16*)(ws + OFF_EB);
    bf16* wqkvT = (bf16*)(ws + OFF_WQKVT);
    bf16* vp1T  = (bf16*)(ws + OFF_VP1T);
    bf16* vp2T  = (bf16*)(ws + OFF_VP2T);
    bf16* ro2T  = (bf16*)(ws + OFF_RO2T);
    bf16* qcat  = (bf16*)(ws + OFF_QCAT);
    bf16* kcat  = (bf16*)(ws + OFF_KCAT);
    bf16* dkT   = (bf16*)(ws + OFF_DKT);
    bf16* vTb   = (bf16*)(ws + OFF_VTB);
    bf16* vlnb  = (bf16*)(ws + OFF_VLNB);
    bf16* v1b   = (bf16*)(ws + OFF_V1B);
    bf16* pcat  = (bf16*)(ws + OFF_PCAT);
    bf16* ro1f  = (bf16*)(ws + OFF_RO1F);

    float* ys = (float*)d_out;
    float* kf = ys + (long)BT_ * D_;
    float* hf = kf + (long)B_ * 2 * M_;

    // scalars + zero split-K accumulators (replaces 2 memsets + scal)
    scal_zero_kernel<<<1024, 256, 0, stream>>>(tq, tk, om, gfr, gvr, scal, scoacc, hacc);

    // bf16 operand prep
    cast4_kernel<<<512, 256, 0, stream>>>((const float4*)e, (ushort4t*)eb, 131072);
    castT6_kernel<<<dim3(16, 16, 6), 256, 0, stream>>>(
        Wq, Wk, Wv, vp_w1, vp_w2, ro_w2,
        wqkvT, wqkvT + 262144, wqkvT + 524288, vp1T, vp2T, ro2T);
    ro1fft_kernel<<<128, 256, 0, stream>>>(ro_w1, ro1f);

    // qkv = e @ [Wq|Wk|Wv]  (1024 x 1536 x 512) -> f32
    gemm_mfma<0, 0, 0><<<dim3(24, 16, 1), 256, 0, stream>>>(
        eb, wqkvT, nullptr, nullptr, qkv, 512, 1536, 0, 0, 0, 1);

    sketch_kernel<<<1024, 256, 0, stream>>>(qkv, sign, scal, h, sk2, qcat, kcat);
    prefix_p1<<<512, 256, 0, stream>>>(sk2, qsum);
    prefix_p2<<<512, 256, 0, stream>>>(sk2, qsum, kp16, dkT, kf);

    // forward FFTs + spectral product (no inverse; scrambled order matches ro1f)
    fwdfft_kernel<<<1024, 256, 0, stream>>>(qcat, kp16, pcat);

    // vTb[b][d][t] from qkv v-columns
    castT_kernel<<<dim3(16, 4, 8), 256, 0, stream>>>(qkv + 1024, vTb, 128, 512, 1536, 196608, 65536);

    // scores: split-K 16, triangle-skip (3 of 4 tiles), f32 atomic accumulate
    gemm_mfma<FLAG_ATOMIC | FLAG_TRI, 0, 0><<<dim3(3, 1, 128), 256, 0, stream>>>(
        qcat, kcat, nullptr, nullptr, scoacc, 4096, 128, 524288, 524288, 16384, 16);

    // vraw[b] = masked(scores) @ v * rsqrt(t+1)  (mask fused in A-load)
    gemm_mfma<FLAG_ROWSCALE, 0, 1><<<dim3(8, 2, 8), 256, 0, stream>>>(
        scoacc, vTb, nullptr, nullptr, vraw, 128, 512, 16384, 65536, 65536, 1);

    ln_kernel<0, 1><<<1024, 256, 0, stream>>>(vraw, nullptr, nullptr, vp_ln_g, vp_ln_b, scal, vlnb);

    // vp MLP
    gemm_mfma<FLAG_BIAS | FLAG_GELU, 1, 0><<<dim3(8, 16, 1), 256, 0, stream>>>(
        vlnb, vp1T, vp_b1, nullptr, v1b, 512, 512, 0, 0, 0, 1);
    gemm_mfma<FLAG_BIAS, 0, 0><<<dim3(8, 16, 1), 256, 0, stream>>>(
        v1b, vp2T, vp_b2, nullptr, vf, 512, 512, 0, 0, 0, 1);

    // hid_pre = pcat @ ro1f^T (1024x128x4096), split-K 8 atomic into hacc
    gemm_mfma<FLAG_ATOMIC, 0, 0><<<dim3(2, 16, 8), 256, 0, stream>>>(
        pcat, ro1f, nullptr, nullptr, hacc, 4096, 128, 0, 0, 0, 8);

    // hfeat = gelu(hacc*scale+b1) @ ro_w2 + b2; hid epilogue fused in A-load
    gemm_mfma<FLAG_BIAS, 0, 2><<<dim3(8, 16, 1), 256, 0, stream>>>(
        hacc, ro2T, ro_b2, ro_b1, hfeat, 128, 512, 0, 0, 0, 1);

    // ys = LN(e + gf*hfeat + gv*vf)
    ln_kernel<1, 0><<<1024, 256, 0, stream>>>(e, hfeat, vf, ln_g, ln_b, scal, ys);

    // Hf fused: z in [0,16), b=z&7, c=z>>3
    gemm_mfma<FLAG_HFB, 0, 0><<<dim3(32, 8, 16), 256, 0, stream>>>(
        vTb, dkT, nullptr, nullptr, hf, 128, 2048, 65536, 0, 0, 1);
}

// Round 14
// 146.208 us; speedup vs baseline: 2.1057x; 1.0909x over previous
//
#include <hip/hip_runtime.h>
#include <hip/hip_bf16.h>
#include <math.h>

#define B_   8
#define T_   128
#define D_   512
#define M_   2048
#define HID_ 128
#define BT_  1024

typedef __attribute__((ext_vector_type(8))) short short8t;
typedef __attribute__((ext_vector_type(8))) unsigned short ushort8t;
typedef __attribute__((ext_vector_type(4))) unsigned short ushort4t;
typedef __attribute__((ext_vector_type(4))) float f32x4;
typedef __hip_bfloat16 bf16;

// ws layout (float offsets; all multiples of 16 -> 64B aligned)
#define OFF_SCAL   0L
#define OFF_QKV    16L                            // 1024*1536 f32
#define OFF_SK2    (OFF_QKV + 1572864L)           // [dKre|dKim] f32, 2*BT*M
#define OFF_KP     (OFF_SK2 + 4194304L)           // [KR|KI] bf16 exclusive prefix (2*BT*M bf16)
#define OFF_VRAW   (OFF_KP + 4194304L)
#define OFF_VF     (OFF_VRAW + 524288L)
#define OFF_HFEAT  (OFF_VF + 524288L)
// bf16 buffers (size in floats = elems/2)
#define OFF_EB     (OFF_HFEAT + 524288L)          // 1024x512
#define OFF_WQKVT  (OFF_EB + 262144L)             // 1536x512
#define OFF_VP1T   (OFF_WQKVT + 393216L)          // 512x512
#define OFF_VP2T   (OFF_VP1T + 131072L)
#define OFF_RO2T   (OFF_VP2T + 131072L)           // 512x128
#define OFF_QCAT   (OFF_RO2T + 32768L)            // 1024x4096
#define OFF_KCAT   (OFF_QCAT + 2097152L)          // 1024x4096
#define OFF_DKT    (OFF_KCAT + 2097152L)          // 2x8x2048x128
#define OFF_VTB    (OFF_DKT + 2097152L)           // 8x512x128
#define OFF_VLNB   (OFF_VTB + 262144L)            // 1024x512
#define OFF_V1B    (OFF_VLNB + 262144L)           // 1024x512
#define OFF_SCOA   (OFF_V1B + 262144L)            // 8x128x128 f32 split-K accumulator
#define OFF_QSUM   (OFF_SCOA + 131072L)           // 4x32768 f32 prefix quarter sums
#define OFF_PCAT   (OFF_QSUM + 131072L)           // 1024x4096 bf16 [ReP|ImP]
#define OFF_RO1F   (OFF_PCAT + 2097152L)          // 128x4096 bf16 [ReG|ImG]
#define OFF_HACC   (OFF_RO1F + 262144L)           // 1024x128 f32

#define FLAG_BIAS     1
#define FLAG_GELU     2
#define FLAG_ROWSCALE 4
#define FLAG_ATOMIC   8
#define FLAG_HFB      32
#define FLAG_TRI      64

__device__ __forceinline__ float gelu_f(float x) {
    return 0.5f * x * (1.0f + erff(x * 0.70710678118654752440f));
}

__device__ __forceinline__ float b2f(unsigned short u) {
    return __uint_as_float(((unsigned int)u) << 16);
}

#define PIDX(i) ((i) + ((i) >> 5))

template<int M>
__device__ __forceinline__ void dif_one(float* re, float* im, int tid) {
    #pragma unroll
    for (int u = 0; u < 4; ++u) {
        int q = u * 256 + tid;
        int k = q & (M - 1);
        int i = (q / M) * (2 * M) + k;
        float s, c;
        __sincosf((float)k * (3.14159265358979323846f / (float)M), &s, &c);
        int p0 = PIDX(i), p1 = PIDX(i + M);
        float ar = re[p0], ai = im[p0], br = re[p1], bi = im[p1];
        re[p0] = ar + br; im[p0] = ai + bi;
        float dr = ar - br, di = ai - bi;
        re[p1] = dr * c + di * s;
        im[p1] = di * c - dr * s;
    }
}

// ==== fused preprocessing: scal+zero | e-cast | 6x weight transpose | ro1 FFT ====
// blocks [0,1024): scalars + zero scoacc/hacc
// blocks [1024,1536): cast4 e->eb
// blocks [1536,3072): castT6 (decode wz/by/bx)
// blocks [3072,3200): ro1fft column j
__global__ __launch_bounds__(256) void preproc_kernel(
    const float* tq, const float* tk, const float* om, const float* gf, const float* gv,
    float* scal, float* scoacc, float* hacc,
    const float4* __restrict__ e4, ushort4t* __restrict__ eb4,
    const float* w0, const float* w1, const float* w2, const float* w3,
    const float* w4, const float* w5,
    bf16* d0, bf16* d1, bf16* d2, bf16* d3, bf16* d4, bf16* d5,
    const float* __restrict__ ro_w1, bf16* __restrict__ ro1f)
{
    __shared__ float smem[4224];   // 16.9 KB union
    int blk = blockIdx.x, tid = threadIdx.x;

    if (blk < 1024) {
        int idx = blk * 256 + tid;
        if (idx < 131072) scoacc[idx] = 0.f;
        else hacc[idx - 131072] = 0.f;
        if (idx == 0) {
            scal[0] = 0.5f * tanhf(tq[0]);
            scal[1] = 0.5f * tanhf(tk[0]);
            scal[2] = 0.5f * tanhf(om[0]);
            scal[3] = 0.25f / (1.0f + expf(-gf[0]));
            scal[4] = 0.25f / (1.0f + expf(-gv[0]));
        }
        return;
    }
    if (blk < 1536) {
        int i = (blk - 1024) * 256 + tid;   // < 131072
        float4 v = e4[i];
        ushort4t o;
        bf16 h0 = __float2bfloat16(v.x), h1 = __float2bfloat16(v.y);
        bf16 h2 = __float2bfloat16(v.z), h3 = __float2bfloat16(v.w);
        o[0] = *(unsigned short*)&h0; o[1] = *(unsigned short*)&h1;
        o[2] = *(unsigned short*)&h2; o[3] = *(unsigned short*)&h3;
        eb4[i] = o;
        return;
    }
    if (blk < 3072) {
        int zz = blk - 1536;
        int wz = zz >> 8;              // /256
        int rem = zz & 255;
        int by = rem >> 4, bx = rem & 15;
        const float* src; bf16* dst; int R = 512;
        if (wz == 0)      { src = w0; dst = d0; }
        else if (wz == 1) { src = w1; dst = d1; }
        else if (wz == 2) { src = w2; dst = d2; }
        else if (wz == 3) { src = w3; dst = d3; }
        else if (wz == 4) { src = w4; dst = d4; }
        else              { src = w5; dst = d5; R = 128; }
        int c0 = bx * 32, r0 = by * 32;
        if (r0 >= R) return;
        float (*tile)[33] = (float(*)[33])smem;
        int tx = tid & 31, ty = tid >> 5;
        for (int rr = ty; rr < 32; rr += 8) {
            int r = r0 + rr;
            tile[rr][tx] = (r < R) ? src[(long)r * 512 + c0 + tx] : 0.f;
        }
        __syncthreads();
        int r = r0 + tx;
        if (r < R)
            for (int cc = ty; cc < 32; cc += 8)
                dst[(long)(c0 + cc) * R + r] = __float2bfloat16(tile[tx][cc]);
        return;
    }
    {   // ro1fft
        int j = blk - 3072;
        float* Rs = smem;
        float* Is = smem + 2112;
        for (int u = 0; u < 8; ++u) {
            int n = u * 256 + tid;
            Rs[PIDX(n)] = ro_w1[(long)n * HID_ + j];
            Is[PIDX(n)] = 0.f;
        }
        __syncthreads();
#define FSTEP(MM) dif_one<MM>(Rs, Is, tid); __syncthreads();
        FSTEP(1024) FSTEP(512) FSTEP(256) FSTEP(128) FSTEP(64)
        FSTEP(32) FSTEP(16) FSTEP(8) FSTEP(4) FSTEP(2) FSTEP(1)
#undef FSTEP
        unsigned short* op = (unsigned short*)(ro1f + (long)j * 4096);
        for (int u = 0; u < 8; ++u) {
            int r = u * 256 + tid;
            int pr = PIDX(r);
            bf16 re = __float2bfloat16(Rs[pr]);
            bf16 im = __float2bfloat16(Is[pr]);
            op[r]        = *(unsigned short*)&re;
            op[2048 + r] = *(unsigned short*)&im;
        }
    }
}

// tiled transpose-cast (still used for vTb)
__global__ __launch_bounds__(256) void castT_kernel(const float* __restrict__ in,
                                                    bf16* __restrict__ out,
                                                    int R, int C, int ld_in,
                                                    long bs_in, long bs_out) {
    __shared__ float tile[32][33];
    int b = blockIdx.z;
    int c0 = blockIdx.x * 32, r0 = blockIdx.y * 32;
    int tx = threadIdx.x & 31, ty = threadIdx.x >> 5;
    for (int rr = ty; rr < 32; rr += 8) {
        int r = r0 + rr, c = c0 + tx;
        tile[rr][tx] = (r < R && c < C) ? in[(long)b * bs_in + (long)r * ld_in + c] : 0.f;
    }
    __syncthreads();
    for (int cc = ty; cc < 32; cc += 8) {
        int c = c0 + cc, r = r0 + tx;
        if (c < C && r < R) out[(long)b * bs_out + (long)c * R + r] = __float2bfloat16(tile[tx][cc]);
    }
}

// sketch (phase fused): SK2 f32 = [dKre|dKim]; qcat bf16 = [Qre|Qim]; kcat bf16 = [dKre|-dKim]
__global__ __launch_bounds__(256) void sketch_kernel(const float* __restrict__ qkv,
                                                     const float* __restrict__ sign,
                                                     const float* __restrict__ scal,
                                                     const int* __restrict__ h,
                                                     float* __restrict__ SK2,
                                                     bf16* __restrict__ qcat,
                                                     bf16* __restrict__ kcat) {
    int bt = blockIdx.x;
    int tid = threadIdx.x;
    __shared__ float s0[M_], s1[M_], s2[M_], s3[M_];
    for (int j = tid; j < M_; j += 256) { s0[j] = 0.f; s1[j] = 0.f; s2[j] = 0.f; s3[j] = 0.f; }
    __syncthreads();
    int t = bt & 127;
    float thq = scal[0], thk = scal[1], omg = scal[2];
    float ft = (float)t;
    for (int i = tid; i < D_; i += 256) {
        float q = qkv[(long)bt * 1536 + i];
        float k = qkv[(long)bt * 1536 + 512 + i];
        float sg = sign[i];
        float sq_, cq_, sk_, ck_;
        __sincosf(thq * q - omg * ft, &sq_, &cq_);
        __sincosf(thk * k + omg * ft, &sk_, &ck_);
        int m = h[i];
        atomicAdd(&s0[m], q * cq_ * sg);
        atomicAdd(&s1[m], q * sq_ * sg);
        atomicAdd(&s2[m], k * ck_ * sg);
        atomicAdd(&s3[m], k * sk_ * sg);
    }
    __syncthreads();
    long ob = (long)bt * M_;
    long qb = (long)bt * 4096;
    for (int j = tid; j < M_; j += 256) {
        SK2[ob + j]                  = s2[j];
        SK2[(long)BT_ * M_ + ob + j] = s3[j];
        qcat[qb + j]        = __float2bfloat16(s0[j]);
        qcat[qb + 2048 + j] = __float2bfloat16(s1[j]);
        kcat[qb + j]        = __float2bfloat16(s2[j]);
        kcat[qb + 2048 + j] = __float2bfloat16(-s3[j]);
    }
}

// ---- two-phase exclusive prefix over t (4-way t split) ----
__global__ __launch_bounds__(256) void prefix_p1(const float* __restrict__ SK2,
                                                 float* __restrict__ qsum) {
    int idx = blockIdx.x * 256 + threadIdx.x;   // 131072
    int col = idx & 32767, q = idx >> 15;
    int m = col & 2047, b = (col >> 11) & 7, comp = col >> 14;
    const float* src = SK2 + (long)comp * BT_ * M_ + (long)b * T_ * M_ + (long)(q * 32) * M_ + m;
    float s = 0.f;
    #pragma unroll 8
    for (int i = 0; i < 32; ++i) s += src[(long)i * M_];
    qsum[(long)q * 32768 + col] = s;
}

// KP written as bf16; also emits dkT[c][b][m][t] bf16 (t-contiguous per thread)
__global__ __launch_bounds__(256) void prefix_p2(const float* __restrict__ SK2,
                                                 const float* __restrict__ qsum,
                                                 bf16* __restrict__ KP16,
                                                 bf16* __restrict__ dkT,
                                                 float* __restrict__ kf_out) {
    int idx = blockIdx.x * 256 + threadIdx.x;   // 131072
    int col = idx & 32767, q = idx >> 15;
    int m = col & 2047, b = (col >> 11) & 7, comp = col >> 14;
    long cb = (long)comp * BT_ * M_ + (long)b * T_ * M_ + m + (long)(q * 32) * M_;
    const float* src = SK2 + cb;
    bf16* dst = KP16 + cb;
    bf16* dkt = dkT + (long)comp * 2097152L + (long)b * 262144L + (long)m * 128L + (long)(q * 32);
    float acc = 0.f;
    for (int p = 0; p < q; ++p) acc += qsum[(long)p * 32768 + col];
    #pragma unroll 4
    for (int i = 0; i < 32; ++i) {
        float v = src[(long)i * M_];
        dst[(long)i * M_] = __float2bfloat16(acc);
        dkt[i] = __float2bfloat16(v);
        acc += v;
    }
    if (q == 3) kf_out[((long)b * 2 + comp) * M_ + m] = acc;
}

// fused 3-stage radix-8 DIF pass on both (K,Q) arrays.
template<int S>
__device__ __forceinline__ void dif8_pair(float* r0, float* i0a, float* r1, float* i1a, int tid) {
    int k = tid % S;
    int grp = tid / S;
    int base = grp * 8 * S + k;
    float sw, cw;
    __sincosf((float)k * (3.14159265358979323846f / (4.0f * (float)S)), &sw, &cw);
    float wr = cw, wi = -sw;
    float w2r = wr * wr - wi * wi, w2i = 2.f * wr * wi;
    float w4r = w2r * w2r - w2i * w2i, w4i = 2.f * w2r * w2i;
    const float RH = 0.70710678118654752440f;
    float t1r[4] = {wr, (wr + wi) * RH, wi, (wi - wr) * RH};
    float t1i[4] = {wi, (wi - wr) * RH, -wr, -(wr + wi) * RH};
    float u0r = w2r, u0i = w2i;
    float u1r = w2i, u1i = -w2r;
    #pragma unroll
    for (int a = 0; a < 2; ++a) {
        float* re = a ? r1 : r0;
        float* im = a ? i1a : i0a;
        float xr[8], xi[8];
        #pragma unroll
        for (int r = 0; r < 8; ++r) { int p = PIDX(base + r * S); xr[r] = re[p]; xi[r] = im[p]; }
        #pragma unroll
        for (int r = 0; r < 4; ++r) {
            float ar = xr[r], ai = xi[r], br = xr[r + 4], bi = xi[r + 4];
            xr[r] = ar + br; xi[r] = ai + bi;
            float dr = ar - br, di = ai - bi;
            xr[r + 4] = dr * t1r[r] - di * t1i[r];
            xi[r + 4] = dr * t1i[r] + di * t1r[r];
        }
        #pragma unroll
        for (int hb = 0; hb < 8; hb += 4) {
            #pragma unroll
            for (int r = 0; r < 2; ++r) {
                float tr = (r == 0) ? u0r : u1r, ti = (r == 0) ? u0i : u1i;
                float ar = xr[hb + r], ai = xi[hb + r], br = xr[hb + r + 2], bi = xi[hb + r + 2];
                xr[hb + r] = ar + br; xi[hb + r] = ai + bi;
                float dr = ar - br, di = ai - bi;
                xr[hb + r + 2] = dr * tr - di * ti;
                xi[hb + r + 2] = dr * ti + di * tr;
            }
        }
        #pragma unroll
        for (int r = 0; r < 8; r += 2) {
            float ar = xr[r], ai = xi[r], br = xr[r + 1], bi = xi[r + 1];
            xr[r] = ar + br; xi[r] = ai + bi;
            float dr = ar - br, di = ai - bi;
            xr[r + 1] = dr * w4r - di * w4i;
            xi[r + 1] = dr * w4i + di * w4r;
        }
        #pragma unroll
        for (int r = 0; r < 8; ++r) { int p = PIDX(base + r * S); re[p] = xr[r]; im[p] = xi[r]; }
    }
}

// forward FFTs of Q sketch and K prefix; pcat = [Re(FQ*FK) | Im(FQ*FK)] bf16 (scrambled order)
__global__ __launch_bounds__(256) void fwdfft_kernel(const bf16* __restrict__ qcat,
                                                     const bf16* __restrict__ KP16,
                                                     bf16* __restrict__ pcat) {
    __shared__ float KRs[2112], KIs[2112], QRs[2112], QIs[2112];   // 33 KB
    int bt = blockIdx.x, tid = threadIdx.x;
    const unsigned short* qp = (const unsigned short*)(qcat + (long)bt * 4096);
    const unsigned short* kpr = (const unsigned short*)(KP16 + (long)bt * M_);
    const unsigned short* kpi = (const unsigned short*)(KP16 + (long)BT_ * M_ + (long)bt * M_);
    for (int u = 0; u < 8; ++u) {
        int j = u * 256 + tid;
        int pj = PIDX(j);
        KRs[pj] = b2f(kpr[j]);
        KIs[pj] = b2f(kpi[j]);
        QRs[pj] = b2f(qp[j]);
        QIs[pj] = b2f(qp[2048 + j]);
    }
    __syncthreads();
    dif8_pair<256>(KRs, KIs, QRs, QIs, tid);  __syncthreads();
    dif8_pair<32>(KRs, KIs, QRs, QIs, tid);   __syncthreads();

    float kr_[8], ki_[8], qr_[8], qi_[8];
    #pragma unroll
    for (int l = 0; l < 8; ++l) {
        int pj = PIDX(8 * tid + l);
        kr_[l] = KRs[pj]; ki_[l] = KIs[pj];
        qr_[l] = QRs[pj]; qi_[l] = QIs[pj];
    }

    const float C16[16] = {1.f, 0.98078528f, 0.92387953f, 0.83146961f,
                           0.70710678f, 0.55557023f, 0.38268343f, 0.19509032f,
                           0.f, -0.19509032f, -0.38268343f, -0.55557023f,
                           -0.70710678f, -0.83146961f, -0.92387953f, -0.98078528f};
    const float S16[16] = {0.f, 0.19509032f, 0.38268343f, 0.55557023f,
                           0.70710678f, 0.83146961f, 0.92387953f, 0.98078528f,
                           1.f, 0.98078528f, 0.92387953f, 0.83146961f,
                           0.70710678f, 0.55557023f, 0.38268343f, 0.19509032f};
    bool odd = (tid & 1) != 0;
    {
        bool hi2 = (tid & 2) != 0;
        #pragma unroll
        for (int l = 0; l < 8; ++l) {
            float c = odd ? C16[l + 8] : C16[l];
            float s = odd ? S16[l + 8] : S16[l];
            float pr, pi2, sr, si, dr, di;
            pr = __shfl_xor(kr_[l], 2); pi2 = __shfl_xor(ki_[l], 2);
            sr = kr_[l] + pr; si = ki_[l] + pi2;
            dr = pr - kr_[l]; di = pi2 - ki_[l];
            kr_[l] = hi2 ? (dr * c + di * s) : sr;
            ki_[l] = hi2 ? (di * c - dr * s) : si;
            pr = __shfl_xor(qr_[l], 2); pi2 = __shfl_xor(qi_[l], 2);
            sr = qr_[l] + pr; si = qi_[l] + pi2;
            dr = pr - qr_[l]; di = pi2 - qi_[l];
            qr_[l] = hi2 ? (dr * c + di * s) : sr;
            qi_[l] = hi2 ? (di * c - dr * s) : si;
        }
    }
    {
        #pragma unroll
        for (int l = 0; l < 8; ++l) {
            float c = C16[2 * l];
            float s = S16[2 * l];
            float pr, pi2, sr, si, dr, di;
            pr = __shfl_xor(kr_[l], 1); pi2 = __shfl_xor(ki_[l], 1);
            sr = kr_[l] + pr; si = ki_[l] + pi2;
            dr = pr - kr_[l]; di = pi2 - ki_[l];
            kr_[l] = odd ? (dr * c + di * s) : sr;
            ki_[l] = odd ? (di * c - dr * s) : si;
            pr = __shfl_xor(qr_[l], 1); pi2 = __shfl_xor(qi_[l], 1);
            sr = qr_[l] + pr; si = qi_[l] + pi2;
            dr = pr - qr_[l]; di = pi2 - qi_[l];
            qr_[l] = odd ? (dr * c + di * s) : sr;
            qi_[l] = odd ? (di * c - dr * s) : si;
        }
    }
    {
        const float C4[4] = {1.f, 0.70710678f, 0.f, -0.70710678f};
        const float S4[4] = {0.f, 0.70710678f, 1.f, 0.70710678f};
        #pragma unroll
        for (int l = 0; l < 4; ++l) {
            float ar, ai, br, bi, dr, di;
            ar = kr_[l]; ai = ki_[l]; br = kr_[l + 4]; bi = ki_[l + 4];
            kr_[l] = ar + br; ki_[l] = ai + bi;
            dr = ar - br; di = ai - bi;
            kr_[l + 4] = dr * C4[l] + di * S4[l];
            ki_[l + 4] = di * C4[l] - dr * S4[l];
            ar = qr_[l]; ai = qi_[l]; br = qr_[l + 4]; bi = qi_[l + 4];
            qr_[l] = ar + br; qi_[l] = ai + bi;
            dr = ar - br; di = ai - bi;
            qr_[l + 4] = dr * C4[l] + di * S4[l];
            qi_[l + 4] = di * C4[l] - dr * S4[l];
        }
    }
    #pragma unroll
    for (int b2 = 0; b2 < 8; b2 += 4) {
        {
            float ar = kr_[b2], ai = ki_[b2], br = kr_[b2 + 2], bi = ki_[b2 + 2];
            kr_[b2] = ar + br; ki_[b2] = ai + bi;
            kr_[b2 + 2] = ar - br; ki_[b2 + 2] = ai - bi;
            ar = qr_[b2]; ai = qi_[b2]; br = qr_[b2 + 2]; bi = qi_[b2 + 2];
            qr_[b2] = ar + br; qi_[b2] = ai + bi;
            qr_[b2 + 2] = ar - br; qi_[b2 + 2] = ai - bi;
        }
        {
            float ar = kr_[b2 + 1], ai = ki_[b2 + 1], br = kr_[b2 + 3], bi = ki_[b2 + 3];
            kr_[b2 + 1] = ar + br; ki_[b2 + 1] = ai + bi;
            float dr = ar - br, di = ai - bi;
            kr_[b2 + 3] = di; ki_[b2 + 3] = -dr;
            ar = qr_[b2 + 1]; ai = qi_[b2 + 1]; br = qr_[b2 + 3]; bi = qi_[b2 + 3];
            qr_[b2 + 1] = ar + br; qi_[b2 + 1] = ai + bi;
            dr = ar - br; di = ai - bi;
            qr_[b2 + 3] = di; qi_[b2 + 3] = -dr;
        }
    }
    #pragma unroll
    for (int i0 = 0; i0 < 8; i0 += 2) {
        float ar = kr_[i0], ai = ki_[i0], br = kr_[i0 + 1], bi = ki_[i0 + 1];
        kr_[i0] = ar + br; ki_[i0] = ai + bi;
        kr_[i0 + 1] = ar - br; ki_[i0 + 1] = ai - bi;
        ar = qr_[i0]; ai = qi_[i0]; br = qr_[i0 + 1]; bi = qi_[i0 + 1];
        qr_[i0] = ar + br; qi_[i0] = ai + bi;
        qr_[i0 + 1] = ar - br; qi_[i0 + 1] = ai - bi;
    }

    unsigned short* op = (unsigned short*)(pcat + (long)bt * 4096 + 8 * tid);
    ushort8t ore, oim;
    #pragma unroll
    for (int l = 0; l < 8; ++l) {
        float pr = qr_[l] * kr_[l] - qi_[l] * ki_[l];
        float pi2 = qr_[l] * ki_[l] + qi_[l] * kr_[l];
        bf16 hr = __float2bfloat16(pr);
        bf16 hi = __float2bfloat16(pi2);
        ore[l] = *(unsigned short*)&hr;
        oim[l] = *(unsigned short*)&hi;
    }
    *(ushort8t*)op = ore;
    *(ushort8t*)(op + 2048) = oim;
}

// MFMA bf16 TN GEMM: C[M,N] = A * Bt^T. 64x64 tile, 4 waves.
// AMODE 0: A bf16. AMODE 1: A f32 + causal mask. AMODE 2: A f32, gelu(a*scale+abias).
// FLAG_TRI: blockIdx.x in {0,1,2} decodes (tile_x,tile_y) = (0,0),(0,1),(1,1).
template<int FLAGS, int OUTB16, int AMODE>
__global__ __launch_bounds__(256) void gemm_mfma(
    const void* __restrict__ Av, const bf16* __restrict__ Bt,
    const float* __restrict__ bias, const float* __restrict__ abias,
    void* __restrict__ Cv,
    int K, int ldc, long abz, long bbz, long cbz, int splitk)
{
    __shared__ __align__(16) bf16 As[64][44];
    __shared__ __align__(16) bf16 Bs[64][44];
    int bz = blockIdx.z;
    int batch = bz, kslice = 0;
    if (FLAGS & FLAG_ATOMIC) { batch = bz / splitk; kslice = bz % splitk; }
    int tbx = blockIdx.x, tby = blockIdx.y;
    if (FLAGS & FLAG_TRI) { tby = (blockIdx.x > 0) ? 1 : 0; tbx = (blockIdx.x == 2) ? 1 : 0; }
    long aoff;
    const bf16* Bb;
    long coff;
    if (FLAGS & FLAG_HFB) {
        int b = bz & 7, c = bz >> 3;
        aoff = (long)b * abz + (long)tby * 64 * K;
        Bb = Bt + (long)c * 2097152L + (long)b * 262144L + (long)tbx * 64 * K;
        coff = (long)b * 2097152L + (long)c * 1048576L;
    } else {
        aoff = (long)batch * abz + (long)tby * 64 * K;
        Bb = Bt + (long)batch * bbz + (long)tbx * 64 * K;
        coff = (long)batch * cbz;
    }
    int tid = threadIdx.x;
    int lrow = tid >> 2;
    int lk = (tid & 3) * 8;
    int w = tid >> 6, lane = tid & 63;
    int wr = (w >> 1) * 32, wc = (w & 1) * 32;
    int fm = lane & 15, fk = (lane >> 4) * 8;
    f32x4 acc00 = {0.f,0.f,0.f,0.f}, acc01 = acc00, acc10 = acc00, acc11 = acc00;

    int klen = K / splitk;
    int k0 = kslice * klen;
    for (int kt = k0; kt < k0 + klen; kt += 32) {
        if (AMODE == 0) {
            const bf16* Ab = (const bf16*)Av + aoff;
            *(float4*)&As[lrow][lk] = *(const float4*)&Ab[(long)lrow * K + kt + lk];
        } else {
            const float* Af = (const float*)Av + aoff;
            int gk0 = kt + lk;
            float4 v0 = *(const float4*)&Af[(long)lrow * K + gk0];
            float4 v1 = *(const float4*)&Af[(long)lrow * K + gk0 + 4];
            float vv[8] = {v0.x, v0.y, v0.z, v0.w, v1.x, v1.y, v1.z, v1.w};
            int grow = tby * 64 + lrow;
            float sc = 0.f;
            if (AMODE == 2) sc = rsqrtf((float)((grow & 127) + 1)) * (1.0f / 92681.900089f);
            #pragma unroll
            for (int j = 0; j < 8; ++j) {
                float val = vv[j];
                int gk = gk0 + j;
                if (AMODE == 1) val = (gk < grow) ? val : 0.f;
                if (AMODE == 2) val = gelu_f(val * sc + abias[gk]);
                As[lrow][lk + j] = __float2bfloat16(val);
            }
        }
        *(float4*)&Bs[lrow][lk] = *(const float4*)&Bb[(long)lrow * K + kt + lk];
        __syncthreads();
        short8t a0 = *(const short8t*)&As[wr + fm][fk];
        short8t a1 = *(const short8t*)&As[wr + 16 + fm][fk];
        short8t b0 = *(const short8t*)&Bs[wc + fm][fk];
        short8t b1 = *(const short8t*)&Bs[wc + 16 + fm][fk];
        acc00 = __builtin_amdgcn_mfma_f32_16x16x32_bf16(a0, b0, acc00, 0, 0, 0);
        acc01 = __builtin_amdgcn_mfma_f32_16x16x32_bf16(a0, b1, acc01, 0, 0, 0);
        acc10 = __builtin_amdgcn_mfma_f32_16x16x32_bf16(a1, b0, acc10, 0, 0, 0);
        acc11 = __builtin_amdgcn_mfma_f32_16x16x32_bf16(a1, b1, acc11, 0, 0, 0);
        __syncthreads();
    }

    float* Cf = (float*)Cv;
    bf16* Cb = (bf16*)Cv;
    int row_base = tby * 64 + wr + (lane >> 4) * 4;
    int col_base = tbx * 64 + wc + fm;
    #pragma unroll
    for (int fr = 0; fr < 2; ++fr) {
        #pragma unroll
        for (int fc = 0; fc < 2; ++fc) {
            const f32x4& a = fr == 0 ? (fc == 0 ? acc00 : acc01) : (fc == 0 ? acc10 : acc11);
            #pragma unroll
            for (int r = 0; r < 4; ++r) {
                int gi = row_base + fr * 16 + r;
                int gj = col_base + fc * 16;
                float v = a[r];
                long ci = coff + (long)gi * ldc + gj;
                if (FLAGS & FLAG_ATOMIC) {
                    atomicAdd(&Cf[ci], v);
                } else {
                    if (FLAGS & FLAG_BIAS) v += bias[gj];
                    if (FLAGS & FLAG_GELU) v = gelu_f(v);
                    if (FLAGS & FLAG_ROWSCALE) v *= rsqrtf((float)(gi & 127) + 1.0f);
                    if (OUTB16) Cb[ci] = __float2bfloat16(v);
                    else        Cf[ci] = v;
                }
            }
        }
    }
}

// fused dual GEMM: z=0: vf = v1b(bf16,K=512) @ vp2T^T + vp_b2
//                  z=1: hfeat = gelu(hacc*scale+ro_b1)(K=128) @ ro2T^T + ro_b2
__global__ __launch_bounds__(256) void gemm_dual(
    const bf16* __restrict__ v1b, const bf16* __restrict__ vp2T, const float* __restrict__ vp_b2,
    const float* __restrict__ hacc, const bf16* __restrict__ ro2T, const float* __restrict__ ro_b1,
    const float* __restrict__ ro_b2, float* __restrict__ vf, float* __restrict__ hfeat)
{
    __shared__ __align__(16) bf16 As[64][44];
    __shared__ __align__(16) bf16 Bs[64][44];
    int tid = threadIdx.x;
    int lrow = tid >> 2, lk = (tid & 3) * 8;
    int w = tid >> 6, lane = tid & 63;
    int wr = (w >> 1) * 32, wc = (w & 1) * 32;
    int fm = lane & 15, fk = (lane >> 4) * 8;
    f32x4 acc00 = {0.f,0.f,0.f,0.f}, acc01 = acc00, acc10 = acc00, acc11 = acc00;
    int mode = blockIdx.z;
    int K = mode ? 128 : 512;
    const bf16* Bb = (mode ? ro2T : vp2T) + (long)blockIdx.x * 64 * K;

    for (int kt = 0; kt < K; kt += 32) {
        if (mode == 0) {
            const bf16* Ab = v1b + (long)blockIdx.y * 64 * K;
            *(float4*)&As[lrow][lk] = *(const float4*)&Ab[(long)lrow * K + kt + lk];
        } else {
            const float* Af = hacc + (long)blockIdx.y * 64 * K;
            int gk0 = kt + lk;
            float4 v0 = *(const float4*)&Af[(long)lrow * K + gk0];
            float4 v1 = *(const float4*)&Af[(long)lrow * K + gk0 + 4];
            float vv[8] = {v0.x, v0.y, v0.z, v0.w, v1.x, v1.y, v1.z, v1.w};
            int grow = blockIdx.y * 64 + lrow;
            float sc = rsqrtf((float)((grow & 127) + 1)) * (1.0f / 92681.900089f);
            #pragma unroll
            for (int j = 0; j < 8; ++j)
                As[lrow][lk + j] = __float2bfloat16(gelu_f(vv[j] * sc + ro_b1[gk0 + j]));
        }
        *(float4*)&Bs[lrow][lk] = *(const float4*)&Bb[(long)lrow * K + kt + lk];
        __syncthreads();
        short8t a0 = *(const short8t*)&As[wr + fm][fk];
        short8t a1 = *(const short8t*)&As[wr + 16 + fm][fk];
        short8t b0 = *(const short8t*)&Bs[wc + fm][fk];
        short8t b1 = *(const short8t*)&Bs[wc + 16 + fm][fk];
        acc00 = __builtin_amdgcn_mfma_f32_16x16x32_bf16(a0, b0, acc00, 0, 0, 0);
        acc01 = __builtin_amdgcn_mfma_f32_16x16x32_bf16(a0, b1, acc01, 0, 0, 0);
        acc10 = __builtin_amdgcn_mfma_f32_16x16x32_bf16(a1, b0, acc10, 0, 0, 0);
        acc11 = __builtin_amdgcn_mfma_f32_16x16x32_bf16(a1, b1, acc11, 0, 0, 0);
        __syncthreads();
    }

    const float* bias = mode ? ro_b2 : vp_b2;
    float* Cf = mode ? hfeat : vf;
    int row_base = blockIdx.y * 64 + wr + (lane >> 4) * 4;
    int col_base = blockIdx.x * 64 + wc + fm;
    #pragma unroll
    for (int fr = 0; fr < 2; ++fr) {
        #pragma unroll
        for (int fc = 0; fc < 2; ++fc) {
            const f32x4& a = fr == 0 ? (fc == 0 ? acc00 : acc01) : (fc == 0 ? acc10 : acc11);
            #pragma unroll
            for (int r = 0; r < 4; ++r) {
                int gi = row_base + fr * 16 + r;
                int gj = col_base + fc * 16;
                Cf[(long)gi * 512 + gj] = a[r] + bias[gj];
            }
        }
    }
}

// LN over D=512. FINAL=0: LN(x1); FINAL=1: LN(x1 + gf*x2 + gv*x3). OB16 selects out dtype.
template<int FINAL, int OB16>
__global__ __launch_bounds__(256) void ln_kernel(const float* __restrict__ x1,
                                                 const float* __restrict__ x2,
                                                 const float* __restrict__ x3,
                                                 const float* __restrict__ g,
                                                 const float* __restrict__ bb,
                                                 const float* __restrict__ scal,
                                                 void* __restrict__ outv) {
    int row = blockIdx.x, tid = threadIdx.x;
    long base = (long)row * D_;
    int d0 = tid, d1 = tid + 256;
    float v0, v1;
    if (FINAL) {
        float gf = scal[3], gv = scal[4];
        v0 = x1[base + d0] + gf * x2[base + d0] + gv * x3[base + d0];
        v1 = x1[base + d1] + gf * x2[base + d1] + gv * x3[base + d1];
    } else {
        v0 = x1[base + d0];
        v1 = x1[base + d1];
    }
    float s = v0 + v1;
    #pragma unroll
    for (int o = 32; o > 0; o >>= 1) s += __shfl_down(s, o);
    __shared__ float red[8];
    int wid = tid >> 6, lane = tid & 63;
    if (lane == 0) red[wid] = s;
    __syncthreads();
    float mu = (red[0] + red[1] + red[2] + red[3]) * (1.0f / D_);
    float e0 = v0 - mu, e1 = v1 - mu;
    float sq = e0 * e0 + e1 * e1;
    #pragma unroll
    for (int o = 32; o > 0; o >>= 1) sq += __shfl_down(sq, o);
    if (lane == 0) red[4 + wid] = sq;
    __syncthreads();
    float var = (red[4] + red[5] + red[6] + red[7]) * (1.0f / D_);
    float rs = rsqrtf(var + 1e-5f);
    float o0 = e0 * rs * g[d0] + bb[d0];
    float o1 = e1 * rs * g[d1] + bb[d1];
    if (OB16) {
        ((bf16*)outv)[base + d0] = __float2bfloat16(o0);
        ((bf16*)outv)[base + d1] = __float2bfloat16(o1);
    } else {
        ((float*)outv)[base + d0] = o0;
        ((float*)outv)[base + d1] = o1;
    }
}

extern "C" void kernel_launch(void* const* d_in, const int* in_sizes, int n_in,
                              void* d_out, int out_size, void* d_ws, size_t ws_size,
                              hipStream_t stream) {
    const float* e      = (const float*)d_in[0];
    const int*   h      = (const int*)d_in[1];
    const float* sign   = (const float*)d_in[2];
    const float* Wq     = (const float*)d_in[3];
    const float* Wk     = (const float*)d_in[4];
    const float* Wv     = (const float*)d_in[5];
    const float* ro_w1  = (const float*)d_in[6];
    const float* ro_b1  = (const float*)d_in[7];
    const float* ro_w2  = (const float*)d_in[8];
    const float* ro_b2  = (const float*)d_in[9];
    const float* vp_ln_g= (const float*)d_in[10];
    const float* vp_ln_b= (const float*)d_in[11];
    const float* vp_w1  = (const float*)d_in[12];
    const float* vp_b1  = (const float*)d_in[13];
    const float* vp_w2  = (const float*)d_in[14];
    const float* vp_b2  = (const float*)d_in[15];
    const float* ln_g   = (const float*)d_in[16];
    const float* ln_b   = (const float*)d_in[17];
    const float* tq     = (const float*)d_in[18];
    const float* tk     = (const float*)d_in[19];
    const float* om     = (const float*)d_in[20];
    const float* gfr    = (const float*)d_in[21];
    const float* gvr    = (const float*)d_in[22];

    float* ws    = (float*)d_ws;
    float* scal  = ws + OFF_SCAL;
    float* qkv   = ws + OFF_QKV;
    float* sk2   = ws + OFF_SK2;
    float* vraw  = ws + OFF_VRAW;
    float* vf    = ws + OFF_VF;
    float* hfeat = ws + OFF_HFEAT;
    float* scoacc= ws + OFF_SCOA;
    float* qsum  = ws + OFF_QSUM;
    float* hacc  = ws + OFF_HACC;
    bf16* kp16  = (bf16*)(ws + OFF_KP);
    bf16* eb    = (bf16*)(ws + OFF_EB);
    bf16* wqkvT = (bf16*)(ws + OFF_WQKVT);
    bf16* vp1T  = (bf16*)(ws + OFF_VP1T);
    bf16* vp2T  = (bf16*)(ws + OFF_VP2T);
    bf16* ro2T  = (bf16*)(ws + OFF_RO2T);
    bf16* qcat  = (bf16*)(ws + OFF_QCAT);
    bf16* kcat  = (bf16*)(ws + OFF_KCAT);
    bf16* dkT   = (bf16*)(ws + OFF_DKT);
    bf16* vTb   = (bf16*)(ws + OFF_VTB);
    bf16* vlnb  = (bf16*)(ws + OFF_VLNB);
    bf16* v1b   = (bf16*)(ws + OFF_V1B);
    bf16* pcat  = (bf16*)(ws + OFF_PCAT);
    bf16* ro1f  = (bf16*)(ws + OFF_RO1F);

    float* ys = (float*)d_out;
    float* kf = ys + (long)BT_ * D_;
    float* hf = kf + (long)B_ * 2 * M_;

    // fused preprocessing: scal+zero | e-cast | weight transposes | ro1 FFT
    preproc_kernel<<<3200, 256, 0, stream>>>(
        tq, tk, om, gfr, gvr, scal, scoacc, hacc,
        (const float4*)e, (ushort4t*)eb,
        Wq, Wk, Wv, vp_w1, vp_w2, ro_w2,
        wqkvT, wqkvT + 262144, wqkvT + 524288, vp1T, vp2T, ro2T,
        ro_w1, ro1f);

    // qkv = e @ [Wq|Wk|Wv]  (1024 x 1536 x 512) -> f32
    gemm_mfma<0, 0, 0><<<dim3(24, 16, 1), 256, 0, stream>>>(
        eb, wqkvT, nullptr, nullptr, qkv, 512, 1536, 0, 0, 0, 1);

    sketch_kernel<<<1024, 256, 0, stream>>>(qkv, sign, scal, h, sk2, qcat, kcat);
    prefix_p1<<<512, 256, 0, stream>>>(sk2, qsum);
    prefix_p2<<<512, 256, 0, stream>>>(sk2, qsum, kp16, dkT, kf);

    // forward FFTs + spectral product (no inverse; scrambled order matches ro1f)
    fwdfft_kernel<<<1024, 256, 0, stream>>>(qcat, kp16, pcat);

    // vTb[b][d][t] from qkv v-columns
    castT_kernel<<<dim3(16, 4, 8), 256, 0, stream>>>(qkv + 1024, vTb, 128, 512, 1536, 196608, 65536);

    // scores: split-K 16, triangle-skip (3 of 4 tiles), f32 atomic accumulate
    gemm_mfma<FLAG_ATOMIC | FLAG_TRI, 0, 0><<<dim3(3, 1, 128), 256, 0, stream>>>(
        qcat, kcat, nullptr, nullptr, scoacc, 4096, 128, 524288, 524288, 16384, 16);

    // vraw[b] = masked(scores) @ v * rsqrt(t+1)  (mask fused in A-load)
    gemm_mfma<FLAG_ROWSCALE, 0, 1><<<dim3(8, 2, 8), 256, 0, stream>>>(
        scoacc, vTb, nullptr, nullptr, vraw, 128, 512, 16384, 65536, 65536, 1);

    ln_kernel<0, 1><<<1024, 256, 0, stream>>>(vraw, nullptr, nullptr, vp_ln_g, vp_ln_b, scal, vlnb);

    // v1b = gelu(vlnb @ vp1T + b1)
    gemm_mfma<FLAG_BIAS | FLAG_GELU, 1, 0><<<dim3(8, 16, 1), 256, 0, stream>>>(
        vlnb, vp1T, vp_b1, nullptr, v1b, 512, 512, 0, 0, 0, 1);

    // hid_pre = pcat @ ro1f^T (1024x128x4096), split-K 8 atomic into hacc
    gemm_mfma<FLAG_ATOMIC, 0, 0><<<dim3(2, 16, 8), 256, 0, stream>>>(
        pcat, ro1f, nullptr, nullptr, hacc, 4096, 128, 0, 0, 0, 8);

    // fused: vf = v1b@vp2T + b2  ||  hfeat = gelu(hacc*scale+ro_b1)@ro2T + ro_b2
    gemm_dual<<<dim3(8, 16, 2), 256, 0, stream>>>(
        v1b, vp2T, vp_b2, hacc, ro2T, ro_b1, ro_b2, vf, hfeat);

    // ys = LN(e + gf*hfeat + gv*vf)
    ln_kernel<1, 0><<<1024, 256, 0, stream>>>(e, hfeat, vf, ln_g, ln_b, scal, ys);

    // Hf fused: z in [0,16), b=z&7, c=z>>3
    gemm_mfma<FLAG_HFB, 0, 0><<<dim3(32, 8, 16), 256, 0, stream>>>(
        vTb, dkT, nullptr, nullptr, hf, 128, 2048, 65536, 0, 0, 1);
}

// Round 15
// 141.442 us; speedup vs baseline: 2.1766x; 1.0337x over previous
//
#include <hip/hip_runtime.h>
#include <hip/hip_bf16.h>
#include <math.h>

#define B_   8
#define T_   128
#define D_   512
#define M_   2048
#define HID_ 128
#define BT_  1024

typedef __attribute__((ext_vector_type(8))) short short8t;
typedef __attribute__((ext_vector_type(8))) unsigned short ushort8t;
typedef __attribute__((ext_vector_type(4))) unsigned short ushort4t;
typedef __attribute__((ext_vector_type(4))) float f32x4;
typedef __hip_bfloat16 bf16;

// ws layout (float offsets; all multiples of 16 -> 64B aligned)
#define OFF_SCAL   0L
#define OFF_QKV    16L                            // 1024*1536 f32
#define OFF_KP     (OFF_QKV + 1572864L)           // [KR|KI] bf16 exclusive prefix (2*BT*M bf16)
#define OFF_VRAW   (OFF_KP + 2097152L)
#define OFF_VF     (OFF_VRAW + 524288L)
#define OFF_HFEAT  (OFF_VF + 524288L)
// bf16 buffers (size in floats = elems/2)
#define OFF_EB     (OFF_HFEAT + 524288L)          // 1024x512
#define OFF_WQKVT  (OFF_EB + 262144L)             // 1536x512
#define OFF_VP1T   (OFF_WQKVT + 393216L)          // 512x512
#define OFF_VP2T   (OFF_VP1T + 131072L)
#define OFF_RO2T   (OFF_VP2T + 131072L)           // 512x128
#define OFF_QCAT   (OFF_RO2T + 32768L)            // 1024x4096
#define OFF_KCAT   (OFF_QCAT + 2097152L)          // 1024x4096
#define OFF_DKT    (OFF_KCAT + 2097152L)          // 2x8x2048x128
#define OFF_VTB    (OFF_DKT + 2097152L)           // 8x512x128
#define OFF_VLNB   (OFF_VTB + 262144L)            // 1024x512
#define OFF_V1B    (OFF_VLNB + 262144L)           // 1024x512
#define OFF_SCOA   (OFF_V1B + 262144L)            // 8x128x128 f32 split-K accumulator
#define OFF_QSUM   (OFF_SCOA + 131072L)           // 4x32768 f32 prefix quarter sums
#define OFF_PCAT   (OFF_QSUM + 131072L)           // 1024x4096 bf16 [ReP|ImP]
#define OFF_RO1F   (OFF_PCAT + 2097152L)          // 128x4096 bf16 [ReG|ImG]
#define OFF_HACC   (OFF_RO1F + 262144L)           // 1024x128 f32

#define FLAG_BIAS     1
#define FLAG_GELU     2
#define FLAG_ROWSCALE 4
#define FLAG_ATOMIC   8
#define FLAG_HFB      32
#define FLAG_TRI      64

__device__ __forceinline__ float gelu_f(float x) {
    return 0.5f * x * (1.0f + erff(x * 0.70710678118654752440f));
}

__device__ __forceinline__ float b2f(unsigned short u) {
    return __uint_as_float(((unsigned int)u) << 16);
}

#define PIDX(i) ((i) + ((i) >> 5))

template<int M>
__device__ __forceinline__ void dif_one(float* re, float* im, int tid) {
    #pragma unroll
    for (int u = 0; u < 4; ++u) {
        int q = u * 256 + tid;
        int k = q & (M - 1);
        int i = (q / M) * (2 * M) + k;
        float s, c;
        __sincosf((float)k * (3.14159265358979323846f / (float)M), &s, &c);
        int p0 = PIDX(i), p1 = PIDX(i + M);
        float ar = re[p0], ai = im[p0], br = re[p1], bi = im[p1];
        re[p0] = ar + br; im[p0] = ai + bi;
        float dr = ar - br, di = ai - bi;
        re[p1] = dr * c + di * s;
        im[p1] = di * c - dr * s;
    }
}

// ==== fused preprocessing: scal+zero | e-cast | 6x weight transpose | ro1 FFT ====
__global__ __launch_bounds__(256) void preproc_kernel(
    const float* tq, const float* tk, const float* om, const float* gf, const float* gv,
    float* scal, float* scoacc, float* hacc,
    const float4* __restrict__ e4, ushort4t* __restrict__ eb4,
    const float* w0, const float* w1, const float* w2, const float* w3,
    const float* w4, const float* w5,
    bf16* d0, bf16* d1, bf16* d2, bf16* d3, bf16* d4, bf16* d5,
    const float* __restrict__ ro_w1, bf16* __restrict__ ro1f)
{
    __shared__ float smem[4224];   // 16.9 KB union
    int blk = blockIdx.x, tid = threadIdx.x;

    if (blk < 1024) {
        int idx = blk * 256 + tid;
        if (idx < 131072) scoacc[idx] = 0.f;
        else hacc[idx - 131072] = 0.f;
        if (idx == 0) {
            scal[0] = 0.5f * tanhf(tq[0]);
            scal[1] = 0.5f * tanhf(tk[0]);
            scal[2] = 0.5f * tanhf(om[0]);
            scal[3] = 0.25f / (1.0f + expf(-gf[0]));
            scal[4] = 0.25f / (1.0f + expf(-gv[0]));
        }
        return;
    }
    if (blk < 1536) {
        int i = (blk - 1024) * 256 + tid;   // < 131072
        float4 v = e4[i];
        ushort4t o;
        bf16 h0 = __float2bfloat16(v.x), h1 = __float2bfloat16(v.y);
        bf16 h2 = __float2bfloat16(v.z), h3 = __float2bfloat16(v.w);
        o[0] = *(unsigned short*)&h0; o[1] = *(unsigned short*)&h1;
        o[2] = *(unsigned short*)&h2; o[3] = *(unsigned short*)&h3;
        eb4[i] = o;
        return;
    }
    if (blk < 3072) {
        int zz = blk - 1536;
        int wz = zz >> 8;
        int rem = zz & 255;
        int by = rem >> 4, bx = rem & 15;
        const float* src; bf16* dst; int R = 512;
        if (wz == 0)      { src = w0; dst = d0; }
        else if (wz == 1) { src = w1; dst = d1; }
        else if (wz == 2) { src = w2; dst = d2; }
        else if (wz == 3) { src = w3; dst = d3; }
        else if (wz == 4) { src = w4; dst = d4; }
        else              { src = w5; dst = d5; R = 128; }
        int c0 = bx * 32, r0 = by * 32;
        if (r0 >= R) return;
        float (*tile)[33] = (float(*)[33])smem;
        int tx = tid & 31, ty = tid >> 5;
        for (int rr = ty; rr < 32; rr += 8) {
            int r = r0 + rr;
            tile[rr][tx] = (r < R) ? src[(long)r * 512 + c0 + tx] : 0.f;
        }
        __syncthreads();
        int r = r0 + tx;
        if (r < R)
            for (int cc = ty; cc < 32; cc += 8)
                dst[(long)(c0 + cc) * R + r] = __float2bfloat16(tile[tx][cc]);
        return;
    }
    {   // ro1fft
        int j = blk - 3072;
        float* Rs = smem;
        float* Is = smem + 2112;
        for (int u = 0; u < 8; ++u) {
            int n = u * 256 + tid;
            Rs[PIDX(n)] = ro_w1[(long)n * HID_ + j];
            Is[PIDX(n)] = 0.f;
        }
        __syncthreads();
#define FSTEP(MM) dif_one<MM>(Rs, Is, tid); __syncthreads();
        FSTEP(1024) FSTEP(512) FSTEP(256) FSTEP(128) FSTEP(64)
        FSTEP(32) FSTEP(16) FSTEP(8) FSTEP(4) FSTEP(2) FSTEP(1)
#undef FSTEP
        unsigned short* op = (unsigned short*)(ro1f + (long)j * 4096);
        for (int u = 0; u < 8; ++u) {
            int r = u * 256 + tid;
            int pr = PIDX(r);
            bf16 re = __float2bfloat16(Rs[pr]);
            bf16 im = __float2bfloat16(Is[pr]);
            op[r]        = *(unsigned short*)&re;
            op[2048 + r] = *(unsigned short*)&im;
        }
    }
}

// ==== fused sketch + vTb transpose (both depend only on qkv) ====
// blocks [0,1024): sketch(bt) -> qcat/kcat (no f32 SK2 anymore)
// blocks [1024,1536): vTb[b][d][t] transpose of qkv v-columns
__global__ __launch_bounds__(256) void sketchvtb_kernel(const float* __restrict__ qkv,
                                                        const float* __restrict__ sign,
                                                        const float* __restrict__ scal,
                                                        const int* __restrict__ h,
                                                        bf16* __restrict__ qcat,
                                                        bf16* __restrict__ kcat,
                                                        bf16* __restrict__ vTb) {
    __shared__ float smem[4 * M_];   // 32 KB: sketch accumulators / transpose tile union
    int blk = blockIdx.x, tid = threadIdx.x;
    if (blk < 1024) {
        int bt = blk;
        float* s0 = smem;
        float* s1 = smem + M_;
        float* s2 = smem + 2 * M_;
        float* s3 = smem + 3 * M_;
        for (int j = tid; j < M_; j += 256) { s0[j] = 0.f; s1[j] = 0.f; s2[j] = 0.f; s3[j] = 0.f; }
        __syncthreads();
        int t = bt & 127;
        float thq = scal[0], thk = scal[1], omg = scal[2];
        float ft = (float)t;
        for (int i = tid; i < D_; i += 256) {
            float q = qkv[(long)bt * 1536 + i];
            float k = qkv[(long)bt * 1536 + 512 + i];
            float sg = sign[i];
            float sq_, cq_, sk_, ck_;
            __sincosf(thq * q - omg * ft, &sq_, &cq_);
            __sincosf(thk * k + omg * ft, &sk_, &ck_);
            int m = h[i];
            atomicAdd(&s0[m], q * cq_ * sg);
            atomicAdd(&s1[m], q * sq_ * sg);
            atomicAdd(&s2[m], k * ck_ * sg);
            atomicAdd(&s3[m], k * sk_ * sg);
        }
        __syncthreads();
        long qb = (long)bt * 4096;
        for (int j = tid; j < M_; j += 256) {
            qcat[qb + j]        = __float2bfloat16(s0[j]);
            qcat[qb + 2048 + j] = __float2bfloat16(s1[j]);
            kcat[qb + j]        = __float2bfloat16(s2[j]);
            kcat[qb + 2048 + j] = __float2bfloat16(-s3[j]);
        }
        return;
    }
    {   // vTb transpose: R=128 (t), C=512 (d), in = qkv+1024, ld 1536
        int zz = blk - 1024;           // [0,512)
        int b = zz >> 6;
        int rem = zz & 63;
        int by = rem >> 4, bx = rem & 15;
        int c0 = bx * 32, r0 = by * 32;
        float (*tile)[33] = (float(*)[33])smem;
        int tx = tid & 31, ty = tid >> 5;
        const float* in = qkv + 1024 + (long)b * 196608L;
        for (int rr = ty; rr < 32; rr += 8)
            tile[rr][tx] = in[(long)(r0 + rr) * 1536 + c0 + tx];
        __syncthreads();
        bf16* out = vTb + (long)b * 65536L;
        for (int cc = ty; cc < 32; cc += 8)
            out[(long)(c0 + cc) * 128 + r0 + tx] = __float2bfloat16(tile[tx][cc]);
    }
}

// ---- two-phase exclusive prefix over t (4-way t split), reading bf16 kcat ----
// kcat element (b,t,comp,m) at [(b*128+t)*4096 + comp*2048 + m]; comp=1 stored negated.
__global__ __launch_bounds__(256) void prefix_p1(const bf16* __restrict__ kcat,
                                                 float* __restrict__ qsum) {
    int idx = blockIdx.x * 256 + threadIdx.x;   // 131072
    int col = idx & 32767, q = idx >> 15;
    int m = col & 2047, b = (col >> 11) & 7, comp = col >> 14;
    const unsigned short* src = (const unsigned short*)kcat
        + ((long)(b * 128 + q * 32) * 4096L + (long)comp * 2048L + m);
    float s = 0.f;
    #pragma unroll 8
    for (int i = 0; i < 32; ++i) s += b2f(src[(long)i * 4096L]);
    if (comp) s = -s;
    qsum[(long)q * 32768 + col] = s;
}

// KP written as bf16; also emits dkT[c][b][m][t] bf16 (t-contiguous per thread)
__global__ __launch_bounds__(256) void prefix_p2(const bf16* __restrict__ kcat,
                                                 const float* __restrict__ qsum,
                                                 bf16* __restrict__ KP16,
                                                 bf16* __restrict__ dkT,
                                                 float* __restrict__ kf_out) {
    int idx = blockIdx.x * 256 + threadIdx.x;   // 131072
    int col = idx & 32767, q = idx >> 15;
    int m = col & 2047, b = (col >> 11) & 7, comp = col >> 14;
    const unsigned short* src = (const unsigned short*)kcat
        + ((long)(b * 128 + q * 32) * 4096L + (long)comp * 2048L + m);
    bf16* dst = KP16 + (long)comp * BT_ * M_ + (long)b * T_ * M_ + m + (long)(q * 32) * M_;
    bf16* dkt = dkT + (long)comp * 2097152L + (long)b * 262144L + (long)m * 128L + (long)(q * 32);
    float acc = 0.f;
    for (int p = 0; p < q; ++p) acc += qsum[(long)p * 32768 + col];
    float sgn = comp ? -1.f : 1.f;
    #pragma unroll 4
    for (int i = 0; i < 32; ++i) {
        float v = sgn * b2f(src[(long)i * 4096L]);
        dst[(long)i * M_] = __float2bfloat16(acc);
        dkt[i] = __float2bfloat16(v);
        acc += v;
    }
    if (q == 3) kf_out[((long)b * 2 + comp) * M_ + m] = acc;
}

// fused 3-stage radix-8 DIF pass on both (K,Q) arrays.
template<int S>
__device__ __forceinline__ void dif8_pair(float* r0, float* i0a, float* r1, float* i1a, int tid) {
    int k = tid % S;
    int grp = tid / S;
    int base = grp * 8 * S + k;
    float sw, cw;
    __sincosf((float)k * (3.14159265358979323846f / (4.0f * (float)S)), &sw, &cw);
    float wr = cw, wi = -sw;
    float w2r = wr * wr - wi * wi, w2i = 2.f * wr * wi;
    float w4r = w2r * w2r - w2i * w2i, w4i = 2.f * w2r * w2i;
    const float RH = 0.70710678118654752440f;
    float t1r[4] = {wr, (wr + wi) * RH, wi, (wi - wr) * RH};
    float t1i[4] = {wi, (wi - wr) * RH, -wr, -(wr + wi) * RH};
    float u0r = w2r, u0i = w2i;
    float u1r = w2i, u1i = -w2r;
    #pragma unroll
    for (int a = 0; a < 2; ++a) {
        float* re = a ? r1 : r0;
        float* im = a ? i1a : i0a;
        float xr[8], xi[8];
        #pragma unroll
        for (int r = 0; r < 8; ++r) { int p = PIDX(base + r * S); xr[r] = re[p]; xi[r] = im[p]; }
        #pragma unroll
        for (int r = 0; r < 4; ++r) {
            float ar = xr[r], ai = xi[r], br = xr[r + 4], bi = xi[r + 4];
            xr[r] = ar + br; xi[r] = ai + bi;
            float dr = ar - br, di = ai - bi;
            xr[r + 4] = dr * t1r[r] - di * t1i[r];
            xi[r + 4] = dr * t1i[r] + di * t1r[r];
        }
        #pragma unroll
        for (int hb = 0; hb < 8; hb += 4) {
            #pragma unroll
            for (int r = 0; r < 2; ++r) {
                float tr = (r == 0) ? u0r : u1r, ti = (r == 0) ? u0i : u1i;
                float ar = xr[hb + r], ai = xi[hb + r], br = xr[hb + r + 2], bi = xi[hb + r + 2];
                xr[hb + r] = ar + br; xi[hb + r] = ai + bi;
                float dr = ar - br, di = ai - bi;
                xr[hb + r + 2] = dr * tr - di * ti;
                xi[hb + r + 2] = dr * ti + di * tr;
            }
        }
        #pragma unroll
        for (int r = 0; r < 8; r += 2) {
            float ar = xr[r], ai = xi[r], br = xr[r + 1], bi = xi[r + 1];
            xr[r] = ar + br; xi[r] = ai + bi;
            float dr = ar - br, di = ai - bi;
            xr[r + 1] = dr * w4r - di * w4i;
            xi[r + 1] = dr * w4i + di * w4r;
        }
        #pragma unroll
        for (int r = 0; r < 8; ++r) { int p = PIDX(base + r * S); re[p] = xr[r]; im[p] = xi[r]; }
    }
}

// forward FFTs of Q sketch and K prefix; pcat = [Re(FQ*FK) | Im(FQ*FK)] bf16 (scrambled order)
__global__ __launch_bounds__(256) void fwdfft_kernel(const bf16* __restrict__ qcat,
                                                     const bf16* __restrict__ KP16,
                                                     bf16* __restrict__ pcat) {
    __shared__ float KRs[2112], KIs[2112], QRs[2112], QIs[2112];   // 33 KB
    int bt = blockIdx.x, tid = threadIdx.x;
    const unsigned short* qp = (const unsigned short*)(qcat + (long)bt * 4096);
    const unsigned short* kpr = (const unsigned short*)(KP16 + (long)bt * M_);
    const unsigned short* kpi = (const unsigned short*)(KP16 + (long)BT_ * M_ + (long)bt * M_);
    for (int u = 0; u < 8; ++u) {
        int j = u * 256 + tid;
        int pj = PIDX(j);
        KRs[pj] = b2f(kpr[j]);
        KIs[pj] = b2f(kpi[j]);
        QRs[pj] = b2f(qp[j]);
        QIs[pj] = b2f(qp[2048 + j]);
    }
    __syncthreads();
    dif8_pair<256>(KRs, KIs, QRs, QIs, tid);  __syncthreads();
    dif8_pair<32>(KRs, KIs, QRs, QIs, tid);   __syncthreads();

    float kr_[8], ki_[8], qr_[8], qi_[8];
    #pragma unroll
    for (int l = 0; l < 8; ++l) {
        int pj = PIDX(8 * tid + l);
        kr_[l] = KRs[pj]; ki_[l] = KIs[pj];
        qr_[l] = QRs[pj]; qi_[l] = QIs[pj];
    }

    const float C16[16] = {1.f, 0.98078528f, 0.92387953f, 0.83146961f,
                           0.70710678f, 0.55557023f, 0.38268343f, 0.19509032f,
                           0.f, -0.19509032f, -0.38268343f, -0.55557023f,
                           -0.70710678f, -0.83146961f, -0.92387953f, -0.98078528f};
    const float S16[16] = {0.f, 0.19509032f, 0.38268343f, 0.55557023f,
                           0.70710678f, 0.83146961f, 0.92387953f, 0.98078528f,
                           1.f, 0.98078528f, 0.92387953f, 0.83146961f,
                           0.70710678f, 0.55557023f, 0.38268343f, 0.19509032f};
    bool odd = (tid & 1) != 0;
    {
        bool hi2 = (tid & 2) != 0;
        #pragma unroll
        for (int l = 0; l < 8; ++l) {
            float c = odd ? C16[l + 8] : C16[l];
            float s = odd ? S16[l + 8] : S16[l];
            float pr, pi2, sr, si, dr, di;
            pr = __shfl_xor(kr_[l], 2); pi2 = __shfl_xor(ki_[l], 2);
            sr = kr_[l] + pr; si = ki_[l] + pi2;
            dr = pr - kr_[l]; di = pi2 - ki_[l];
            kr_[l] = hi2 ? (dr * c + di * s) : sr;
            ki_[l] = hi2 ? (di * c - dr * s) : si;
            pr = __shfl_xor(qr_[l], 2); pi2 = __shfl_xor(qi_[l], 2);
            sr = qr_[l] + pr; si = qi_[l] + pi2;
            dr = pr - qr_[l]; di = pi2 - qi_[l];
            qr_[l] = hi2 ? (dr * c + di * s) : sr;
            qi_[l] = hi2 ? (di * c - dr * s) : si;
        }
    }
    {
        #pragma unroll
        for (int l = 0; l < 8; ++l) {
            float c = C16[2 * l];
            float s = S16[2 * l];
            float pr, pi2, sr, si, dr, di;
            pr = __shfl_xor(kr_[l], 1); pi2 = __shfl_xor(ki_[l], 1);
            sr = kr_[l] + pr; si = ki_[l] + pi2;
            dr = pr - kr_[l]; di = pi2 - ki_[l];
            kr_[l] = odd ? (dr * c + di * s) : sr;
            ki_[l] = odd ? (di * c - dr * s) : si;
            pr = __shfl_xor(qr_[l], 1); pi2 = __shfl_xor(qi_[l], 1);
            sr = qr_[l] + pr; si = qi_[l] + pi2;
            dr = pr - qr_[l]; di = pi2 - qi_[l];
            qr_[l] = odd ? (dr * c + di * s) : sr;
            qi_[l] = odd ? (di * c - dr * s) : si;
        }
    }
    {
        const float C4[4] = {1.f, 0.70710678f, 0.f, -0.70710678f};
        const float S4[4] = {0.f, 0.70710678f, 1.f, 0.70710678f};
        #pragma unroll
        for (int l = 0; l < 4; ++l) {
            float ar, ai, br, bi, dr, di;
            ar = kr_[l]; ai = ki_[l]; br = kr_[l + 4]; bi = ki_[l + 4];
            kr_[l] = ar + br; ki_[l] = ai + bi;
            dr = ar - br; di = ai - bi;
            kr_[l + 4] = dr * C4[l] + di * S4[l];
            ki_[l + 4] = di * C4[l] - dr * S4[l];
            ar = qr_[l]; ai = qi_[l]; br = qr_[l + 4]; bi = qi_[l + 4];
            qr_[l] = ar + br; qi_[l] = ai + bi;
            dr = ar - br; di = ai - bi;
            qr_[l + 4] = dr * C4[l] + di * S4[l];
            qi_[l + 4] = di * C4[l] - dr * S4[l];
        }
    }
    #pragma unroll
    for (int b2 = 0; b2 < 8; b2 += 4) {
        {
            float ar = kr_[b2], ai = ki_[b2], br = kr_[b2 + 2], bi = ki_[b2 + 2];
            kr_[b2] = ar + br; ki_[b2] = ai + bi;
            kr_[b2 + 2] = ar - br; ki_[b2 + 2] = ai - bi;
            ar = qr_[b2]; ai = qi_[b2]; br = qr_[b2 + 2]; bi = qi_[b2 + 2];
            qr_[b2] = ar + br; qi_[b2] = ai + bi;
            qr_[b2 + 2] = ar - br; qi_[b2 + 2] = ai - bi;
        }
        {
            float ar = kr_[b2 + 1], ai = ki_[b2 + 1], br = kr_[b2 + 3], bi = ki_[b2 + 3];
            kr_[b2 + 1] = ar + br; ki_[b2 + 1] = ai + bi;
            float dr = ar - br, di = ai - bi;
            kr_[b2 + 3] = di; ki_[b2 + 3] = -dr;
            ar = qr_[b2 + 1]; ai = qi_[b2 + 1]; br = qr_[b2 + 3]; bi = qi_[b2 + 3];
            qr_[b2 + 1] = ar + br; qi_[b2 + 1] = ai + bi;
            dr = ar - br; di = ai - bi;
            qr_[b2 + 3] = di; qi_[b2 + 3] = -dr;
        }
    }
    #pragma unroll
    for (int i0 = 0; i0 < 8; i0 += 2) {
        float ar = kr_[i0], ai = ki_[i0], br = kr_[i0 + 1], bi = ki_[i0 + 1];
        kr_[i0] = ar + br; ki_[i0] = ai + bi;
        kr_[i0 + 1] = ar - br; ki_[i0 + 1] = ai - bi;
        ar = qr_[i0]; ai = qi_[i0]; br = qr_[i0 + 1]; bi = qi_[i0 + 1];
        qr_[i0] = ar + br; qi_[i0] = ai + bi;
        qr_[i0 + 1] = ar - br; qi_[i0 + 1] = ai - bi;
    }

    unsigned short* op = (unsigned short*)(pcat + (long)bt * 4096 + 8 * tid);
    ushort8t ore, oim;
    #pragma unroll
    for (int l = 0; l < 8; ++l) {
        float pr = qr_[l] * kr_[l] - qi_[l] * ki_[l];
        float pi2 = qr_[l] * ki_[l] + qi_[l] * kr_[l];
        bf16 hr = __float2bfloat16(pr);
        bf16 hi = __float2bfloat16(pi2);
        ore[l] = *(unsigned short*)&hr;
        oim[l] = *(unsigned short*)&hi;
    }
    *(ushort8t*)op = ore;
    *(ushort8t*)(op + 2048) = oim;
}

// MFMA bf16 TN GEMM: C[M,N] = A * Bt^T. 64x64 tile, 4 waves.
// AMODE 0: A bf16. AMODE 1: A f32 + causal mask. AMODE 2: A f32, gelu(a*scale+abias).
// FLAG_TRI: blockIdx.x in {0,1,2} decodes (tile_x,tile_y) = (0,0),(0,1),(1,1).
template<int FLAGS, int OUTB16, int AMODE>
__global__ __launch_bounds__(256) void gemm_mfma(
    const void* __restrict__ Av, const bf16* __restrict__ Bt,
    const float* __restrict__ bias, const float* __restrict__ abias,
    void* __restrict__ Cv,
    int K, int ldc, long abz, long bbz, long cbz, int splitk)
{
    __shared__ __align__(16) bf16 As[64][44];
    __shared__ __align__(16) bf16 Bs[64][44];
    int bz = blockIdx.z;
    int batch = bz, kslice = 0;
    if (FLAGS & FLAG_ATOMIC) { batch = bz / splitk; kslice = bz % splitk; }
    int tbx = blockIdx.x, tby = blockIdx.y;
    if (FLAGS & FLAG_TRI) { tby = (blockIdx.x > 0) ? 1 : 0; tbx = (blockIdx.x == 2) ? 1 : 0; }
    long aoff;
    const bf16* Bb;
    long coff;
    if (FLAGS & FLAG_HFB) {
        int b = bz & 7, c = bz >> 3;
        aoff = (long)b * abz + (long)tby * 64 * K;
        Bb = Bt + (long)c * 2097152L + (long)b * 262144L + (long)tbx * 64 * K;
        coff = (long)b * 2097152L + (long)c * 1048576L;
    } else {
        aoff = (long)batch * abz + (long)tby * 64 * K;
        Bb = Bt + (long)batch * bbz + (long)tbx * 64 * K;
        coff = (long)batch * cbz;
    }
    int tid = threadIdx.x;
    int lrow = tid >> 2;
    int lk = (tid & 3) * 8;
    int w = tid >> 6, lane = tid & 63;
    int wr = (w >> 1) * 32, wc = (w & 1) * 32;
    int fm = lane & 15, fk = (lane >> 4) * 8;
    f32x4 acc00 = {0.f,0.f,0.f,0.f}, acc01 = acc00, acc10 = acc00, acc11 = acc00;

    int klen = K / splitk;
    int k0 = kslice * klen;
    for (int kt = k0; kt < k0 + klen; kt += 32) {
        if (AMODE == 0) {
            const bf16* Ab = (const bf16*)Av + aoff;
            *(float4*)&As[lrow][lk] = *(const float4*)&Ab[(long)lrow * K + kt + lk];
        } else {
            const float* Af = (const float*)Av + aoff;
            int gk0 = kt + lk;
            float4 v0 = *(const float4*)&Af[(long)lrow * K + gk0];
            float4 v1 = *(const float4*)&Af[(long)lrow * K + gk0 + 4];
            float vv[8] = {v0.x, v0.y, v0.z, v0.w, v1.x, v1.y, v1.z, v1.w};
            int grow = tby * 64 + lrow;
            float sc = 0.f;
            if (AMODE == 2) sc = rsqrtf((float)((grow & 127) + 1)) * (1.0f / 92681.900089f);
            #pragma unroll
            for (int j = 0; j < 8; ++j) {
                float val = vv[j];
                int gk = gk0 + j;
                if (AMODE == 1) val = (gk < grow) ? val : 0.f;
                if (AMODE == 2) val = gelu_f(val * sc + abias[gk]);
                As[lrow][lk + j] = __float2bfloat16(val);
            }
        }
        *(float4*)&Bs[lrow][lk] = *(const float4*)&Bb[(long)lrow * K + kt + lk];
        __syncthreads();
        short8t a0 = *(const short8t*)&As[wr + fm][fk];
        short8t a1 = *(const short8t*)&As[wr + 16 + fm][fk];
        short8t b0 = *(const short8t*)&Bs[wc + fm][fk];
        short8t b1 = *(const short8t*)&Bs[wc + 16 + fm][fk];
        acc00 = __builtin_amdgcn_mfma_f32_16x16x32_bf16(a0, b0, acc00, 0, 0, 0);
        acc01 = __builtin_amdgcn_mfma_f32_16x16x32_bf16(a0, b1, acc01, 0, 0, 0);
        acc10 = __builtin_amdgcn_mfma_f32_16x16x32_bf16(a1, b0, acc10, 0, 0, 0);
        acc11 = __builtin_amdgcn_mfma_f32_16x16x32_bf16(a1, b1, acc11, 0, 0, 0);
        __syncthreads();
    }

    float* Cf = (float*)Cv;
    bf16* Cb = (bf16*)Cv;
    int row_base = tby * 64 + wr + (lane >> 4) * 4;
    int col_base = tbx * 64 + wc + fm;
    #pragma unroll
    for (int fr = 0; fr < 2; ++fr) {
        #pragma unroll
        for (int fc = 0; fc < 2; ++fc) {
            const f32x4& a = fr == 0 ? (fc == 0 ? acc00 : acc01) : (fc == 0 ? acc10 : acc11);
            #pragma unroll
            for (int r = 0; r < 4; ++r) {
                int gi = row_base + fr * 16 + r;
                int gj = col_base + fc * 16;
                float v = a[r];
                long ci = coff + (long)gi * ldc + gj;
                if (FLAGS & FLAG_ATOMIC) {
                    atomicAdd(&Cf[ci], v);
                } else {
                    if (FLAGS & FLAG_BIAS) v += bias[gj];
                    if (FLAGS & FLAG_GELU) v = gelu_f(v);
                    if (FLAGS & FLAG_ROWSCALE) v *= rsqrtf((float)(gi & 127) + 1.0f);
                    if (OUTB16) Cb[ci] = __float2bfloat16(v);
                    else        Cf[ci] = v;
                }
            }
        }
    }
}

// fused dual GEMM: z=0: vf = v1b(bf16,K=512) @ vp2T^T + vp_b2
//                  z=1: hfeat = gelu(hacc*scale+ro_b1)(K=128) @ ro2T^T + ro_b2
__global__ __launch_bounds__(256) void gemm_dual(
    const bf16* __restrict__ v1b, const bf16* __restrict__ vp2T, const float* __restrict__ vp_b2,
    const float* __restrict__ hacc, const bf16* __restrict__ ro2T, const float* __restrict__ ro_b1,
    const float* __restrict__ ro_b2, float* __restrict__ vf, float* __restrict__ hfeat)
{
    __shared__ __align__(16) bf16 As[64][44];
    __shared__ __align__(16) bf16 Bs[64][44];
    int tid = threadIdx.x;
    int lrow = tid >> 2, lk = (tid & 3) * 8;
    int w = tid >> 6, lane = tid & 63;
    int wr = (w >> 1) * 32, wc = (w & 1) * 32;
    int fm = lane & 15, fk = (lane >> 4) * 8;
    f32x4 acc00 = {0.f,0.f,0.f,0.f}, acc01 = acc00, acc10 = acc00, acc11 = acc00;
    int mode = blockIdx.z;
    int K = mode ? 128 : 512;
    const bf16* Bb = (mode ? ro2T : vp2T) + (long)blockIdx.x * 64 * K;

    for (int kt = 0; kt < K; kt += 32) {
        if (mode == 0) {
            const bf16* Ab = v1b + (long)blockIdx.y * 64 * K;
            *(float4*)&As[lrow][lk] = *(const float4*)&Ab[(long)lrow * K + kt + lk];
        } else {
            const float* Af = hacc + (long)blockIdx.y * 64 * K;
            int gk0 = kt + lk;
            float4 v0 = *(const float4*)&Af[(long)lrow * K + gk0];
            float4 v1 = *(const float4*)&Af[(long)lrow * K + gk0 + 4];
            float vv[8] = {v0.x, v0.y, v0.z, v0.w, v1.x, v1.y, v1.z, v1.w};
            int grow = blockIdx.y * 64 + lrow;
            float sc = rsqrtf((float)((grow & 127) + 1)) * (1.0f / 92681.900089f);
            #pragma unroll
            for (int j = 0; j < 8; ++j)
                As[lrow][lk + j] = __float2bfloat16(gelu_f(vv[j] * sc + ro_b1[gk0 + j]));
        }
        *(float4*)&Bs[lrow][lk] = *(const float4*)&Bb[(long)lrow * K + kt + lk];
        __syncthreads();
        short8t a0 = *(const short8t*)&As[wr + fm][fk];
        short8t a1 = *(const short8t*)&As[wr + 16 + fm][fk];
        short8t b0 = *(const short8t*)&Bs[wc + fm][fk];
        short8t b1 = *(const short8t*)&Bs[wc + 16 + fm][fk];
        acc00 = __builtin_amdgcn_mfma_f32_16x16x32_bf16(a0, b0, acc00, 0, 0, 0);
        acc01 = __builtin_amdgcn_mfma_f32_16x16x32_bf16(a0, b1, acc01, 0, 0, 0);
        acc10 = __builtin_amdgcn_mfma_f32_16x16x32_bf16(a1, b0, acc10, 0, 0, 0);
        acc11 = __builtin_amdgcn_mfma_f32_16x16x32_bf16(a1, b1, acc11, 0, 0, 0);
        __syncthreads();
    }

    const float* bias = mode ? ro_b2 : vp_b2;
    float* Cf = mode ? hfeat : vf;
    int row_base = blockIdx.y * 64 + wr + (lane >> 4) * 4;
    int col_base = blockIdx.x * 64 + wc + fm;
    #pragma unroll
    for (int fr = 0; fr < 2; ++fr) {
        #pragma unroll
        for (int fc = 0; fc < 2; ++fc) {
            const f32x4& a = fr == 0 ? (fc == 0 ? acc00 : acc01) : (fc == 0 ? acc10 : acc11);
            #pragma unroll
            for (int r = 0; r < 4; ++r) {
                int gi = row_base + fr * 16 + r;
                int gj = col_base + fc * 16;
                Cf[(long)gi * 512 + gj] = a[r] + bias[gj];
            }
        }
    }
}

// LN over D=512. FINAL=0: LN(x1); FINAL=1: LN(x1 + gf*x2 + gv*x3). OB16 selects out dtype.
template<int FINAL, int OB16>
__global__ __launch_bounds__(256) void ln_kernel(const float* __restrict__ x1,
                                                 const float* __restrict__ x2,
                                                 const float* __restrict__ x3,
                                                 const float* __restrict__ g,
                                                 const float* __restrict__ bb,
                                                 const float* __restrict__ scal,
                                                 void* __restrict__ outv) {
    int row = blockIdx.x, tid = threadIdx.x;
    long base = (long)row * D_;
    int d0 = tid, d1 = tid + 256;
    float v0, v1;
    if (FINAL) {
        float gf = scal[3], gv = scal[4];
        v0 = x1[base + d0] + gf * x2[base + d0] + gv * x3[base + d0];
        v1 = x1[base + d1] + gf * x2[base + d1] + gv * x3[base + d1];
    } else {
        v0 = x1[base + d0];
        v1 = x1[base + d1];
    }
    float s = v0 + v1;
    #pragma unroll
    for (int o = 32; o > 0; o >>= 1) s += __shfl_down(s, o);
    __shared__ float red[8];
    int wid = tid >> 6, lane = tid & 63;
    if (lane == 0) red[wid] = s;
    __syncthreads();
    float mu = (red[0] + red[1] + red[2] + red[3]) * (1.0f / D_);
    float e0 = v0 - mu, e1 = v1 - mu;
    float sq = e0 * e0 + e1 * e1;
    #pragma unroll
    for (int o = 32; o > 0; o >>= 1) sq += __shfl_down(sq, o);
    if (lane == 0) red[4 + wid] = sq;
    __syncthreads();
    float var = (red[4] + red[5] + red[6] + red[7]) * (1.0f / D_);
    float rs = rsqrtf(var + 1e-5f);
    float o0 = e0 * rs * g[d0] + bb[d0];
    float o1 = e1 * rs * g[d1] + bb[d1];
    if (OB16) {
        ((bf16*)outv)[base + d0] = __float2bfloat16(o0);
        ((bf16*)outv)[base + d1] = __float2bfloat16(o1);
    } else {
        ((float*)outv)[base + d0] = o0;
        ((float*)outv)[base + d1] = o1;
    }
}

extern "C" void kernel_launch(void* const* d_in, const int* in_sizes, int n_in,
                              void* d_out, int out_size, void* d_ws, size_t ws_size,
                              hipStream_t stream) {
    const float* e      = (const float*)d_in[0];
    const int*   h      = (const int*)d_in[1];
    const float* sign   = (const float*)d_in[2];
    const float* Wq     = (const float*)d_in[3];
    const float* Wk     = (const float*)d_in[4];
    const float* Wv     = (const float*)d_in[5];
    const float* ro_w1  = (const float*)d_in[6];
    const float* ro_b1  = (const float*)d_in[7];
    const float* ro_w2  = (const float*)d_in[8];
    const float* ro_b2  = (const float*)d_in[9];
    const float* vp_ln_g= (const float*)d_in[10];
    const float* vp_ln_b= (const float*)d_in[11];
    const float* vp_w1  = (const float*)d_in[12];
    const float* vp_b1  = (const float*)d_in[13];
    const float* vp_w2  = (const float*)d_in[14];
    const float* vp_b2  = (const float*)d_in[15];
    const float* ln_g   = (const float*)d_in[16];
    const float* ln_b   = (const float*)d_in[17];
    const float* tq     = (const float*)d_in[18];
    const float* tk     = (const float*)d_in[19];
    const float* om     = (const float*)d_in[20];
    const float* gfr    = (const float*)d_in[21];
    const float* gvr    = (const float*)d_in[22];

    float* ws    = (float*)d_ws;
    float* scal  = ws + OFF_SCAL;
    float* qkv   = ws + OFF_QKV;
    float* vraw  = ws + OFF_VRAW;
    float* vf    = ws + OFF_VF;
    float* hfeat = ws + OFF_HFEAT;
    float* scoacc= ws + OFF_SCOA;
    float* qsum  = ws + OFF_QSUM;
    float* hacc  = ws + OFF_HACC;
    bf16* kp16  = (bf16*)(ws + OFF_KP);
    bf16* eb    = (bf16*)(ws + OFF_EB);
    bf16* wqkvT = (bf16*)(ws + OFF_WQKVT);
    bf16* vp1T  = (bf16*)(ws + OFF_VP1T);
    bf16* vp2T  = (bf16*)(ws + OFF_VP2T);
    bf16* ro2T  = (bf16*)(ws + OFF_RO2T);
    bf16* qcat  = (bf16*)(ws + OFF_QCAT);
    bf16* kcat  = (bf16*)(ws + OFF_KCAT);
    bf16* dkT   = (bf16*)(ws + OFF_DKT);
    bf16* vTb   = (bf16*)(ws + OFF_VTB);
    bf16* vlnb  = (bf16*)(ws + OFF_VLNB);
    bf16* v1b   = (bf16*)(ws + OFF_V1B);
    bf16* pcat  = (bf16*)(ws + OFF_PCAT);
    bf16* ro1f  = (bf16*)(ws + OFF_RO1F);

    float* ys = (float*)d_out;
    float* kf = ys + (long)BT_ * D_;
    float* hf = kf + (long)B_ * 2 * M_;

    // fused preprocessing: scal+zero | e-cast | weight transposes | ro1 FFT
    preproc_kernel<<<3200, 256, 0, stream>>>(
        tq, tk, om, gfr, gvr, scal, scoacc, hacc,
        (const float4*)e, (ushort4t*)eb,
        Wq, Wk, Wv, vp_w1, vp_w2, ro_w2,
        wqkvT, wqkvT + 262144, wqkvT + 524288, vp1T, vp2T, ro2T,
        ro_w1, ro1f);

    // qkv = e @ [Wq|Wk|Wv]  (1024 x 1536 x 512) -> f32
    gemm_mfma<0, 0, 0><<<dim3(24, 16, 1), 256, 0, stream>>>(
        eb, wqkvT, nullptr, nullptr, qkv, 512, 1536, 0, 0, 0, 1);

    // fused sketch + vTb transpose (both depend only on qkv)
    sketchvtb_kernel<<<1536, 256, 0, stream>>>(qkv, sign, scal, h, qcat, kcat, vTb);

    // prefix over t reading bf16 kcat directly (SK2 deleted)
    prefix_p1<<<512, 256, 0, stream>>>(kcat, qsum);
    prefix_p2<<<512, 256, 0, stream>>>(kcat, qsum, kp16, dkT, kf);

    // forward FFTs + spectral product (no inverse; scrambled order matches ro1f)
    fwdfft_kernel<<<1024, 256, 0, stream>>>(qcat, kp16, pcat);

    // scores: split-K 16, triangle-skip (3 of 4 tiles), f32 atomic accumulate
    gemm_mfma<FLAG_ATOMIC | FLAG_TRI, 0, 0><<<dim3(3, 1, 128), 256, 0, stream>>>(
        qcat, kcat, nullptr, nullptr, scoacc, 4096, 128, 524288, 524288, 16384, 16);

    // vraw[b] = masked(scores) @ v * rsqrt(t+1)  (mask fused in A-load)
    gemm_mfma<FLAG_ROWSCALE, 0, 1><<<dim3(8, 2, 8), 256, 0, stream>>>(
        scoacc, vTb, nullptr, nullptr, vraw, 128, 512, 16384, 65536, 65536, 1);

    ln_kernel<0, 1><<<1024, 256, 0, stream>>>(vraw, nullptr, nullptr, vp_ln_g, vp_ln_b, scal, vlnb);

    // v1b = gelu(vlnb @ vp1T + b1)
    gemm_mfma<FLAG_BIAS | FLAG_GELU, 1, 0><<<dim3(8, 16, 1), 256, 0, stream>>>(
        vlnb, vp1T, vp_b1, nullptr, v1b, 512, 512, 0, 0, 0, 1);

    // hid_pre = pcat @ ro1f^T (1024x128x4096), split-K 8 atomic into hacc
    gemm_mfma<FLAG_ATOMIC, 0, 0><<<dim3(2, 16, 8), 256, 0, stream>>>(
        pcat, ro1f, nullptr, nullptr, hacc, 4096, 128, 0, 0, 0, 8);

    // fused: vf = v1b@vp2T + b2  ||  hfeat = gelu(hacc*scale+ro_b1)@ro2T + ro_b2
    gemm_dual<<<dim3(8, 16, 2), 256, 0, stream>>>(
        v1b, vp2T, vp_b2, hacc, ro2T, ro_b1, ro_b2, vf, hfeat);

    // ys = LN(e + gf*hfeat + gv*vf)
    ln_kernel<1, 0><<<1024, 256, 0, stream>>>(e, hfeat, vf, ln_g, ln_b, scal, ys);

    // Hf fused: z in [0,16), b=z&7, c=z>>3
    gemm_mfma<FLAG_HFB, 0, 0><<<dim3(32, 8, 16), 256, 0, stream>>>(
        vTb, dkT, nullptr, nullptr, hf, 128, 2048, 65536, 0, 0, 1);
}

// Round 16
// 131.877 us; speedup vs baseline: 2.3345x; 1.0725x over previous
//
#include <hip/hip_runtime.h>
#include <hip/hip_bf16.h>
#include <math.h>

#define B_   8
#define T_   128
#define D_   512
#define M_   2048
#define HID_ 128
#define BT_  1024

typedef __attribute__((ext_vector_type(8))) short short8t;
typedef __attribute__((ext_vector_type(8))) unsigned short ushort8t;
typedef __attribute__((ext_vector_type(4))) unsigned short ushort4t;
typedef __attribute__((ext_vector_type(4))) float f32x4;
typedef __hip_bfloat16 bf16;

// ws layout (float offsets; all multiples of 16 -> 64B aligned)
#define OFF_SCAL   0L
#define OFF_QKV    16L                            // 1024*1536 f32
#define OFF_KP     (OFF_QKV + 1572864L)           // [KR|KI] bf16 exclusive prefix (2*BT*M bf16)
#define OFF_VRAW   (OFF_KP + 2097152L)
#define OFF_VF     (OFF_VRAW + 524288L)
#define OFF_HFEAT  (OFF_VF + 524288L)
// bf16 buffers (size in floats = elems/2)
#define OFF_EB     (OFF_HFEAT + 524288L)          // 1024x512
#define OFF_WQKVT  (OFF_EB + 262144L)             // 1536x512
#define OFF_VP1T   (OFF_WQKVT + 393216L)          // 512x512
#define OFF_VP2T   (OFF_VP1T + 131072L)
#define OFF_RO2T   (OFF_VP2T + 131072L)           // 512x128
#define OFF_QCAT   (OFF_RO2T + 32768L)            // 1024x4096
#define OFF_KCAT   (OFF_QCAT + 2097152L)          // 1024x4096
#define OFF_DKT    (OFF_KCAT + 2097152L)          // 2x8x2048x128
#define OFF_VTB    (OFF_DKT + 2097152L)           // 8x512x128
#define OFF_VLNB   (OFF_VTB + 262144L)            // 1024x512
#define OFF_V1B    (OFF_VLNB + 262144L)           // 1024x512
#define OFF_SCOA   (OFF_V1B + 262144L)            // 8x128x128 f32 split-K accumulator
#define OFF_QSUM   (OFF_SCOA + 131072L)           // 4x32768 f32 prefix quarter sums
#define OFF_PCAT   (OFF_QSUM + 131072L)           // 1024x4096 bf16 [ReP|ImP]
#define OFF_RO1F   (OFF_PCAT + 2097152L)          // 128x4096 bf16 [ReG|ImG]
#define OFF_HACC   (OFF_RO1F + 262144L)           // 1024x128 f32

#define FLAG_BIAS     1
#define FLAG_GELU     2
#define FLAG_ROWSCALE 4
#define FLAG_ATOMIC   8
#define FLAG_HFB      32
#define FLAG_TRI      64

__device__ __forceinline__ float gelu_f(float x) {
    return 0.5f * x * (1.0f + erff(x * 0.70710678118654752440f));
}

__device__ __forceinline__ float b2f(unsigned short u) {
    return __uint_as_float(((unsigned int)u) << 16);
}

#define PIDX(i) ((i) + ((i) >> 5))

template<int M>
__device__ __forceinline__ void dif_one(float* re, float* im, int tid) {
    #pragma unroll
    for (int u = 0; u < 4; ++u) {
        int q = u * 256 + tid;
        int k = q & (M - 1);
        int i = (q / M) * (2 * M) + k;
        float s, c;
        __sincosf((float)k * (3.14159265358979323846f / (float)M), &s, &c);
        int p0 = PIDX(i), p1 = PIDX(i + M);
        float ar = re[p0], ai = im[p0], br = re[p1], bi = im[p1];
        re[p0] = ar + br; im[p0] = ai + bi;
        float dr = ar - br, di = ai - bi;
        re[p1] = dr * c + di * s;
        im[p1] = di * c - dr * s;
    }
}

// ==== fused preprocessing: scal+zero | e-cast | 6x weight transpose | ro1 FFT ====
__global__ __launch_bounds__(256) void preproc_kernel(
    const float* tq, const float* tk, const float* om, const float* gf, const float* gv,
    float* scal, float* scoacc, float* hacc,
    const float4* __restrict__ e4, ushort4t* __restrict__ eb4,
    const float* w0, const float* w1, const float* w2, const float* w3,
    const float* w4, const float* w5,
    bf16* d0, bf16* d1, bf16* d2, bf16* d3, bf16* d4, bf16* d5,
    const float* __restrict__ ro_w1, bf16* __restrict__ ro1f)
{
    __shared__ float smem[4224];   // 16.9 KB union
    int blk = blockIdx.x, tid = threadIdx.x;

    if (blk < 1024) {
        int idx = blk * 256 + tid;
        if (idx < 131072) scoacc[idx] = 0.f;
        else hacc[idx - 131072] = 0.f;
        if (idx == 0) {
            scal[0] = 0.5f * tanhf(tq[0]);
            scal[1] = 0.5f * tanhf(tk[0]);
            scal[2] = 0.5f * tanhf(om[0]);
            scal[3] = 0.25f / (1.0f + expf(-gf[0]));
            scal[4] = 0.25f / (1.0f + expf(-gv[0]));
        }
        return;
    }
    if (blk < 1536) {
        int i = (blk - 1024) * 256 + tid;   // < 131072
        float4 v = e4[i];
        ushort4t o;
        bf16 h0 = __float2bfloat16(v.x), h1 = __float2bfloat16(v.y);
        bf16 h2 = __float2bfloat16(v.z), h3 = __float2bfloat16(v.w);
        o[0] = *(unsigned short*)&h0; o[1] = *(unsigned short*)&h1;
        o[2] = *(unsigned short*)&h2; o[3] = *(unsigned short*)&h3;
        eb4[i] = o;
        return;
    }
    if (blk < 3072) {
        int zz = blk - 1536;
        int wz = zz >> 8;
        int rem = zz & 255;
        int by = rem >> 4, bx = rem & 15;
        const float* src; bf16* dst; int R = 512;
        if (wz == 0)      { src = w0; dst = d0; }
        else if (wz == 1) { src = w1; dst = d1; }
        else if (wz == 2) { src = w2; dst = d2; }
        else if (wz == 3) { src = w3; dst = d3; }
        else if (wz == 4) { src = w4; dst = d4; }
        else              { src = w5; dst = d5; R = 128; }
        int c0 = bx * 32, r0 = by * 32;
        if (r0 >= R) return;
        float (*tile)[33] = (float(*)[33])smem;
        int tx = tid & 31, ty = tid >> 5;
        for (int rr = ty; rr < 32; rr += 8) {
            int r = r0 + rr;
            tile[rr][tx] = (r < R) ? src[(long)r * 512 + c0 + tx] : 0.f;
        }
        __syncthreads();
        int r = r0 + tx;
        if (r < R)
            for (int cc = ty; cc < 32; cc += 8)
                dst[(long)(c0 + cc) * R + r] = __float2bfloat16(tile[tx][cc]);
        return;
    }
    {   // ro1fft
        int j = blk - 3072;
        float* Rs = smem;
        float* Is = smem + 2112;
        for (int u = 0; u < 8; ++u) {
            int n = u * 256 + tid;
            Rs[PIDX(n)] = ro_w1[(long)n * HID_ + j];
            Is[PIDX(n)] = 0.f;
        }
        __syncthreads();
#define FSTEP(MM) dif_one<MM>(Rs, Is, tid); __syncthreads();
        FSTEP(1024) FSTEP(512) FSTEP(256) FSTEP(128) FSTEP(64)
        FSTEP(32) FSTEP(16) FSTEP(8) FSTEP(4) FSTEP(2) FSTEP(1)
#undef FSTEP
        unsigned short* op = (unsigned short*)(ro1f + (long)j * 4096);
        for (int u = 0; u < 8; ++u) {
            int r = u * 256 + tid;
            int pr = PIDX(r);
            bf16 re = __float2bfloat16(Rs[pr]);
            bf16 im = __float2bfloat16(Is[pr]);
            op[r]        = *(unsigned short*)&re;
            op[2048 + r] = *(unsigned short*)&im;
        }
    }
}

// ==== fused sketch + vTb transpose ====
__global__ __launch_bounds__(256) void sketchvtb_kernel(const float* __restrict__ qkv,
                                                        const float* __restrict__ sign,
                                                        const float* __restrict__ scal,
                                                        const int* __restrict__ h,
                                                        bf16* __restrict__ qcat,
                                                        bf16* __restrict__ kcat,
                                                        bf16* __restrict__ vTb) {
    __shared__ float smem[4 * M_];
    int blk = blockIdx.x, tid = threadIdx.x;
    if (blk < 1024) {
        int bt = blk;
        float* s0 = smem;
        float* s1 = smem + M_;
        float* s2 = smem + 2 * M_;
        float* s3 = smem + 3 * M_;
        for (int j = tid; j < M_; j += 256) { s0[j] = 0.f; s1[j] = 0.f; s2[j] = 0.f; s3[j] = 0.f; }
        __syncthreads();
        int t = bt & 127;
        float thq = scal[0], thk = scal[1], omg = scal[2];
        float ft = (float)t;
        for (int i = tid; i < D_; i += 256) {
            float q = qkv[(long)bt * 1536 + i];
            float k = qkv[(long)bt * 1536 + 512 + i];
            float sg = sign[i];
            float sq_, cq_, sk_, ck_;
            __sincosf(thq * q - omg * ft, &sq_, &cq_);
            __sincosf(thk * k + omg * ft, &sk_, &ck_);
            int m = h[i];
            atomicAdd(&s0[m], q * cq_ * sg);
            atomicAdd(&s1[m], q * sq_ * sg);
            atomicAdd(&s2[m], k * ck_ * sg);
            atomicAdd(&s3[m], k * sk_ * sg);
        }
        __syncthreads();
        long qb = (long)bt * 4096;
        for (int j = tid; j < M_; j += 256) {
            qcat[qb + j]        = __float2bfloat16(s0[j]);
            qcat[qb + 2048 + j] = __float2bfloat16(s1[j]);
            kcat[qb + j]        = __float2bfloat16(s2[j]);
            kcat[qb + 2048 + j] = __float2bfloat16(-s3[j]);
        }
        return;
    }
    {   // vTb transpose
        int zz = blk - 1024;
        int b = zz >> 6;
        int rem = zz & 63;
        int by = rem >> 4, bx = rem & 15;
        int c0 = bx * 32, r0 = by * 32;
        float (*tile)[33] = (float(*)[33])smem;
        int tx = tid & 31, ty = tid >> 5;
        const float* in = qkv + 1024 + (long)b * 196608L;
        for (int rr = ty; rr < 32; rr += 8)
            tile[rr][tx] = in[(long)(r0 + rr) * 1536 + c0 + tx];
        __syncthreads();
        bf16* out = vTb + (long)b * 65536L;
        for (int cc = ty; cc < 32; cc += 8)
            out[(long)(c0 + cc) * 128 + r0 + tx] = __float2bfloat16(tile[tx][cc]);
    }
}

// ---- two-phase exclusive prefix over t, reading bf16 kcat ----
__global__ __launch_bounds__(256) void prefix_p1(const bf16* __restrict__ kcat,
                                                 float* __restrict__ qsum) {
    int idx = blockIdx.x * 256 + threadIdx.x;   // 131072
    int col = idx & 32767, q = idx >> 15;
    int m = col & 2047, b = (col >> 11) & 7, comp = col >> 14;
    const unsigned short* src = (const unsigned short*)kcat
        + ((long)(b * 128 + q * 32) * 4096L + (long)comp * 2048L + m);
    float s = 0.f;
    #pragma unroll 8
    for (int i = 0; i < 32; ++i) s += b2f(src[(long)i * 4096L]);
    if (comp) s = -s;
    qsum[(long)q * 32768 + col] = s;
}

__global__ __launch_bounds__(256) void prefix_p2(const bf16* __restrict__ kcat,
                                                 const float* __restrict__ qsum,
                                                 bf16* __restrict__ KP16,
                                                 bf16* __restrict__ dkT,
                                                 float* __restrict__ kf_out) {
    int idx = blockIdx.x * 256 + threadIdx.x;   // 131072
    int col = idx & 32767, q = idx >> 15;
    int m = col & 2047, b = (col >> 11) & 7, comp = col >> 14;
    const unsigned short* src = (const unsigned short*)kcat
        + ((long)(b * 128 + q * 32) * 4096L + (long)comp * 2048L + m);
    bf16* dst = KP16 + (long)comp * BT_ * M_ + (long)b * T_ * M_ + m + (long)(q * 32) * M_;
    bf16* dkt = dkT + (long)comp * 2097152L + (long)b * 262144L + (long)m * 128L + (long)(q * 32);
    float acc = 0.f;
    for (int p = 0; p < q; ++p) acc += qsum[(long)p * 32768 + col];
    float sgn = comp ? -1.f : 1.f;
    #pragma unroll 4
    for (int i = 0; i < 32; ++i) {
        float v = sgn * b2f(src[(long)i * 4096L]);
        dst[(long)i * M_] = __float2bfloat16(acc);
        dkt[i] = __float2bfloat16(v);
        acc += v;
    }
    if (q == 3) kf_out[((long)b * 2 + comp) * M_ + m] = acc;
}

// fused 3-stage radix-8 DIF pass on both (K,Q) arrays.
template<int S>
__device__ __forceinline__ void dif8_pair(float* r0, float* i0a, float* r1, float* i1a, int tid) {
    int k = tid % S;
    int grp = tid / S;
    int base = grp * 8 * S + k;
    float sw, cw;
    __sincosf((float)k * (3.14159265358979323846f / (4.0f * (float)S)), &sw, &cw);
    float wr = cw, wi = -sw;
    float w2r = wr * wr - wi * wi, w2i = 2.f * wr * wi;
    float w4r = w2r * w2r - w2i * w2i, w4i = 2.f * w2r * w2i;
    const float RH = 0.70710678118654752440f;
    float t1r[4] = {wr, (wr + wi) * RH, wi, (wi - wr) * RH};
    float t1i[4] = {wi, (wi - wr) * RH, -wr, -(wr + wi) * RH};
    float u0r = w2r, u0i = w2i;
    float u1r = w2i, u1i = -w2r;
    #pragma unroll
    for (int a = 0; a < 2; ++a) {
        float* re = a ? r1 : r0;
        float* im = a ? i1a : i0a;
        float xr[8], xi[8];
        #pragma unroll
        for (int r = 0; r < 8; ++r) { int p = PIDX(base + r * S); xr[r] = re[p]; xi[r] = im[p]; }
        #pragma unroll
        for (int r = 0; r < 4; ++r) {
            float ar = xr[r], ai = xi[r], br = xr[r + 4], bi = xi[r + 4];
            xr[r] = ar + br; xi[r] = ai + bi;
            float dr = ar - br, di = ai - bi;
            xr[r + 4] = dr * t1r[r] - di * t1i[r];
            xi[r + 4] = dr * t1i[r] + di * t1r[r];
        }
        #pragma unroll
        for (int hb = 0; hb < 8; hb += 4) {
            #pragma unroll
            for (int r = 0; r < 2; ++r) {
                float tr = (r == 0) ? u0r : u1r, ti = (r == 0) ? u0i : u1i;
                float ar = xr[hb + r], ai = xi[hb + r], br = xr[hb + r + 2], bi = xi[hb + r + 2];
                xr[hb + r] = ar + br; xi[hb + r] = ai + bi;
                float dr = ar - br, di = ai - bi;
                xr[hb + r + 2] = dr * tr - di * ti;
                xi[hb + r + 2] = dr * ti + di * tr;
            }
        }
        #pragma unroll
        for (int r = 0; r < 8; r += 2) {
            float ar = xr[r], ai = xi[r], br = xr[r + 1], bi = xi[r + 1];
            xr[r] = ar + br; xi[r] = ai + bi;
            float dr = ar - br, di = ai - bi;
            xr[r + 1] = dr * w4r - di * w4i;
            xi[r + 1] = dr * w4i + di * w4r;
        }
        #pragma unroll
        for (int r = 0; r < 8; ++r) { int p = PIDX(base + r * S); re[p] = xr[r]; im[p] = xi[r]; }
    }
}

// GEMM inner body macro shared by fused launch kernels (bf16 TN, 64x64 tile)
#define GEMM_CORE(ABASE, BBASE, KK)                                            \
    for (int kt = k0; kt < k0 + klen; kt += 32) {                              \
        *(float4*)&As[lrow][lk] = *(const float4*)&(ABASE)[(long)lrow * (KK) + kt + lk]; \
        *(float4*)&Bs[lrow][lk] = *(const float4*)&(BBASE)[(long)lrow * (KK) + kt + lk]; \
        __syncthreads();                                                       \
        short8t a0 = *(const short8t*)&As[wr + fm][fk];                        \
        short8t a1 = *(const short8t*)&As[wr + 16 + fm][fk];                   \
        short8t b0 = *(const short8t*)&Bs[wc + fm][fk];                        \
        short8t b1 = *(const short8t*)&Bs[wc + 16 + fm][fk];                   \
        acc00 = __builtin_amdgcn_mfma_f32_16x16x32_bf16(a0, b0, acc00, 0, 0, 0); \
        acc01 = __builtin_amdgcn_mfma_f32_16x16x32_bf16(a0, b1, acc01, 0, 0, 0); \
        acc10 = __builtin_amdgcn_mfma_f32_16x16x32_bf16(a1, b0, acc10, 0, 0, 0); \
        acc11 = __builtin_amdgcn_mfma_f32_16x16x32_bf16(a1, b1, acc11, 0, 0, 0); \
        __syncthreads();                                                       \
    }

// ==== fused: fwdfft (blocks [0,1024)) | scores GEMM (blocks [1024,1408)) ====
__global__ __launch_bounds__(256) void fftsco_kernel(const bf16* __restrict__ qcat,
                                                     const bf16* __restrict__ KP16,
                                                     bf16* __restrict__ pcat,
                                                     const bf16* __restrict__ kcat,
                                                     float* __restrict__ scoacc) {
    __shared__ float smem[8448];   // 33 KB union (FFT: 4x2112 f32; GEMM: 2x1408 f32)
    int blk = blockIdx.x, tid = threadIdx.x;

    if (blk >= 1024) {   // ---- scores GEMM tile: flattened (3,1,128) TRI split-K ----
        int s = blk - 1024;            // [0,384)
        int xx = s % 3, bz = s / 3;    // bz in [0,128)
        int tby = (xx > 0) ? 1 : 0, tbx = (xx == 2) ? 1 : 0;
        int batch = bz >> 4, kslice = bz & 15;
        const int K = 4096;
        int klen = 256, k0 = kslice * 256;
        bf16 (*As)[44] = (bf16(*)[44])smem;
        bf16 (*Bs)[44] = (bf16(*)[44])(smem + 1408);
        const bf16* Ab = qcat + (long)batch * 524288L + (long)tby * 64 * K;
        const bf16* Bb = kcat + (long)batch * 524288L + (long)tbx * 64 * K;
        int lrow = tid >> 2, lk = (tid & 3) * 8;
        int w = tid >> 6, lane = tid & 63;
        int wr = (w >> 1) * 32, wc = (w & 1) * 32;
        int fm = lane & 15, fk = (lane >> 4) * 8;
        f32x4 acc00 = {0.f,0.f,0.f,0.f}, acc01 = acc00, acc10 = acc00, acc11 = acc00;
        GEMM_CORE(Ab, Bb, K)
        float* Cf = scoacc + (long)batch * 16384L;
        int row_base = tby * 64 + wr + (lane >> 4) * 4;
        int col_base = tbx * 64 + wc + fm;
        #pragma unroll
        for (int fr = 0; fr < 2; ++fr)
            #pragma unroll
            for (int fc = 0; fc < 2; ++fc) {
                const f32x4& a = fr == 0 ? (fc == 0 ? acc00 : acc01) : (fc == 0 ? acc10 : acc11);
                #pragma unroll
                for (int r = 0; r < 4; ++r)
                    atomicAdd(&Cf[(long)(row_base + fr * 16 + r) * 128 + col_base + fc * 16], a[r]);
            }
        return;
    }

    // ---- fwdfft per (b,t) ----
    float* KRs = smem;
    float* KIs = smem + 2112;
    float* QRs = smem + 4224;
    float* QIs = smem + 6336;
    int bt = blk;
    const unsigned short* qp = (const unsigned short*)(qcat + (long)bt * 4096);
    const unsigned short* kpr = (const unsigned short*)(KP16 + (long)bt * M_);
    const unsigned short* kpi = (const unsigned short*)(KP16 + (long)BT_ * M_ + (long)bt * M_);
    for (int u = 0; u < 8; ++u) {
        int j = u * 256 + tid;
        int pj = PIDX(j);
        KRs[pj] = b2f(kpr[j]);
        KIs[pj] = b2f(kpi[j]);
        QRs[pj] = b2f(qp[j]);
        QIs[pj] = b2f(qp[2048 + j]);
    }
    __syncthreads();
    dif8_pair<256>(KRs, KIs, QRs, QIs, tid);  __syncthreads();
    dif8_pair<32>(KRs, KIs, QRs, QIs, tid);   __syncthreads();

    float kr_[8], ki_[8], qr_[8], qi_[8];
    #pragma unroll
    for (int l = 0; l < 8; ++l) {
        int pj = PIDX(8 * tid + l);
        kr_[l] = KRs[pj]; ki_[l] = KIs[pj];
        qr_[l] = QRs[pj]; qi_[l] = QIs[pj];
    }

    const float C16[16] = {1.f, 0.98078528f, 0.92387953f, 0.83146961f,
                           0.70710678f, 0.55557023f, 0.38268343f, 0.19509032f,
                           0.f, -0.19509032f, -0.38268343f, -0.55557023f,
                           -0.70710678f, -0.83146961f, -0.92387953f, -0.98078528f};
    const float S16[16] = {0.f, 0.19509032f, 0.38268343f, 0.55557023f,
                           0.70710678f, 0.83146961f, 0.92387953f, 0.98078528f,
                           1.f, 0.98078528f, 0.92387953f, 0.83146961f,
                           0.70710678f, 0.55557023f, 0.38268343f, 0.19509032f};
    bool odd = (tid & 1) != 0;
    {
        bool hi2 = (tid & 2) != 0;
        #pragma unroll
        for (int l = 0; l < 8; ++l) {
            float c = odd ? C16[l + 8] : C16[l];
            float s = odd ? S16[l + 8] : S16[l];
            float pr, pi2, sr, si, dr, di;
            pr = __shfl_xor(kr_[l], 2); pi2 = __shfl_xor(ki_[l], 2);
            sr = kr_[l] + pr; si = ki_[l] + pi2;
            dr = pr - kr_[l]; di = pi2 - ki_[l];
            kr_[l] = hi2 ? (dr * c + di * s) : sr;
            ki_[l] = hi2 ? (di * c - dr * s) : si;
            pr = __shfl_xor(qr_[l], 2); pi2 = __shfl_xor(qi_[l], 2);
            sr = qr_[l] + pr; si = qi_[l] + pi2;
            dr = pr - qr_[l]; di = pi2 - qi_[l];
            qr_[l] = hi2 ? (dr * c + di * s) : sr;
            qi_[l] = hi2 ? (di * c - dr * s) : si;
        }
    }
    {
        #pragma unroll
        for (int l = 0; l < 8; ++l) {
            float c = C16[2 * l];
            float s = S16[2 * l];
            float pr, pi2, sr, si, dr, di;
            pr = __shfl_xor(kr_[l], 1); pi2 = __shfl_xor(ki_[l], 1);
            sr = kr_[l] + pr; si = ki_[l] + pi2;
            dr = pr - kr_[l]; di = pi2 - ki_[l];
            kr_[l] = odd ? (dr * c + di * s) : sr;
            ki_[l] = odd ? (di * c - dr * s) : si;
            pr = __shfl_xor(qr_[l], 1); pi2 = __shfl_xor(qi_[l], 1);
            sr = qr_[l] + pr; si = qi_[l] + pi2;
            dr = pr - qr_[l]; di = pi2 - qi_[l];
            qr_[l] = odd ? (dr * c + di * s) : sr;
            qi_[l] = odd ? (di * c - dr * s) : si;
        }
    }
    {
        const float C4[4] = {1.f, 0.70710678f, 0.f, -0.70710678f};
        const float S4[4] = {0.f, 0.70710678f, 1.f, 0.70710678f};
        #pragma unroll
        for (int l = 0; l < 4; ++l) {
            float ar, ai, br, bi, dr, di;
            ar = kr_[l]; ai = ki_[l]; br = kr_[l + 4]; bi = ki_[l + 4];
            kr_[l] = ar + br; ki_[l] = ai + bi;
            dr = ar - br; di = ai - bi;
            kr_[l + 4] = dr * C4[l] + di * S4[l];
            ki_[l + 4] = di * C4[l] - dr * S4[l];
            ar = qr_[l]; ai = qi_[l]; br = qr_[l + 4]; bi = qi_[l + 4];
            qr_[l] = ar + br; qi_[l] = ai + bi;
            dr = ar - br; di = ai - bi;
            qr_[l + 4] = dr * C4[l] + di * S4[l];
            qi_[l + 4] = di * C4[l] - dr * S4[l];
        }
    }
    #pragma unroll
    for (int b2 = 0; b2 < 8; b2 += 4) {
        {
            float ar = kr_[b2], ai = ki_[b2], br = kr_[b2 + 2], bi = ki_[b2 + 2];
            kr_[b2] = ar + br; ki_[b2] = ai + bi;
            kr_[b2 + 2] = ar - br; ki_[b2 + 2] = ai - bi;
            ar = qr_[b2]; ai = qi_[b2]; br = qr_[b2 + 2]; bi = qi_[b2 + 2];
            qr_[b2] = ar + br; qi_[b2] = ai + bi;
            qr_[b2 + 2] = ar - br; qi_[b2 + 2] = ai - bi;
        }
        {
            float ar = kr_[b2 + 1], ai = ki_[b2 + 1], br = kr_[b2 + 3], bi = ki_[b2 + 3];
            kr_[b2 + 1] = ar + br; ki_[b2 + 1] = ai + bi;
            float dr = ar - br, di = ai - bi;
            kr_[b2 + 3] = di; ki_[b2 + 3] = -dr;
            ar = qr_[b2 + 1]; ai = qi_[b2 + 1]; br = qr_[b2 + 3]; bi = qi_[b2 + 3];
            qr_[b2 + 1] = ar + br; qi_[b2 + 1] = ai + bi;
            dr = ar - br; di = ai - bi;
            qr_[b2 + 3] = di; qi_[b2 + 3] = -dr;
        }
    }
    #pragma unroll
    for (int i0 = 0; i0 < 8; i0 += 2) {
        float ar = kr_[i0], ai = ki_[i0], br = kr_[i0 + 1], bi = ki_[i0 + 1];
        kr_[i0] = ar + br; ki_[i0] = ai + bi;
        kr_[i0 + 1] = ar - br; ki_[i0 + 1] = ai - bi;
        ar = qr_[i0]; ai = qi_[i0]; br = qr_[i0 + 1]; bi = qi_[i0 + 1];
        qr_[i0] = ar + br; qi_[i0] = ai + bi;
        qr_[i0 + 1] = ar - br; qi_[i0 + 1] = ai - bi;
    }

    unsigned short* op = (unsigned short*)(pcat + (long)bt * 4096 + 8 * tid);
    ushort8t ore, oim;
    #pragma unroll
    for (int l = 0; l < 8; ++l) {
        float pr = qr_[l] * kr_[l] - qi_[l] * ki_[l];
        float pi2 = qr_[l] * ki_[l] + qi_[l] * kr_[l];
        bf16 hr = __float2bfloat16(pr);
        bf16 hi = __float2bfloat16(pi2);
        ore[l] = *(unsigned short*)&hr;
        oim[l] = *(unsigned short*)&hi;
    }
    *(ushort8t*)op = ore;
    *(ushort8t*)(op + 2048) = oim;
}

// ==== fused: v1b GEMM (blocks [0,128)) | hid split-K GEMM (blocks [128,384)) ====
__global__ __launch_bounds__(256) void v1hid_kernel(const bf16* __restrict__ vlnb,
                                                    const bf16* __restrict__ vp1T,
                                                    const float* __restrict__ vp_b1,
                                                    bf16* __restrict__ v1b,
                                                    const bf16* __restrict__ pcat,
                                                    const bf16* __restrict__ ro1f,
                                                    float* __restrict__ hacc) {
    __shared__ __align__(16) bf16 As[64][44];
    __shared__ __align__(16) bf16 Bs[64][44];
    int blk = blockIdx.x, tid = threadIdx.x;
    int lrow = tid >> 2, lk = (tid & 3) * 8;
    int w = tid >> 6, lane = tid & 63;
    int wr = (w >> 1) * 32, wc = (w & 1) * 32;
    int fm = lane & 15, fk = (lane >> 4) * 8;
    f32x4 acc00 = {0.f,0.f,0.f,0.f}, acc01 = acc00, acc10 = acc00, acc11 = acc00;

    if (blk < 128) {   // v1b = gelu(vlnb @ vp1T^T + vp_b1), K=512
        int tbx = blk & 7, tby = blk >> 3;
        const int K = 512;
        int klen = K, k0 = 0;
        const bf16* Ab = vlnb + (long)tby * 64 * K;
        const bf16* Bb = vp1T + (long)tbx * 64 * K;
        GEMM_CORE(Ab, Bb, K)
        int row_base = tby * 64 + wr + (lane >> 4) * 4;
        int col_base = tbx * 64 + wc + fm;
        #pragma unroll
        for (int fr = 0; fr < 2; ++fr)
            #pragma unroll
            for (int fc = 0; fc < 2; ++fc) {
                const f32x4& a = fr == 0 ? (fc == 0 ? acc00 : acc01) : (fc == 0 ? acc10 : acc11);
                #pragma unroll
                for (int r = 0; r < 4; ++r) {
                    int gi = row_base + fr * 16 + r, gj = col_base + fc * 16;
                    v1b[(long)gi * 512 + gj] = __float2bfloat16(gelu_f(a[r] + vp_b1[gj]));
                }
            }
        return;
    }
    {   // hid_pre split-K: pcat(1024x4096) @ ro1f^T(128x4096), atomic into hacc
        int s2 = blk - 128;            // [0,256): (2,16,8) flatten
        int tbx = s2 & 1, tby = (s2 >> 1) & 15, kslice = s2 >> 5;
        const int K = 4096;
        int klen = 512, k0 = kslice * 512;
        const bf16* Ab = pcat + (long)tby * 64 * K;
        const bf16* Bb = ro1f + (long)tbx * 64 * K;
        GEMM_CORE(Ab, Bb, K)
        int row_base = tby * 64 + wr + (lane >> 4) * 4;
        int col_base = tbx * 64 + wc + fm;
        #pragma unroll
        for (int fr = 0; fr < 2; ++fr)
            #pragma unroll
            for (int fc = 0; fc < 2; ++fc) {
                const f32x4& a = fr == 0 ? (fc == 0 ? acc00 : acc01) : (fc == 0 ? acc10 : acc11);
                #pragma unroll
                for (int r = 0; r < 4; ++r)
                    atomicAdd(&hacc[(long)(row_base + fr * 16 + r) * 128 + col_base + fc * 16], a[r]);
            }
    }
}

// MFMA bf16 TN GEMM (generic; used for qkv, vraw, hf)
template<int FLAGS, int OUTB16, int AMODE>
__global__ __launch_bounds__(256) void gemm_mfma(
    const void* __restrict__ Av, const bf16* __restrict__ Bt,
    const float* __restrict__ bias, const float* __restrict__ abias,
    void* __restrict__ Cv,
    int K, int ldc, long abz, long bbz, long cbz, int splitk)
{
    __shared__ __align__(16) bf16 As[64][44];
    __shared__ __align__(16) bf16 Bs[64][44];
    int bz = blockIdx.z;
    int batch = bz, kslice = 0;
    if (FLAGS & FLAG_ATOMIC) { batch = bz / splitk; kslice = bz % splitk; }
    int tbx = blockIdx.x, tby = blockIdx.y;
    long aoff;
    const bf16* Bb;
    long coff;
    if (FLAGS & FLAG_HFB) {
        int b = bz & 7, c = bz >> 3;
        aoff = (long)b * abz + (long)tby * 64 * K;
        Bb = Bt + (long)c * 2097152L + (long)b * 262144L + (long)tbx * 64 * K;
        coff = (long)b * 2097152L + (long)c * 1048576L;
    } else {
        aoff = (long)batch * abz + (long)tby * 64 * K;
        Bb = Bt + (long)batch * bbz + (long)tbx * 64 * K;
        coff = (long)batch * cbz;
    }
    int tid = threadIdx.x;
    int lrow = tid >> 2;
    int lk = (tid & 3) * 8;
    int w = tid >> 6, lane = tid & 63;
    int wr = (w >> 1) * 32, wc = (w & 1) * 32;
    int fm = lane & 15, fk = (lane >> 4) * 8;
    f32x4 acc00 = {0.f,0.f,0.f,0.f}, acc01 = acc00, acc10 = acc00, acc11 = acc00;

    int klen = K / splitk;
    int k0 = kslice * klen;
    for (int kt = k0; kt < k0 + klen; kt += 32) {
        if (AMODE == 0) {
            const bf16* Ab = (const bf16*)Av + aoff;
            *(float4*)&As[lrow][lk] = *(const float4*)&Ab[(long)lrow * K + kt + lk];
        } else {
            const float* Af = (const float*)Av + aoff;
            int gk0 = kt + lk;
            float4 v0 = *(const float4*)&Af[(long)lrow * K + gk0];
            float4 v1 = *(const float4*)&Af[(long)lrow * K + gk0 + 4];
            float vv[8] = {v0.x, v0.y, v0.z, v0.w, v1.x, v1.y, v1.z, v1.w};
            int grow = tby * 64 + lrow;
            #pragma unroll
            for (int j = 0; j < 8; ++j) {
                float val = vv[j];
                int gk = gk0 + j;
                if (AMODE == 1) val = (gk < grow) ? val : 0.f;
                As[lrow][lk + j] = __float2bfloat16(val);
            }
        }
        *(float4*)&Bs[lrow][lk] = *(const float4*)&Bb[(long)lrow * K + kt + lk];
        __syncthreads();
        short8t a0 = *(const short8t*)&As[wr + fm][fk];
        short8t a1 = *(const short8t*)&As[wr + 16 + fm][fk];
        short8t b0 = *(const short8t*)&Bs[wc + fm][fk];
        short8t b1 = *(const short8t*)&Bs[wc + 16 + fm][fk];
        acc00 = __builtin_amdgcn_mfma_f32_16x16x32_bf16(a0, b0, acc00, 0, 0, 0);
        acc01 = __builtin_amdgcn_mfma_f32_16x16x32_bf16(a0, b1, acc01, 0, 0, 0);
        acc10 = __builtin_amdgcn_mfma_f32_16x16x32_bf16(a1, b0, acc10, 0, 0, 0);
        acc11 = __builtin_amdgcn_mfma_f32_16x16x32_bf16(a1, b1, acc11, 0, 0, 0);
        __syncthreads();
    }

    float* Cf = (float*)Cv;
    bf16* Cb = (bf16*)Cv;
    int row_base = tby * 64 + wr + (lane >> 4) * 4;
    int col_base = tbx * 64 + wc + fm;
    #pragma unroll
    for (int fr = 0; fr < 2; ++fr) {
        #pragma unroll
        for (int fc = 0; fc < 2; ++fc) {
            const f32x4& a = fr == 0 ? (fc == 0 ? acc00 : acc01) : (fc == 0 ? acc10 : acc11);
            #pragma unroll
            for (int r = 0; r < 4; ++r) {
                int gi = row_base + fr * 16 + r;
                int gj = col_base + fc * 16;
                float v = a[r];
                long ci = coff + (long)gi * ldc + gj;
                if (FLAGS & FLAG_ATOMIC) {
                    atomicAdd(&Cf[ci], v);
                } else {
                    if (FLAGS & FLAG_BIAS) v += bias[gj];
                    if (FLAGS & FLAG_GELU) v = gelu_f(v);
                    if (FLAGS & FLAG_ROWSCALE) v *= rsqrtf((float)(gi & 127) + 1.0f);
                    if (OUTB16) Cb[ci] = __float2bfloat16(v);
                    else        Cf[ci] = v;
                }
            }
        }
    }
}

// fused dual GEMM: z=0: vf = v1b @ vp2T^T + vp_b2;  z=1: hfeat = gelu(hacc..) @ ro2T^T + ro_b2
__global__ __launch_bounds__(256) void gemm_dual(
    const bf16* __restrict__ v1b, const bf16* __restrict__ vp2T, const float* __restrict__ vp_b2,
    const float* __restrict__ hacc, const bf16* __restrict__ ro2T, const float* __restrict__ ro_b1,
    const float* __restrict__ ro_b2, float* __restrict__ vf, float* __restrict__ hfeat)
{
    __shared__ __align__(16) bf16 As[64][44];
    __shared__ __align__(16) bf16 Bs[64][44];
    int tid = threadIdx.x;
    int lrow = tid >> 2, lk = (tid & 3) * 8;
    int w = tid >> 6, lane = tid & 63;
    int wr = (w >> 1) * 32, wc = (w & 1) * 32;
    int fm = lane & 15, fk = (lane >> 4) * 8;
    f32x4 acc00 = {0.f,0.f,0.f,0.f}, acc01 = acc00, acc10 = acc00, acc11 = acc00;
    int mode = blockIdx.z;
    int K = mode ? 128 : 512;
    const bf16* Bb = (mode ? ro2T : vp2T) + (long)blockIdx.x * 64 * K;

    for (int kt = 0; kt < K; kt += 32) {
        if (mode == 0) {
            const bf16* Ab = v1b + (long)blockIdx.y * 64 * K;
            *(float4*)&As[lrow][lk] = *(const float4*)&Ab[(long)lrow * K + kt + lk];
        } else {
            const float* Af = hacc + (long)blockIdx.y * 64 * K;
            int gk0 = kt + lk;
            float4 v0 = *(const float4*)&Af[(long)lrow * K + gk0];
            float4 v1 = *(const float4*)&Af[(long)lrow * K + gk0 + 4];
            float vv[8] = {v0.x, v0.y, v0.z, v0.w, v1.x, v1.y, v1.z, v1.w};
            int grow = blockIdx.y * 64 + lrow;
            float sc = rsqrtf((float)((grow & 127) + 1)) * (1.0f / 92681.900089f);
            #pragma unroll
            for (int j = 0; j < 8; ++j)
                As[lrow][lk + j] = __float2bfloat16(gelu_f(vv[j] * sc + ro_b1[gk0 + j]));
        }
        *(float4*)&Bs[lrow][lk] = *(const float4*)&Bb[(long)lrow * K + kt + lk];
        __syncthreads();
        short8t a0 = *(const short8t*)&As[wr + fm][fk];
        short8t a1 = *(const short8t*)&As[wr + 16 + fm][fk];
        short8t b0 = *(const short8t*)&Bs[wc + fm][fk];
        short8t b1 = *(const short8t*)&Bs[wc + 16 + fm][fk];
        acc00 = __builtin_amdgcn_mfma_f32_16x16x32_bf16(a0, b0, acc00, 0, 0, 0);
        acc01 = __builtin_amdgcn_mfma_f32_16x16x32_bf16(a0, b1, acc01, 0, 0, 0);
        acc10 = __builtin_amdgcn_mfma_f32_16x16x32_bf16(a1, b0, acc10, 0, 0, 0);
        acc11 = __builtin_amdgcn_mfma_f32_16x16x32_bf16(a1, b1, acc11, 0, 0, 0);
        __syncthreads();
    }

    const float* bias = mode ? ro_b2 : vp_b2;
    float* Cf = mode ? hfeat : vf;
    int row_base = blockIdx.y * 64 + wr + (lane >> 4) * 4;
    int col_base = blockIdx.x * 64 + wc + fm;
    #pragma unroll
    for (int fr = 0; fr < 2; ++fr) {
        #pragma unroll
        for (int fc = 0; fc < 2; ++fc) {
            const f32x4& a = fr == 0 ? (fc == 0 ? acc00 : acc01) : (fc == 0 ? acc10 : acc11);
            #pragma unroll
            for (int r = 0; r < 4; ++r) {
                int gi = row_base + fr * 16 + r;
                int gj = col_base + fc * 16;
                Cf[(long)gi * 512 + gj] = a[r] + bias[gj];
            }
        }
    }
}

// LN over D=512. FINAL=0: LN(x1); FINAL=1: LN(x1 + gf*x2 + gv*x3). OB16 selects out dtype.
template<int FINAL, int OB16>
__global__ __launch_bounds__(256) void ln_kernel(const float* __restrict__ x1,
                                                 const float* __restrict__ x2,
                                                 const float* __restrict__ x3,
                                                 const float* __restrict__ g,
                                                 const float* __restrict__ bb,
                                                 const float* __restrict__ scal,
                                                 void* __restrict__ outv) {
    int row = blockIdx.x, tid = threadIdx.x;
    long base = (long)row * D_;
    int d0 = tid, d1 = tid + 256;
    float v0, v1;
    if (FINAL) {
        float gf = scal[3], gv = scal[4];
        v0 = x1[base + d0] + gf * x2[base + d0] + gv * x3[base + d0];
        v1 = x1[base + d1] + gf * x2[base + d1] + gv * x3[base + d1];
    } else {
        v0 = x1[base + d0];
        v1 = x1[base + d1];
    }
    float s = v0 + v1;
    #pragma unroll
    for (int o = 32; o > 0; o >>= 1) s += __shfl_down(s, o);
    __shared__ float red[8];
    int wid = tid >> 6, lane = tid & 63;
    if (lane == 0) red[wid] = s;
    __syncthreads();
    float mu = (red[0] + red[1] + red[2] + red[3]) * (1.0f / D_);
    float e0 = v0 - mu, e1 = v1 - mu;
    float sq = e0 * e0 + e1 * e1;
    #pragma unroll
    for (int o = 32; o > 0; o >>= 1) sq += __shfl_down(sq, o);
    if (lane == 0) red[4 + wid] = sq;
    __syncthreads();
    float var = (red[4] + red[5] + red[6] + red[7]) * (1.0f / D_);
    float rs = rsqrtf(var + 1e-5f);
    float o0 = e0 * rs * g[d0] + bb[d0];
    float o1 = e1 * rs * g[d1] + bb[d1];
    if (OB16) {
        ((bf16*)outv)[base + d0] = __float2bfloat16(o0);
        ((bf16*)outv)[base + d1] = __float2bfloat16(o1);
    } else {
        ((float*)outv)[base + d0] = o0;
        ((float*)outv)[base + d1] = o1;
    }
}

extern "C" void kernel_launch(void* const* d_in, const int* in_sizes, int n_in,
                              void* d_out, int out_size, void* d_ws, size_t ws_size,
                              hipStream_t stream) {
    const float* e      = (const float*)d_in[0];
    const int*   h      = (const int*)d_in[1];
    const float* sign   = (const float*)d_in[2];
    const float* Wq     = (const float*)d_in[3];
    const float* Wk     = (const float*)d_in[4];
    const float* Wv     = (const float*)d_in[5];
    const float* ro_w1  = (const float*)d_in[6];
    const float* ro_b1  = (const float*)d_in[7];
    const float* ro_w2  = (const float*)d_in[8];
    const float* ro_b2  = (const float*)d_in[9];
    const float* vp_ln_g= (const float*)d_in[10];
    const float* vp_ln_b= (const float*)d_in[11];
    const float* vp_w1  = (const float*)d_in[12];
    const float* vp_b1  = (const float*)d_in[13];
    const float* vp_w2  = (const float*)d_in[14];
    const float* vp_b2  = (const float*)d_in[15];
    const float* ln_g   = (const float*)d_in[16];
    const float* ln_b   = (const float*)d_in[17];
    const float* tq     = (const float*)d_in[18];
    const float* tk     = (const float*)d_in[19];
    const float* om     = (const float*)d_in[20];
    const float* gfr    = (const float*)d_in[21];
    const float* gvr    = (const float*)d_in[22];

    float* ws    = (float*)d_ws;
    float* scal  = ws + OFF_SCAL;
    float* qkv   = ws + OFF_QKV;
    float* vraw  = ws + OFF_VRAW;
    float* vf    = ws + OFF_VF;
    float* hfeat = ws + OFF_HFEAT;
    float* scoacc= ws + OFF_SCOA;
    float* qsum  = ws + OFF_QSUM;
    float* hacc  = ws + OFF_HACC;
    bf16* kp16  = (bf16*)(ws + OFF_KP);
    bf16* eb    = (bf16*)(ws + OFF_EB);
    bf16* wqkvT = (bf16*)(ws + OFF_WQKVT);
    bf16* vp1T  = (bf16*)(ws + OFF_VP1T);
    bf16* vp2T  = (bf16*)(ws + OFF_VP2T);
    bf16* ro2T  = (bf16*)(ws + OFF_RO2T);
    bf16* qcat  = (bf16*)(ws + OFF_QCAT);
    bf16* kcat  = (bf16*)(ws + OFF_KCAT);
    bf16* dkT   = (bf16*)(ws + OFF_DKT);
    bf16* vTb   = (bf16*)(ws + OFF_VTB);
    bf16* vlnb  = (bf16*)(ws + OFF_VLNB);
    bf16* v1b   = (bf16*)(ws + OFF_V1B);
    bf16* pcat  = (bf16*)(ws + OFF_PCAT);
    bf16* ro1f  = (bf16*)(ws + OFF_RO1F);

    float* ys = (float*)d_out;
    float* kf = ys + (long)BT_ * D_;
    float* hf = kf + (long)B_ * 2 * M_;

    // fused preprocessing: scal+zero | e-cast | weight transposes | ro1 FFT
    preproc_kernel<<<3200, 256, 0, stream>>>(
        tq, tk, om, gfr, gvr, scal, scoacc, hacc,
        (const float4*)e, (ushort4t*)eb,
        Wq, Wk, Wv, vp_w1, vp_w2, ro_w2,
        wqkvT, wqkvT + 262144, wqkvT + 524288, vp1T, vp2T, ro2T,
        ro_w1, ro1f);

    // qkv = e @ [Wq|Wk|Wv]  (1024 x 1536 x 512) -> f32
    gemm_mfma<0, 0, 0><<<dim3(24, 16, 1), 256, 0, stream>>>(
        eb, wqkvT, nullptr, nullptr, qkv, 512, 1536, 0, 0, 0, 1);

    // fused sketch + vTb transpose
    sketchvtb_kernel<<<1536, 256, 0, stream>>>(qkv, sign, scal, h, qcat, kcat, vTb);

    // prefix over t reading bf16 kcat
    prefix_p1<<<512, 256, 0, stream>>>(kcat, qsum);
    prefix_p2<<<512, 256, 0, stream>>>(kcat, qsum, kp16, dkT, kf);

    // fused: forward FFTs + spectral product | scores split-K GEMM
    fftsco_kernel<<<1408, 256, 0, stream>>>(qcat, kp16, pcat, kcat, scoacc);

    // vraw[b] = masked(scores) @ v * rsqrt(t+1)  (mask fused in A-load)
    gemm_mfma<FLAG_ROWSCALE, 0, 1><<<dim3(8, 2, 8), 256, 0, stream>>>(
        scoacc, vTb, nullptr, nullptr, vraw, 128, 512, 16384, 65536, 65536, 1);

    ln_kernel<0, 1><<<1024, 256, 0, stream>>>(vraw, nullptr, nullptr, vp_ln_g, vp_ln_b, scal, vlnb);

    // fused: v1b = gelu(vlnb@vp1T+b1) | hid_pre split-K atomic into hacc
    v1hid_kernel<<<384, 256, 0, stream>>>(vlnb, vp1T, vp_b1, v1b, pcat, ro1f, hacc);

    // fused: vf = v1b@vp2T + b2  ||  hfeat = gelu(hacc*scale+ro_b1)@ro2T + ro_b2
    gemm_dual<<<dim3(8, 16, 2), 256, 0, stream>>>(
        v1b, vp2T, vp_b2, hacc, ro2T, ro_b1, ro_b2, vf, hfeat);

    // ys = LN(e + gf*hfeat + gv*vf)
    ln_kernel<1, 0><<<1024, 256, 0, stream>>>(e, hfeat, vf, ln_g, ln_b, scal, ys);

    // Hf fused: z in [0,16), b=z&7, c=z>>3
    gemm_mfma<FLAG_HFB, 0, 0><<<dim3(32, 8, 16), 256, 0, stream>>>(
        vTb, dkT, nullptr, nullptr, hf, 128, 2048, 65536, 0, 0, 1);
}